// Round 11
// baseline (491.672 us; speedup 1.0000x reference)
//
#include <hip/hip_runtime.h>
#include <hip/hip_bf16.h>
#include <cstdint>

#define M_ROWS 16384

typedef __attribute__((ext_vector_type(8))) short short8;
typedef __attribute__((ext_vector_type(4))) float f32x4;
typedef __attribute__((ext_vector_type(2))) float f32x2;

__device__ __forceinline__ unsigned long long umin64(unsigned long long a,
                                                     unsigned long long b) {
  return a < b ? a : b;
}

// ---------------------------------------------------------------------------
// fp32 GEMM body (SA1/SA2 — feeds masks, bit-identical path). smem >= 8704 B.
// ---------------------------------------------------------------------------
__device__ void gemm32_body(char* smemraw,
    const float* __restrict__ X, int ldx,
    const float* __restrict__ W,
    const float* __restrict__ bias,
    float* __restrict__ Y, int ldy,
    int N, int K, int bx, int by)
{
  float (*As)[68] = (float(*)[68])smemraw;
  float (*Bs)[68] = (float(*)[68])(smemraw + 16 * 68 * 4);
  int tid = threadIdx.x;
  int tx = tid & 15, ty = tid >> 4;
  int m0 = by << 6, n0 = bx << 6;
  float acc[4][4] = {};
  for (int k0 = 0; k0 < K; k0 += 16) {
#pragma unroll
    for (int i = 0; i < 4; i++) {
      int idx = tid + (i << 8);
      int m = idx >> 4, k = idx & 15;
      As[k][m] = (k0 + k < K) ? X[(size_t)(m0 + m) * ldx + k0 + k] : 0.f;
    }
#pragma unroll
    for (int i = 0; i < 4; i++) {
      int idx = tid + (i << 8);
      int n = idx & 63, k = idx >> 6;
      Bs[k][n] = (k0 + k < K) ? W[(size_t)(k0 + k) * N + n0 + n] : 0.f;
    }
    __syncthreads();
#pragma unroll
    for (int k = 0; k < 16; k++) {
      float4 a4 = *(const float4*)&As[k][ty << 2];
      float4 b4 = *(const float4*)&Bs[k][tx << 2];
      float av[4] = {a4.x, a4.y, a4.z, a4.w};
      float bv[4] = {b4.x, b4.y, b4.z, b4.w};
#pragma unroll
      for (int i = 0; i < 4; i++)
#pragma unroll
        for (int j = 0; j < 4; j++)
          acc[i][j] += av[i] * bv[j];
    }
    __syncthreads();
  }
  float4 bb = *(const float4*)&bias[n0 + (tx << 2)];
  float bv[4] = {bb.x, bb.y, bb.z, bb.w};
#pragma unroll
  for (int i = 0; i < 4; i++) {
    int m = m0 + (ty << 2) + i;
    float4 o;
    o.x = fmaxf(acc[i][0] + bv[0], 0.f);
    o.y = fmaxf(acc[i][1] + bv[1], 0.f);
    o.z = fmaxf(acc[i][2] + bv[2], 0.f);
    o.w = fmaxf(acc[i][3] + bv[3], 0.f);
    *(float4*)&Y[(size_t)m * ldy + n0 + (tx << 2)] = o;
  }
}

__global__ __launch_bounds__(256) void gemm_bias_relu(
    const float* __restrict__ X, int ldx,
    const float* __restrict__ W,
    const float* __restrict__ bias,
    float* __restrict__ Y, int ldy,
    int N, int K)
{
  __shared__ __align__(16) char smem[8704];
  gemm32_body(smem, X, ldx, W, bias, Y, ldy, N, K, blockIdx.x, blockIdx.y);
}

// ---------------------------------------------------------------------------
// Ball-query pass 1 body (symmetric, packed inner — bit-identical masks).
// smem >= 18944 B. NO min-occupancy bound anywhere (256,3 spilled: 10x).
// ---------------------------------------------------------------------------
template <int C>
__device__ void ball_body(char* smemraw,
    const float* __restrict__ F,
    unsigned long long* __restrict__ mask,
    float r2, int pairIdx, int batch)
{
  float (*As)[132] = (float(*)[132])smemraw;
  float (*Bs)[132] = (float(*)[132])(smemraw + 8448);
  unsigned int (*tw)[4] = (unsigned int(*)[4])(smemraw + 16896);
  int tid = threadIdx.x;
  int tx = tid & 15, ty = tid >> 4;
  int p = pairIdx;
  int qt = 0;
  while (p >= 16 - qt) { p -= 16 - qt; qt++; }
  int ct = qt + p;
  int b0 = batch << 11;
  int q0 = b0 + (qt << 7), c0 = b0 + (ct << 7);
  tw[tid >> 2][tid & 3] = 0;
  tw[(tid + 256) >> 2][tid & 3] = 0;
  f32x2 acc2[8][4] = {};
  for (int k0 = 0; k0 < C; k0 += 16) {
#pragma unroll
    for (int c = 0; c < 2; c++) {
      int idx = tid + (c << 8);
      int row = idx >> 2, qr = idx & 3;
      float4 va = *(const float4*)&F[(size_t)(q0 + row) * C + k0 + qr * 4];
      As[qr * 4 + 0][row] = va.x;
      As[qr * 4 + 1][row] = va.y;
      As[qr * 4 + 2][row] = va.z;
      As[qr * 4 + 3][row] = va.w;
      float4 vb = *(const float4*)&F[(size_t)(c0 + row) * C + k0 + qr * 4];
      Bs[qr * 4 + 0][row] = vb.x;
      Bs[qr * 4 + 1][row] = vb.y;
      Bs[qr * 4 + 2][row] = vb.z;
      Bs[qr * 4 + 3][row] = vb.w;
    }
    __syncthreads();
#pragma unroll
    for (int k = 0; k < 16; k++) {
      float av[8];
      f32x2 bv2[4];
      *(float4*)&av[0] = *(const float4*)&As[k][ty * 8];
      *(float4*)&av[4] = *(const float4*)&As[k][ty * 8 + 4];
      *(float4*)&bv2[0] = *(const float4*)&Bs[k][tx * 4];
      *(float4*)&bv2[2] = *(const float4*)&Bs[k][64 + tx * 4];
#pragma unroll
      for (int i = 0; i < 8; i++) {
        f32x2 a2 = {av[i], av[i]};
#pragma unroll
        for (int j2 = 0; j2 < 4; j2++) {
          f32x2 d = a2 - bv2[j2];
          acc2[i][j2] += d * d;
        }
      }
    }
    __syncthreads();
  }
  int w0 = ct << 1;
  unsigned int bytes[8] = {0, 0, 0, 0, 0, 0, 0, 0};
#pragma unroll
  for (int i = 0; i < 8; i++) {
    unsigned long long wlo = 0, whi = 0;
#pragma unroll
    for (int j = 0; j < 4; j++) {
      float dlo = acc2[i][j >> 1][j & 1];
      float dhi = acc2[i][2 + (j >> 1)][j & 1];
      if (dlo <= r2) { wlo |= 1ULL << (tx * 4 + j); bytes[j] |= 1u << i; }
      if (dhi <= r2) { whi |= 1ULL << (tx * 4 + j); bytes[4 + j] |= 1u << i; }
    }
#pragma unroll
    for (int s = 1; s <= 8; s <<= 1) {
      wlo |= __shfl_xor(wlo, s);
      whi |= __shfl_xor(whi, s);
    }
    if (tx == 0) {
      int q = q0 + ty * 8 + i;
      mask[(size_t)q * 32 + w0] = wlo;
      mask[(size_t)q * 32 + w0 + 1] = whi;
    }
  }
  if (qt != ct) {
    int sh = (ty & 3) * 8, wq = ty >> 2;
#pragma unroll
    for (int j2 = 0; j2 < 8; j2++) {
      int cl = ((j2 >> 2) << 6) + tx * 4 + (j2 & 3);
      atomicOr(&tw[cl][wq], bytes[j2] << sh);
    }
    __syncthreads();
    int row = tid >> 1, word = tid & 1;
    unsigned long long v = (unsigned long long)tw[row][word * 2] |
                           ((unsigned long long)tw[row][word * 2 + 1] << 32);
    mask[(size_t)(c0 + row) * 32 + (qt << 1) + word] = v;
  }
}

// ---------------------------------------------------------------------------
// bf16 MFMA GEMM body. smem >= 20480 B.
// ---------------------------------------------------------------------------
__device__ void mfma_body(char* smemraw,
    const short* __restrict__ Ag, const short* __restrict__ Bg,
    const float* __restrict__ bias, __hip_bfloat16* __restrict__ Y,
    int lda, int ldw, int ldy, int K, int m0, int n0)
{
  short (*As)[40] = (short(*)[40])smemraw;
  short (*Bs)[40] = (short(*)[40])(smemraw + 10240);
  int tid = threadIdx.x;
  int wave = tid >> 6, lane = tid & 63;
  int quad = lane >> 4, l16 = lane & 15;
  int wm = (wave >> 1) << 6, wn = (wave & 1) << 6;
  f32x4 acc[4][4] = {};
  int srow = tid >> 2, sq = tid & 3;
  for (int k0 = 0; k0 < K; k0 += 32) {
#pragma unroll
    for (int h = 0; h < 2; h++) {
      int r = srow + (h << 6);
      uint4 va = *(const uint4*)&Ag[(size_t)(m0 + r) * lda + k0 + sq * 8];
      *(uint4*)&As[r][sq * 8] = va;
      uint4 vb = *(const uint4*)&Bg[(size_t)(n0 + r) * ldw + k0 + sq * 8];
      *(uint4*)&Bs[r][sq * 8] = vb;
    }
    __syncthreads();
    short8 a[4], b[4];
#pragma unroll
    for (int mi = 0; mi < 4; mi++)
      a[mi] = *(const short8*)&As[wm + mi * 16 + l16][quad * 8];
#pragma unroll
    for (int ni = 0; ni < 4; ni++)
      b[ni] = *(const short8*)&Bs[wn + ni * 16 + l16][quad * 8];
#pragma unroll
    for (int mi = 0; mi < 4; mi++)
#pragma unroll
      for (int ni = 0; ni < 4; ni++)
        acc[mi][ni] = __builtin_amdgcn_mfma_f32_16x16x32_bf16(
            a[mi], b[ni], acc[mi][ni], 0, 0, 0);
    __syncthreads();
  }
  float bn[4];
#pragma unroll
  for (int ni = 0; ni < 4; ni++) bn[ni] = bias[n0 + wn + ni * 16 + l16];
#pragma unroll
  for (int mi = 0; mi < 4; mi++)
#pragma unroll
    for (int ni = 0; ni < 4; ni++) {
      int n = n0 + wn + ni * 16 + l16;
#pragma unroll
      for (int r = 0; r < 4; r++) {
        int m = m0 + wm + mi * 16 + quad * 4 + r;
        float v = fmaxf(acc[mi][ni][r] + bn[ni], 0.f);
        Y[(size_t)m * ldy + n] = (__hip_bfloat16)v;
      }
    }
}

struct GJobs {
  const short* A[3];
  const short* W[3];
  const float* bias[3];
  __hip_bfloat16* Y[3];
  int lda[3], ldw[3], ldy[3], N[3], K[3], xt[3], off[3];
};

__global__ __launch_bounds__(256) void gemm_mfma_multi(GJobs g)
{
  __shared__ __align__(16) char smem[20480];
  int bid = blockIdx.x;
  int j = 0;
#pragma unroll
  for (int t = 1; t < 3; t++)
    if (bid >= g.off[t]) j = t;
  int rel = bid - g.off[j];
  mfma_body(smem, g.A[j], g.W[j], g.bias[j], g.Y[j],
            g.lda[j], g.ldw[j], g.ldy[j], g.K[j],
            (rel / g.xt[j]) << 7, (rel % g.xt[j]) << 7);
}

// single-job variant (fc1) — bf16 out
__global__ __launch_bounds__(256) void gemm_mfma1(
    const __hip_bfloat16* __restrict__ A, int lda,
    const __hip_bfloat16* __restrict__ Wt, int ldw,
    const float* __restrict__ bias,
    __hip_bfloat16* __restrict__ Y, int ldy, int K)
{
  __shared__ __align__(16) char smem[20480];
  mfma_body(smem, (const short*)A, (const short*)Wt, bias, Y,
            lda, ldw, ldy, K, blockIdx.y << 7, blockIdx.x << 7);
}

// ---------------------------------------------------------------------------
// HETEROGENEOUS MERGE A: ball_mask<64> (1088 blocks) + sa2-l1 fp32 (512).
// Both depend only on X1; VALU-only and fp32-GEMM blocks co-schedule.
// ---------------------------------------------------------------------------
__global__ __launch_bounds__(256) void fused_ball64_sa2l1(
    const float* __restrict__ X1,
    unsigned long long* __restrict__ MASK, float r2,
    const float* __restrict__ W, const float* __restrict__ bias,
    float* __restrict__ T)
{
  __shared__ __align__(16) char smem[18944];
  int bid = blockIdx.x;
  if (bid < 1088) {
    ball_body<64>(smem, X1, MASK, r2, bid % 136, bid / 136);
  } else {
    int rel = bid - 1088;  // [0,512): bx = rel&1, by = rel>>1
    gemm32_body(smem, X1, 64, W, bias, T, 128, 128, 64, rel & 1, rel >> 1);
  }
}

// ---------------------------------------------------------------------------
// HETEROGENEOUS MERGE B: ball_mask<128> (1088 blocks) + g1 MFMA triple
// (1024 blocks). Both ready after gather2; MFMA pipe + VALU pipe overlap
// (m114). All math identical to the standalone kernels.
// ---------------------------------------------------------------------------
__global__ __launch_bounds__(256) void fused_ball128_g1(
    const float* __restrict__ X2,
    unsigned long long* __restrict__ MASK, float r2, GJobs g)
{
  __shared__ __align__(16) char smem[20480];
  int bid = blockIdx.x;
  if (bid < 1088) {
    ball_body<128>(smem, X2, MASK, r2, bid % 136, bid / 136);
    return;
  }
  int rel0 = bid - 1088;
  int j = 0;
#pragma unroll
  for (int t = 1; t < 3; t++)
    if (rel0 >= g.off[t]) j = t;
  int rel = rel0 - g.off[j];
  mfma_body(smem, g.A[j], g.W[j], g.bias[j], g.Y[j],
            g.lda[j], g.ldw[j], g.ldy[j], g.K[j],
            (rel / g.xt[j]) << 7, (rel % g.xt[j]) << 7);
}

// ---------------------------------------------------------------------------
// Fused weight prep: 8 transposes in one dispatch.
// ---------------------------------------------------------------------------
struct TJobs {
  const float* W[8];
  __hip_bfloat16* Wt[8];
  int K[8], N[8], bx[8], off[8];
};

__global__ __launch_bounds__(256) void transpose_cast_all(TJobs jb)
{
  __shared__ float tile[32][33];
  int bid = blockIdx.x;
  int j = 0;
#pragma unroll
  for (int t = 1; t < 8; t++)
    if (bid >= jb.off[t]) j = t;
  int rel = bid - jb.off[j];
  int K = jb.K[j], N = jb.N[j];
  const float* W = jb.W[j];
  __hip_bfloat16* Wt = jb.Wt[j];
  int n0 = (rel % jb.bx[j]) << 5, k0 = (rel / jb.bx[j]) << 5;
  int c = threadIdx.x & 31, i0 = threadIdx.x >> 5;
#pragma unroll
  for (int p = 0; p < 4; p++) {
    int i = i0 + p * 8;
    tile[i][c] = W[(size_t)(k0 + i) * N + n0 + c];
  }
  __syncthreads();
#pragma unroll
  for (int p = 0; p < 4; p++) {
    int r = i0 + p * 8;
    Wt[(size_t)(n0 + r) * K + k0 + c] = (__hip_bfloat16)tile[c][r];
  }
}

// ---------------------------------------------------------------------------
// fc2 + out head fused.
// ---------------------------------------------------------------------------
__global__ __launch_bounds__(256) void gemm_fc2_out(
    const __hip_bfloat16* __restrict__ A,
    const __hip_bfloat16* __restrict__ Wt,
    const float* __restrict__ bias,
    const float* __restrict__ wout,
    const float* __restrict__ bout,
    float* __restrict__ out)
{
  __shared__ __align__(16) short As[128][40];
  __shared__ __align__(16) short Bs[128][40];
  __shared__ float red[128][2];
  const int N = 128, K = 256, lda = 256, ldw = 256;
  int tid = threadIdx.x;
  int wave = tid >> 6, lane = tid & 63;
  int quad = lane >> 4, l16 = lane & 15;
  int m0 = blockIdx.y << 7;
  int wm = (wave >> 1) << 6, wn = (wave & 1) << 6;
  f32x4 acc[4][4] = {};
  const short* Ag = (const short*)A;
  const short* Bg = (const short*)Wt;
  int srow = tid >> 2, sq = tid & 3;
  for (int k0 = 0; k0 < K; k0 += 32) {
#pragma unroll
    for (int h = 0; h < 2; h++) {
      int r = srow + (h << 6);
      uint4 va = *(const uint4*)&Ag[(size_t)(m0 + r) * lda + k0 + sq * 8];
      *(uint4*)&As[r][sq * 8] = va;
      uint4 vb = *(const uint4*)&Bg[(size_t)(r % N) * ldw + k0 + sq * 8];
      *(uint4*)&Bs[r][sq * 8] = vb;
    }
    __syncthreads();
    short8 a[4], b[4];
#pragma unroll
    for (int mi = 0; mi < 4; mi++)
      a[mi] = *(const short8*)&As[wm + mi * 16 + l16][quad * 8];
#pragma unroll
    for (int ni = 0; ni < 4; ni++)
      b[ni] = *(const short8*)&Bs[wn + ni * 16 + l16][quad * 8];
#pragma unroll
    for (int mi = 0; mi < 4; mi++)
#pragma unroll
      for (int ni = 0; ni < 4; ni++)
        acc[mi][ni] = __builtin_amdgcn_mfma_f32_16x16x32_bf16(
            a[mi], b[ni], acc[mi][ni], 0, 0, 0);
    __syncthreads();
  }
  float bn[4], wo[4];
#pragma unroll
  for (int ni = 0; ni < 4; ni++) {
    int n = wn + ni * 16 + l16;
    bn[ni] = bias[n];
    wo[ni] = wout[n];
  }
  float sacc[4][4];
#pragma unroll
  for (int mi = 0; mi < 4; mi++)
#pragma unroll
    for (int r = 0; r < 4; r++) {
      float s = 0.f;
#pragma unroll
      for (int ni = 0; ni < 4; ni++)
        s += fmaxf(acc[mi][ni][r] + bn[ni], 0.f) * wo[ni];
      sacc[mi][r] = s;
    }
#pragma unroll
  for (int off = 1; off < 16; off <<= 1)
#pragma unroll
    for (int mi = 0; mi < 4; mi++)
#pragma unroll
      for (int r = 0; r < 4; r++)
        sacc[mi][r] += __shfl_xor(sacc[mi][r], off);
  int wp = wave & 1;
  if (l16 == 0) {
#pragma unroll
    for (int mi = 0; mi < 4; mi++)
#pragma unroll
      for (int r = 0; r < 4; r++)
        red[wm + mi * 16 + quad * 4 + r][wp] = sacc[mi][r];
  }
  __syncthreads();
  if (tid < 128) {
    float s = red[tid][0] + red[tid][1] + bout[0];
    out[(size_t)(m0 + tid)] = 1.f / (1.f + expf(-s));
  }
}

// ---------------------------------------------------------------------------
// SA1 KNN v5 (round-8/10 version — two-level threshold, passing).
// ---------------------------------------------------------------------------
__global__ __launch_bounds__(256) void knn_mean_kernel(
    const float* __restrict__ X,
    const float* __restrict__ G1,
    float* __restrict__ X1,
    __hip_bfloat16* __restrict__ X1b)
{
  int q = blockIdx.x;
  int base = q & ~2047;
  int tid = threadIdx.x;
  __shared__ unsigned long long lmins[256];
  __shared__ unsigned long long qmins[64];
  __shared__ unsigned long long surv[2048];
  __shared__ unsigned long long thr;
  __shared__ int scnt;
  __shared__ int selidx[32];
  if (tid == 0) scnt = 0;
  float qx = X[(size_t)q * 2], qy = X[(size_t)q * 2 + 1];
  unsigned long long key[8];
#pragma unroll
  for (int u = 0; u < 8; u++) {
    int j = (u << 8) + tid;
    float dx = X[(size_t)(base + j) * 2] - qx;
    float dy = X[(size_t)(base + j) * 2 + 1] - qy;
    float d2 = dx * dx + dy * dy;
    key[u] = ((unsigned long long)__float_as_uint(d2) << 32) | (unsigned)j;
  }
  unsigned long long lm = key[0];
#pragma unroll
  for (int u = 1; u < 8; u++) lm = umin64(lm, key[u]);
  lmins[tid] = lm;
  __syncthreads();
  if (tid < 64) {
    unsigned long long qm = umin64(umin64(lmins[tid], lmins[tid + 64]),
                                   umin64(lmins[tid + 128], lmins[tid + 192]));
    qmins[tid] = qm;
    int rank = 0;
    for (int i = 0; i < 64; i++) rank += (qmins[i] < qm);
    if (rank == 31) thr = qm;
  }
  __syncthreads();
  unsigned long long T = thr;
#pragma unroll
  for (int u = 0; u < 8; u++) {
    if (key[u] <= T) {
      int p = atomicAdd(&scnt, 1);
      surv[p] = key[u];
    }
  }
  __syncthreads();
  int s = scnt;
  for (int i = tid; i < s; i += 256) {
    unsigned long long c = surv[i];
    int r = 0;
    for (int j2 = 0; j2 < s; j2++) r += (surv[j2] < c);
    if (r < 32) selidx[r] = (int)(c & 0xffffffffULL);
  }
  __syncthreads();
  if (tid < 64) {
    float acc = 0.f;
#pragma unroll 4
    for (int sI = 0; sI < 32; sI++)
      acc += G1[(size_t)(base + selidx[sI]) * 64 + tid];
    float v = acc * (1.0f / 32.0f);
    X1[(size_t)q * 64 + tid] = v;
    X1b[(size_t)q * 64 + tid] = (__hip_bfloat16)v;
  }
}

// ---------------------------------------------------------------------------
// Ball-query pass 2 (templated input dtype; fp32 accumulate).
// ---------------------------------------------------------------------------
template <typename TIn>
__global__ void ball_gather_kernel(
    const unsigned long long* __restrict__ mask,
    const TIn* __restrict__ H, int CH,
    float* __restrict__ Yf, __hip_bfloat16* __restrict__ Yb,
    int ldy, int S)
{
  int q = blockIdx.x;
  int base = q & ~2047;
  int tid = threadIdx.x;
  __shared__ int idxl[64];
  __shared__ float wtab[64];
  __shared__ int scount;
  if (tid < 32) {
    unsigned long long w = mask[(size_t)q * 32 + tid];
    int cnt = __popcll(w);
    int inc = cnt;
#pragma unroll
    for (int off = 1; off < 32; off <<= 1) {
      int o = __shfl_up(inc, off);
      if (tid >= off) inc += o;
    }
    if (tid == 31) scount = inc;
    int p = inc - cnt;
    while (w && p < 64) {
      int j = (tid << 6) + __builtin_ctzll(w);
      w &= w - 1;
      idxl[p++] = j;
    }
  }
  __syncthreads();
  int c = scount;
  if (tid < 64) {
    int p = tid;
    int cnt = (p < c && p < S) ? ((S - 1 - p) / c + 1) : 0;
    wtab[p] = (float)cnt / (float)S;
  }
  __syncthreads();
  float acc = 0.f;
  int lim = c < S ? c : S;
#pragma unroll 4
  for (int s = 0; s < lim; s++)
    acc += wtab[s] * (float)H[(size_t)(base + idxl[s]) * CH + tid];
  if (Yf) Yf[(size_t)q * ldy + tid] = acc;
  if (Yb) Yb[(size_t)q * ldy + tid] = (__hip_bfloat16)acc;
}

// ---------------------------------------------------------------------------
extern "C" void kernel_launch(void* const* d_in, const int* in_sizes, int n_in,
                              void* d_out, int out_size, void* d_ws,
                              size_t ws_size, hipStream_t stream)
{
  const float* x      = (const float*)d_in[0];
  const float* sa1_w0 = (const float*)d_in[1];
  const float* sa1_b0 = (const float*)d_in[2];
  const float* sa1_w1 = (const float*)d_in[3];
  const float* sa1_b1 = (const float*)d_in[4];
  const float* sa2_w0 = (const float*)d_in[5];
  const float* sa2_b0 = (const float*)d_in[6];
  const float* sa2_w1 = (const float*)d_in[7];
  const float* sa2_b1 = (const float*)d_in[8];
  const float* sa3_w0 = (const float*)d_in[9];
  const float* sa3_b0 = (const float*)d_in[10];
  const float* sa3_w1 = (const float*)d_in[11];
  const float* sa3_b1 = (const float*)d_in[12];
  const float* fp1_w0 = (const float*)d_in[13];
  const float* fp1_b0 = (const float*)d_in[14];
  const float* fp1_w1 = (const float*)d_in[15];
  const float* fp1_b1 = (const float*)d_in[16];
  const float* fp2_w0 = (const float*)d_in[17];
  const float* fp2_b0 = (const float*)d_in[18];
  const float* fp2_w1 = (const float*)d_in[19];
  const float* fp2_b1 = (const float*)d_in[20];
  const float* fc1_w  = (const float*)d_in[21];
  const float* fc1_b  = (const float*)d_in[22];
  const float* fc2_w  = (const float*)d_in[23];
  const float* fc2_b  = (const float*)d_in[24];
  const float* out_w  = (const float*)d_in[25];
  const float* out_b  = (const float*)d_in[26];
  float* out = (float*)d_out;

  const size_t M = M_ROWS;
  float* ws = (float*)d_ws;
  float* T   = ws;             // [0,256)
  float* G1  = ws + M * 256;   // [256,320)
  float* X1  = ws + M * 320;   // [320,384)
  float* X2  = ws + M * 384;   // [384,512)
  float* H2  = ws + M * 512;   // [512,640)
  __hip_bfloat16* H3b16 = (__hip_bfloat16*)(ws + M * 640);  // [640,768)
  unsigned long long* MASK = (unsigned long long*)(ws + M * 896);  // [896,960)
  __hip_bfloat16* X1b = (__hip_bfloat16*)(ws + M * 960);    // [960,992)
  __hip_bfloat16* X2b = (__hip_bfloat16*)(ws + M * 992);    // [992,1056)
  __hip_bfloat16* TB0 = (__hip_bfloat16*)(ws + M * 1056);   // [1056,1184)
  __hip_bfloat16* TB1 = (__hip_bfloat16*)(ws + M * 1184);   // [1184,1440)
  __hip_bfloat16* TB2 = (__hip_bfloat16*)(ws + M * 1440);   // [1440,1568)
  __hip_bfloat16* G   = (__hip_bfloat16*)(ws + M * 1568);   // [1568,2080)
  __hip_bfloat16* H3b = (__hip_bfloat16*)(ws + M * 2080);   // [2080,2208)
  __hip_bfloat16* WB  = (__hip_bfloat16*)(ws + M * 2208);
  if (ws_size < (size_t)M * 2240 * sizeof(float)) return;
  __hip_bfloat16* w_sa3_0 = WB;               // 256x128
  __hip_bfloat16* w_sa3_1 = w_sa3_0 + 32768;  // 256x256
  __hip_bfloat16* w_fp1_0 = w_sa3_1 + 65536;  // 512x128
  __hip_bfloat16* w_fp1_1 = w_fp1_0 + 65536;  // 512x512
  __hip_bfloat16* w_fp2_0 = w_fp1_1 + 262144; // 256x64
  __hip_bfloat16* w_fp2_1 = w_fp2_0 + 16384;  // 256x256
  __hip_bfloat16* w_fc1   = w_fp2_1 + 65536;  // 256x1024
  __hip_bfloat16* w_fc2   = w_fc1 + 262144;   // 128x256

  dim3 blk(256);
  TJobs jb;
  const float* srcs[8] = {sa3_w0, sa3_w1, fp1_w0, fp1_w1, fp2_w0, fp2_w1, fc1_w, fc2_w};
  __hip_bfloat16* dsts[8] = {w_sa3_0, w_sa3_1, w_fp1_0, w_fp1_1, w_fp2_0, w_fp2_1, w_fc1, w_fc2};
  int Ks[8] = {128, 256, 128, 512, 64, 256, 1024, 256};
  int Ns[8] = {256, 256, 512, 512, 256, 256, 256, 128};
  int off = 0;
  for (int i = 0; i < 8; i++) {
    jb.W[i] = srcs[i]; jb.Wt[i] = dsts[i];
    jb.K[i] = Ks[i]; jb.N[i] = Ns[i];
    jb.bx[i] = Ns[i] >> 5;
    jb.off[i] = off;
    off += (Ns[i] >> 5) * (Ks[i] >> 5);
  }
  transpose_cast_all<<<off, blk, 0, stream>>>(jb);

  // SA1 (fp32 exact) + knn.
  gemm_bias_relu<<<dim3(1, 256), blk, 0, stream>>>(x, 2, sa1_w0, sa1_b0, T, 64, 64, 2);
  gemm_bias_relu<<<dim3(1, 256), blk, 0, stream>>>(T, 64, sa1_w1, sa1_b1, G1, 64, 64, 64);
  knn_mean_kernel<<<16384, 256, 0, stream>>>(x, G1, X1, X1b);
  // MERGE A: ball64 + sa2-l1 (both depend only on X1); then sa2-l2, gather2.
  fused_ball64_sa2l1<<<1088 + 512, blk, 0, stream>>>(X1, MASK, 0.2f * 0.2f,
                                                     sa2_w0, sa2_b0, T);
  gemm_bias_relu<<<dim3(2, 256), blk, 0, stream>>>(T, 128, sa2_w1, sa2_b1, H2, 128, 128, 128);
  ball_gather_kernel<float><<<16384, 128, 0, stream>>>(MASK, H2, 128, X2, X2b, 128, 32);
  // MERGE B: ball128 + layer-1 MFMA triple (all depend only on gather2/knn outs).
  GJobs g1;
  g1.A[0] = (const short*)X2b; g1.W[0] = (const short*)w_sa3_0; g1.bias[0] = sa3_b0;
  g1.Y[0] = TB0; g1.lda[0] = 128; g1.ldw[0] = 128; g1.ldy[0] = 256; g1.N[0] = 256; g1.K[0] = 128;
  g1.A[1] = (const short*)X2b; g1.W[1] = (const short*)w_fp1_0; g1.bias[1] = fp1_b0;
  g1.Y[1] = TB1; g1.lda[1] = 128; g1.ldw[1] = 128; g1.ldy[1] = 512; g1.N[1] = 512; g1.K[1] = 128;
  g1.A[2] = (const short*)X1b; g1.W[2] = (const short*)w_fp2_0; g1.bias[2] = fp2_b0;
  g1.Y[2] = TB2; g1.lda[2] = 64; g1.ldw[2] = 64; g1.ldy[2] = 256; g1.N[2] = 256; g1.K[2] = 64;
  int tot1 = 0;
  for (int i = 0; i < 3; i++) {
    g1.xt[i] = g1.N[i] >> 7;
    g1.off[i] = tot1;
    tot1 += g1.xt[i] * 128;
  }
  fused_ball128_g1<<<1088 + tot1, blk, 0, stream>>>(X2, MASK, 0.4f * 0.4f, g1);

  GJobs g2;
  g2.A[0] = (const short*)TB0; g2.W[0] = (const short*)w_sa3_1; g2.bias[0] = sa3_b1;
  g2.Y[0] = H3b16; g2.lda[0] = 256; g2.ldw[0] = 256; g2.ldy[0] = 256; g2.N[0] = 256; g2.K[0] = 256;
  g2.A[1] = (const short*)TB1; g2.W[1] = (const short*)w_fp1_1; g2.bias[1] = fp1_b1;
  g2.Y[1] = G + 256; g2.lda[1] = 512; g2.ldw[1] = 512; g2.ldy[1] = 1024; g2.N[1] = 512; g2.K[1] = 512;
  g2.A[2] = (const short*)TB2; g2.W[2] = (const short*)w_fp2_1; g2.bias[2] = fp2_b1;
  g2.Y[2] = G; g2.lda[2] = 256; g2.ldw[2] = 256; g2.ldy[2] = 1024; g2.N[2] = 256; g2.K[2] = 256;
  int tot2 = 0;
  for (int i = 0; i < 3; i++) {
    g2.xt[i] = g2.N[i] >> 7;
    g2.off[i] = tot2;
    tot2 += g2.xt[i] * 128;
  }
  gemm_mfma_multi<<<tot2, blk, 0, stream>>>(g2);

  // gather3 fills G[768:1024] from sa3 output.
  ball_gather_kernel<__hip_bfloat16><<<16384, 256, 0, stream>>>(MASK, H3b16, 256, nullptr, G + 768, 1024, 64);
  // Head: fc1 (bf16), then fc2+out fused.
  gemm_mfma1<<<dim3(2, 128), blk, 0, stream>>>(G, 1024, w_fc1, 1024, fc1_b, H3b, 256, 1024);
  gemm_fc2_out<<<dim3(1, 128), blk, 0, stream>>>(H3b, w_fc2, fc2_b, out_w, out_b, out);
}

// Round 12
// 402.635 us; speedup vs baseline: 1.2211x; 1.2211x over previous
//
#include <hip/hip_runtime.h>
#include <hip/hip_bf16.h>
#include <cstdint>

#define M_ROWS 16384

typedef __attribute__((ext_vector_type(8))) short short8;
typedef __attribute__((ext_vector_type(4))) float f32x4;

__device__ __forceinline__ unsigned long long umin64(unsigned long long a,
                                                     unsigned long long b) {
  return a < b ? a : b;
}

// ---------------------------------------------------------------------------
// fp32 GEMM (SA1/SA2 — feeds masks, bit-identical path).
// ---------------------------------------------------------------------------
__global__ __launch_bounds__(256) void gemm_bias_relu(
    const float* __restrict__ X, int ldx,
    const float* __restrict__ W,
    const float* __restrict__ bias,
    float* __restrict__ Y, int ldy,
    int N, int K)
{
  __shared__ __align__(16) float As[16][68];
  __shared__ __align__(16) float Bs[16][68];
  int tid = threadIdx.x;
  int tx = tid & 15, ty = tid >> 4;
  int m0 = blockIdx.y << 6, n0 = blockIdx.x << 6;
  float acc[4][4] = {};
  for (int k0 = 0; k0 < K; k0 += 16) {
#pragma unroll
    for (int i = 0; i < 4; i++) {
      int idx = tid + (i << 8);
      int m = idx >> 4, k = idx & 15;
      As[k][m] = (k0 + k < K) ? X[(size_t)(m0 + m) * ldx + k0 + k] : 0.f;
    }
#pragma unroll
    for (int i = 0; i < 4; i++) {
      int idx = tid + (i << 8);
      int n = idx & 63, k = idx >> 6;
      Bs[k][n] = (k0 + k < K) ? W[(size_t)(k0 + k) * N + n0 + n] : 0.f;
    }
    __syncthreads();
#pragma unroll
    for (int k = 0; k < 16; k++) {
      float4 a4 = *(const float4*)&As[k][ty << 2];
      float4 b4 = *(const float4*)&Bs[k][tx << 2];
      float av[4] = {a4.x, a4.y, a4.z, a4.w};
      float bv[4] = {b4.x, b4.y, b4.z, b4.w};
#pragma unroll
      for (int i = 0; i < 4; i++)
#pragma unroll
        for (int j = 0; j < 4; j++)
          acc[i][j] += av[i] * bv[j];
    }
    __syncthreads();
  }
  float4 bb = *(const float4*)&bias[n0 + (tx << 2)];
  float bv[4] = {bb.x, bb.y, bb.z, bb.w};
#pragma unroll
  for (int i = 0; i < 4; i++) {
    int m = m0 + (ty << 2) + i;
    float4 o;
    o.x = fmaxf(acc[i][0] + bv[0], 0.f);
    o.y = fmaxf(acc[i][1] + bv[1], 0.f);
    o.z = fmaxf(acc[i][2] + bv[2], 0.f);
    o.w = fmaxf(acc[i][3] + bv[3], 0.f);
    *(float4*)&Y[(size_t)m * ldy + n0 + (tx << 2)] = o;
  }
}

// ---------------------------------------------------------------------------
// Fused weight prep: 8 transposes (W KxN fp32 -> Wt NxK bf16) in one dispatch.
// ---------------------------------------------------------------------------
struct TJobs {
  const float* W[8];
  __hip_bfloat16* Wt[8];
  int K[8], N[8], bx[8], off[8];
};

__global__ __launch_bounds__(256) void transpose_cast_all(TJobs jb)
{
  __shared__ float tile[32][33];
  int bid = blockIdx.x;
  int j = 0;
#pragma unroll
  for (int t = 1; t < 8; t++)
    if (bid >= jb.off[t]) j = t;
  int rel = bid - jb.off[j];
  int K = jb.K[j], N = jb.N[j];
  const float* W = jb.W[j];
  __hip_bfloat16* Wt = jb.Wt[j];
  int n0 = (rel % jb.bx[j]) << 5, k0 = (rel / jb.bx[j]) << 5;
  int c = threadIdx.x & 31, i0 = threadIdx.x >> 5;
#pragma unroll
  for (int p = 0; p < 4; p++) {
    int i = i0 + p * 8;
    tile[i][c] = W[(size_t)(k0 + i) * N + n0 + c];
  }
  __syncthreads();
#pragma unroll
  for (int p = 0; p < 4; p++) {
    int r = i0 + p * 8;
    Wt[(size_t)(n0 + r) * K + k0 + c] = (__hip_bfloat16)tile[c][r];
  }
}

// ---------------------------------------------------------------------------
// bf16 MFMA GEMM (single-job; used for fc1).
// ---------------------------------------------------------------------------
template <bool OUT_BF16>
__global__ __launch_bounds__(256) void gemm_mfma(
    const __hip_bfloat16* __restrict__ A, int lda,
    const __hip_bfloat16* __restrict__ Wt, int ldw,
    const float* __restrict__ bias,
    void* __restrict__ Y, int ldy, int N, int K)
{
  __shared__ __align__(16) short As[128][40];
  __shared__ __align__(16) short Bs[128][40];
  int tid = threadIdx.x;
  int wave = tid >> 6, lane = tid & 63;
  int quad = lane >> 4, l16 = lane & 15;
  int m0 = blockIdx.y << 7, n0 = blockIdx.x << 7;
  int wm = (wave >> 1) << 6, wn = (wave & 1) << 6;
  f32x4 acc[4][4] = {};
  const short* Ag = (const short*)A;
  const short* Bg = (const short*)Wt;
  int srow = tid >> 2, sq = tid & 3;
  for (int k0 = 0; k0 < K; k0 += 32) {
#pragma unroll
    for (int h = 0; h < 2; h++) {
      int r = srow + (h << 6);
      uint4 va = *(const uint4*)&Ag[(size_t)(m0 + r) * lda + k0 + sq * 8];
      *(uint4*)&As[r][sq * 8] = va;
      uint4 vb = *(const uint4*)&Bg[(size_t)(n0 + r) * ldw + k0 + sq * 8];
      *(uint4*)&Bs[r][sq * 8] = vb;
    }
    __syncthreads();
    short8 a[4], b[4];
#pragma unroll
    for (int mi = 0; mi < 4; mi++)
      a[mi] = *(const short8*)&As[wm + mi * 16 + l16][quad * 8];
#pragma unroll
    for (int ni = 0; ni < 4; ni++)
      b[ni] = *(const short8*)&Bs[wn + ni * 16 + l16][quad * 8];
#pragma unroll
    for (int mi = 0; mi < 4; mi++)
#pragma unroll
      for (int ni = 0; ni < 4; ni++)
        acc[mi][ni] = __builtin_amdgcn_mfma_f32_16x16x32_bf16(
            a[mi], b[ni], acc[mi][ni], 0, 0, 0);
    __syncthreads();
  }
  float bn[4];
#pragma unroll
  for (int ni = 0; ni < 4; ni++) bn[ni] = bias[n0 + wn + ni * 16 + l16];
#pragma unroll
  for (int mi = 0; mi < 4; mi++)
#pragma unroll
    for (int ni = 0; ni < 4; ni++) {
      int n = n0 + wn + ni * 16 + l16;
#pragma unroll
      for (int r = 0; r < 4; r++) {
        int m = m0 + wm + mi * 16 + quad * 4 + r;
        float v = fmaxf(acc[mi][ni][r] + bn[ni], 0.f);
        if (OUT_BF16)
          ((__hip_bfloat16*)Y)[(size_t)m * ldy + n] = (__hip_bfloat16)v;
        else
          ((float*)Y)[(size_t)m * ldy + n] = v;
      }
    }
}

// ---------------------------------------------------------------------------
// Multi-job bf16 MFMA GEMM (round-10 version — bit-identical outputs).
// ---------------------------------------------------------------------------
struct GJobs {
  const short* A[3];
  const short* W[3];
  const float* bias[3];
  __hip_bfloat16* Y[3];
  int lda[3], ldw[3], ldy[3], N[3], K[3], xt[3], off[3];
};

__global__ __launch_bounds__(256) void gemm_mfma_multi(GJobs g)
{
  __shared__ __align__(16) short As[128][40];
  __shared__ __align__(16) short Bs[128][40];
  int bid = blockIdx.x;
  int j = 0;
#pragma unroll
  for (int t = 1; t < 3; t++)
    if (bid >= g.off[t]) j = t;
  int rel = bid - g.off[j];
  int xt = g.xt[j];
  int m0 = (rel / xt) << 7, n0 = (rel % xt) << 7;
  int lda = g.lda[j], ldw = g.ldw[j], ldy = g.ldy[j], K = g.K[j];
  const short* Ag = g.A[j];
  const short* Bg = g.W[j];
  const float* bias = g.bias[j];
  __hip_bfloat16* Y = g.Y[j];

  int tid = threadIdx.x;
  int wave = tid >> 6, lane = tid & 63;
  int quad = lane >> 4, l16 = lane & 15;
  int wm = (wave >> 1) << 6, wn = (wave & 1) << 6;
  f32x4 acc[4][4] = {};
  int srow = tid >> 2, sq = tid & 3;
  for (int k0 = 0; k0 < K; k0 += 32) {
#pragma unroll
    for (int h = 0; h < 2; h++) {
      int r = srow + (h << 6);
      uint4 va = *(const uint4*)&Ag[(size_t)(m0 + r) * lda + k0 + sq * 8];
      *(uint4*)&As[r][sq * 8] = va;
      uint4 vb = *(const uint4*)&Bg[(size_t)(n0 + r) * ldw + k0 + sq * 8];
      *(uint4*)&Bs[r][sq * 8] = vb;
    }
    __syncthreads();
    short8 a[4], b[4];
#pragma unroll
    for (int mi = 0; mi < 4; mi++)
      a[mi] = *(const short8*)&As[wm + mi * 16 + l16][quad * 8];
#pragma unroll
    for (int ni = 0; ni < 4; ni++)
      b[ni] = *(const short8*)&Bs[wn + ni * 16 + l16][quad * 8];
#pragma unroll
    for (int mi = 0; mi < 4; mi++)
#pragma unroll
      for (int ni = 0; ni < 4; ni++)
        acc[mi][ni] = __builtin_amdgcn_mfma_f32_16x16x32_bf16(
            a[mi], b[ni], acc[mi][ni], 0, 0, 0);
    __syncthreads();
  }
  float bn[4];
#pragma unroll
  for (int ni = 0; ni < 4; ni++) bn[ni] = bias[n0 + wn + ni * 16 + l16];
#pragma unroll
  for (int mi = 0; mi < 4; mi++)
#pragma unroll
    for (int ni = 0; ni < 4; ni++) {
      int n = n0 + wn + ni * 16 + l16;
#pragma unroll
      for (int r = 0; r < 4; r++) {
        int m = m0 + wm + mi * 16 + quad * 4 + r;
        float v = fmaxf(acc[mi][ni][r] + bn[ni], 0.f);
        Y[(size_t)m * ldy + n] = (__hip_bfloat16)v;
      }
    }
}

// ---------------------------------------------------------------------------
// fc2 + out head fused.
// ---------------------------------------------------------------------------
__global__ __launch_bounds__(256) void gemm_fc2_out(
    const __hip_bfloat16* __restrict__ A,
    const __hip_bfloat16* __restrict__ Wt,
    const float* __restrict__ bias,
    const float* __restrict__ wout,
    const float* __restrict__ bout,
    float* __restrict__ out)
{
  __shared__ __align__(16) short As[128][40];
  __shared__ __align__(16) short Bs[128][40];
  __shared__ float red[128][2];
  const int N = 128, K = 256, lda = 256, ldw = 256;
  int tid = threadIdx.x;
  int wave = tid >> 6, lane = tid & 63;
  int quad = lane >> 4, l16 = lane & 15;
  int m0 = blockIdx.y << 7;
  int wm = (wave >> 1) << 6, wn = (wave & 1) << 6;
  f32x4 acc[4][4] = {};
  const short* Ag = (const short*)A;
  const short* Bg = (const short*)Wt;
  int srow = tid >> 2, sq = tid & 3;
  for (int k0 = 0; k0 < K; k0 += 32) {
#pragma unroll
    for (int h = 0; h < 2; h++) {
      int r = srow + (h << 6);
      uint4 va = *(const uint4*)&Ag[(size_t)(m0 + r) * lda + k0 + sq * 8];
      *(uint4*)&As[r][sq * 8] = va;
      uint4 vb = *(const uint4*)&Bg[(size_t)(r % N) * ldw + k0 + sq * 8];
      *(uint4*)&Bs[r][sq * 8] = vb;
    }
    __syncthreads();
    short8 a[4], b[4];
#pragma unroll
    for (int mi = 0; mi < 4; mi++)
      a[mi] = *(const short8*)&As[wm + mi * 16 + l16][quad * 8];
#pragma unroll
    for (int ni = 0; ni < 4; ni++)
      b[ni] = *(const short8*)&Bs[wn + ni * 16 + l16][quad * 8];
#pragma unroll
    for (int mi = 0; mi < 4; mi++)
#pragma unroll
      for (int ni = 0; ni < 4; ni++)
        acc[mi][ni] = __builtin_amdgcn_mfma_f32_16x16x32_bf16(
            a[mi], b[ni], acc[mi][ni], 0, 0, 0);
    __syncthreads();
  }
  float bn[4], wo[4];
#pragma unroll
  for (int ni = 0; ni < 4; ni++) {
    int n = wn + ni * 16 + l16;
    bn[ni] = bias[n];
    wo[ni] = wout[n];
  }
  float sacc[4][4];
#pragma unroll
  for (int mi = 0; mi < 4; mi++)
#pragma unroll
    for (int r = 0; r < 4; r++) {
      float s = 0.f;
#pragma unroll
      for (int ni = 0; ni < 4; ni++)
        s += fmaxf(acc[mi][ni][r] + bn[ni], 0.f) * wo[ni];
      sacc[mi][r] = s;
    }
#pragma unroll
  for (int off = 1; off < 16; off <<= 1)
#pragma unroll
    for (int mi = 0; mi < 4; mi++)
#pragma unroll
      for (int r = 0; r < 4; r++)
        sacc[mi][r] += __shfl_xor(sacc[mi][r], off);
  int wp = wave & 1;
  if (l16 == 0) {
#pragma unroll
    for (int mi = 0; mi < 4; mi++)
#pragma unroll
      for (int r = 0; r < 4; r++)
        red[wm + mi * 16 + quad * 4 + r][wp] = sacc[mi][r];
  }
  __syncthreads();
  if (tid < 128) {
    float s = red[tid][0] + red[tid][1] + bout[0];
    out[(size_t)(m0 + tid)] = 1.f / (1.f + expf(-s));
  }
}

// ---------------------------------------------------------------------------
// SA1 KNN v5 + hi/lo/norm emission for X1 (hi == X1b, value unchanged).
// ---------------------------------------------------------------------------
__global__ __launch_bounds__(256) void knn_mean_kernel(
    const float* __restrict__ X,
    const float* __restrict__ G1,
    float* __restrict__ X1,
    __hip_bfloat16* __restrict__ X1b,
    __hip_bfloat16* __restrict__ X1lo,
    float* __restrict__ nrmX1)
{
  int q = blockIdx.x;
  int base = q & ~2047;
  int tid = threadIdx.x;
  __shared__ unsigned long long lmins[256];
  __shared__ unsigned long long qmins[64];
  __shared__ unsigned long long surv[2048];
  __shared__ unsigned long long thr;
  __shared__ int scnt;
  __shared__ int selidx[32];
  if (tid == 0) scnt = 0;
  float qx = X[(size_t)q * 2], qy = X[(size_t)q * 2 + 1];
  unsigned long long key[8];
#pragma unroll
  for (int u = 0; u < 8; u++) {
    int j = (u << 8) + tid;
    float dx = X[(size_t)(base + j) * 2] - qx;
    float dy = X[(size_t)(base + j) * 2 + 1] - qy;
    float d2 = dx * dx + dy * dy;
    key[u] = ((unsigned long long)__float_as_uint(d2) << 32) | (unsigned)j;
  }
  unsigned long long lm = key[0];
#pragma unroll
  for (int u = 1; u < 8; u++) lm = umin64(lm, key[u]);
  lmins[tid] = lm;
  __syncthreads();
  if (tid < 64) {
    unsigned long long qm = umin64(umin64(lmins[tid], lmins[tid + 64]),
                                   umin64(lmins[tid + 128], lmins[tid + 192]));
    qmins[tid] = qm;
    int rank = 0;
    for (int i = 0; i < 64; i++) rank += (qmins[i] < qm);
    if (rank == 31) thr = qm;
  }
  __syncthreads();
  unsigned long long T = thr;
#pragma unroll
  for (int u = 0; u < 8; u++) {
    if (key[u] <= T) {
      int p = atomicAdd(&scnt, 1);
      surv[p] = key[u];
    }
  }
  __syncthreads();
  int s = scnt;
  for (int i = tid; i < s; i += 256) {
    unsigned long long c = surv[i];
    int r = 0;
    for (int j2 = 0; j2 < s; j2++) r += (surv[j2] < c);
    if (r < 32) selidx[r] = (int)(c & 0xffffffffULL);
  }
  __syncthreads();
  if (tid < 64) {
    float acc = 0.f;
#pragma unroll 4
    for (int sI = 0; sI < 32; sI++)
      acc += G1[(size_t)(base + selidx[sI]) * 64 + tid];
    float v = acc * (1.0f / 32.0f);
    X1[(size_t)q * 64 + tid] = v;
    __hip_bfloat16 hi = (__hip_bfloat16)v;
    X1b[(size_t)q * 64 + tid] = hi;
    X1lo[(size_t)q * 64 + tid] = (__hip_bfloat16)(v - (float)hi);
    float nv = v * v;
#pragma unroll
    for (int off = 32; off > 0; off >>= 1) nv += __shfl_down(nv, off);
    if (tid == 0) nrmX1[q] = nv;
  }
}

// ---------------------------------------------------------------------------
// Ball-query pass 1 v6 — split-bf16 MFMA gram + exact-decision guard band.
// d2a = nq + nc - 2*S with S = sum(hi*hi + hi*lo + lo*hi) via 3 MFMAs.
// |d2a - d2_exact| <= ~1.5e-5*(nq+nc); band eps = 4e-5*(nq+nc)+1e-6.
// In-band pairs recomputed with the ORIGINAL ascending-k fp32 fma chain
// (bitwise-identical to the v4/v5 tile math) -> masks bit-identical.
// Symmetric tile-pairs as before. Mask assembly: per-lane bit-pack ->
// LDS atomicOr into c-major tile tw; direct (q-major) words derived by
// bit-transpose reads. NO min-occupancy bound (256,3 spilled: 10x).
// ---------------------------------------------------------------------------
template <int C>
__global__ __launch_bounds__(256) void ball_mask_mfma(
    const float* __restrict__ F32,
    const __hip_bfloat16* __restrict__ Fhi,
    const __hip_bfloat16* __restrict__ Flo,
    const float* __restrict__ nrm,
    unsigned long long* __restrict__ mask,
    float r2)
{
  __shared__ __align__(16) short Qh[128][40];
  __shared__ __align__(16) short Ql[128][40];
  __shared__ __align__(16) short Ch[128][40];
  __shared__ __align__(16) short Cl[128][40];
  __shared__ unsigned int tw[128][4];
  __shared__ float nqs[128], ncs[128];
  int tid = threadIdx.x;
  int p = blockIdx.x;
  int qt = 0;
  while (p >= 16 - qt) { p -= 16 - qt; qt++; }
  int ct = qt + p;
  int b0 = blockIdx.y << 11;
  int q0 = b0 + (qt << 7), c0 = b0 + (ct << 7);
  tw[tid >> 1][(tid & 1) * 2] = 0;
  tw[tid >> 1][(tid & 1) * 2 + 1] = 0;
  if (tid < 128) nqs[tid] = nrm[q0 + tid];
  else ncs[tid - 128] = nrm[c0 + tid - 128];

  int wave = tid >> 6, lane = tid & 63;
  int quad = lane >> 4, l16 = lane & 15;
  int wm = (wave >> 1) << 6, wn = (wave & 1) << 6;
  f32x4 acc[4][4] = {};
  const short* QH = (const short*)Fhi;
  const short* QL = (const short*)Flo;
  int srow = tid >> 2, sq = tid & 3;
  for (int k0 = 0; k0 < C; k0 += 32) {
#pragma unroll
    for (int h = 0; h < 2; h++) {
      int r = srow + (h << 6);
      *(uint4*)&Qh[r][sq * 8] = *(const uint4*)&QH[(size_t)(q0 + r) * C + k0 + sq * 8];
      *(uint4*)&Ql[r][sq * 8] = *(const uint4*)&QL[(size_t)(q0 + r) * C + k0 + sq * 8];
      *(uint4*)&Ch[r][sq * 8] = *(const uint4*)&QH[(size_t)(c0 + r) * C + k0 + sq * 8];
      *(uint4*)&Cl[r][sq * 8] = *(const uint4*)&QL[(size_t)(c0 + r) * C + k0 + sq * 8];
    }
    __syncthreads();
    short8 ah[4], al[4];
#pragma unroll
    for (int mi = 0; mi < 4; mi++) {
      ah[mi] = *(const short8*)&Qh[wm + mi * 16 + l16][quad * 8];
      al[mi] = *(const short8*)&Ql[wm + mi * 16 + l16][quad * 8];
    }
#pragma unroll
    for (int ni = 0; ni < 4; ni++) {
      short8 bh = *(const short8*)&Ch[wn + ni * 16 + l16][quad * 8];
      short8 bl = *(const short8*)&Cl[wn + ni * 16 + l16][quad * 8];
#pragma unroll
      for (int mi = 0; mi < 4; mi++) {
        acc[mi][ni] = __builtin_amdgcn_mfma_f32_16x16x32_bf16(ah[mi], bh, acc[mi][ni], 0, 0, 0);
        acc[mi][ni] = __builtin_amdgcn_mfma_f32_16x16x32_bf16(ah[mi], bl, acc[mi][ni], 0, 0, 0);
        acc[mi][ni] = __builtin_amdgcn_mfma_f32_16x16x32_bf16(al[mi], bh, acc[mi][ni], 0, 0, 0);
      }
    }
    __syncthreads();
  }
  // decide membership (approx + guard band with exact fallback)
  unsigned long long memb = 0, fb = 0;
#pragma unroll
  for (int mi = 0; mi < 4; mi++)
#pragma unroll
    for (int ni = 0; ni < 4; ni++)
#pragma unroll
      for (int r = 0; r < 4; r++) {
        int e = (mi << 4) | (ni << 2) | r;
        float nqv = nqs[wm + mi * 16 + quad * 4 + r];
        float ncv = ncs[wn + ni * 16 + l16];
        float d2a = nqv + ncv - 2.f * acc[mi][ni][r];
        float eps = 4.0e-5f * (nqv + ncv) + 1.0e-6f;
        if (d2a < r2 - eps) memb |= 1ull << e;
        else if (d2a <= r2 + eps) fb |= 1ull << e;
      }
  while (fb) {
    int e = __builtin_ctzll(fb);
    fb &= fb - 1;
    int mi = e >> 4, ni = (e >> 2) & 3, r = e & 3;
    int qrow = q0 + wm + mi * 16 + quad * 4 + r;
    int ccol = c0 + wn + ni * 16 + l16;
    float a2 = 0.f;
    for (int k = 0; k < C; k++) {
      float d = F32[(size_t)qrow * C + k] - F32[(size_t)ccol * C + k];
      a2 = fmaf(d, d, a2);
    }
    if (a2 <= r2) memb |= 1ull << e;
  }
  // pack bits into c-major tile tw[col][q-word]
#pragma unroll
  for (int ni = 0; ni < 4; ni++) {
    int cl = wn + ni * 16 + l16;
    unsigned int w0b = 0, w1b = 0;
#pragma unroll
    for (int mi = 0; mi < 4; mi++)
#pragma unroll
      for (int r = 0; r < 4; r++)
        if (memb & (1ull << ((mi << 4) | (ni << 2) | r))) {
          unsigned int bitpos = ((mi & 1) << 4) | (quad << 2) | r;
          if (mi < 2) w0b |= 1u << bitpos;
          else w1b |= 1u << bitpos;
        }
    if (w0b) atomicOr(&tw[cl][(wm >> 5)], w0b);
    if (w1b) atomicOr(&tw[cl][(wm >> 5) + 1], w1b);
  }
  __syncthreads();
  // direct (q-major) words via bit-transpose read of tw
  {
    int row = tid >> 1, half = tid & 1;
    int wq = row >> 5, sb = row & 31;
    unsigned int lo = 0, hi = 0;
    for (int j = 0; j < 32; j++) {
      lo |= ((tw[half * 64 + j][wq] >> sb) & 1u) << j;
      hi |= ((tw[half * 64 + 32 + j][wq] >> sb) & 1u) << j;
    }
    mask[(size_t)(q0 + row) * 32 + (ct << 1) + half] =
        ((unsigned long long)hi << 32) | lo;
  }
  if (qt != ct) {
    int row = tid >> 1, word = tid & 1;
    unsigned long long v = (unsigned long long)tw[row][word * 2] |
                           ((unsigned long long)tw[row][word * 2 + 1] << 32);
    mask[(size_t)(c0 + row) * 32 + (qt << 1) + word] = v;
  }
}

// ---------------------------------------------------------------------------
// Ball-query pass 2 (templated input dtype; fp32 accumulate). Optional
// hi/lo/norm emission for the fp32 output (gather2 -> X2 path).
// ---------------------------------------------------------------------------
template <typename TIn>
__global__ void ball_gather_kernel(
    const unsigned long long* __restrict__ mask,
    const TIn* __restrict__ H, int CH,
    float* __restrict__ Yf, __hip_bfloat16* __restrict__ Yb,
    __hip_bfloat16* __restrict__ Ylo, float* __restrict__ nrm,
    int ldy, int S)
{
  int q = blockIdx.x;
  int base = q & ~2047;
  int tid = threadIdx.x;
  __shared__ int idxl[64];
  __shared__ float wtab[64];
  __shared__ float npart[4];
  __shared__ int scount;
  if (tid < 32) {
    unsigned long long w = mask[(size_t)q * 32 + tid];
    int cnt = __popcll(w);
    int inc = cnt;
#pragma unroll
    for (int off = 1; off < 32; off <<= 1) {
      int o = __shfl_up(inc, off);
      if (tid >= off) inc += o;
    }
    if (tid == 31) scount = inc;
    int p = inc - cnt;
    while (w && p < 64) {
      int j = (tid << 6) + __builtin_ctzll(w);
      w &= w - 1;
      idxl[p++] = j;
    }
  }
  __syncthreads();
  int c = scount;
  if (tid < 64) {
    int p = tid;
    int cnt = (p < c && p < S) ? ((S - 1 - p) / c + 1) : 0;
    wtab[p] = (float)cnt / (float)S;
  }
  __syncthreads();
  float acc = 0.f;
  int lim = c < S ? c : S;
#pragma unroll 4
  for (int s = 0; s < lim; s++)
    acc += wtab[s] * (float)H[(size_t)(base + idxl[s]) * CH + tid];
  if (Yf) Yf[(size_t)q * ldy + tid] = acc;
  if (Yb) Yb[(size_t)q * ldy + tid] = (__hip_bfloat16)acc;
  if (Ylo) {
    __hip_bfloat16 hi = (__hip_bfloat16)acc;
    Ylo[(size_t)q * ldy + tid] = (__hip_bfloat16)(acc - (float)hi);
  }
  if (nrm) {
    float nv = acc * acc;
#pragma unroll
    for (int off = 32; off > 0; off >>= 1) nv += __shfl_down(nv, off);
    if ((tid & 63) == 0) npart[tid >> 6] = nv;
    __syncthreads();
    if (tid == 0) {
      float t = 0.f;
      for (int w = 0; w < (blockDim.x >> 6); w++) t += npart[w];
      nrm[q] = t;
    }
  }
}

// ---------------------------------------------------------------------------
extern "C" void kernel_launch(void* const* d_in, const int* in_sizes, int n_in,
                              void* d_out, int out_size, void* d_ws,
                              size_t ws_size, hipStream_t stream)
{
  const float* x      = (const float*)d_in[0];
  const float* sa1_w0 = (const float*)d_in[1];
  const float* sa1_b0 = (const float*)d_in[2];
  const float* sa1_w1 = (const float*)d_in[3];
  const float* sa1_b1 = (const float*)d_in[4];
  const float* sa2_w0 = (const float*)d_in[5];
  const float* sa2_b0 = (const float*)d_in[6];
  const float* sa2_w1 = (const float*)d_in[7];
  const float* sa2_b1 = (const float*)d_in[8];
  const float* sa3_w0 = (const float*)d_in[9];
  const float* sa3_b0 = (const float*)d_in[10];
  const float* sa3_w1 = (const float*)d_in[11];
  const float* sa3_b1 = (const float*)d_in[12];
  const float* fp1_w0 = (const float*)d_in[13];
  const float* fp1_b0 = (const float*)d_in[14];
  const float* fp1_w1 = (const float*)d_in[15];
  const float* fp1_b1 = (const float*)d_in[16];
  const float* fp2_w0 = (const float*)d_in[17];
  const float* fp2_b0 = (const float*)d_in[18];
  const float* fp2_w1 = (const float*)d_in[19];
  const float* fp2_b1 = (const float*)d_in[20];
  const float* fc1_w  = (const float*)d_in[21];
  const float* fc1_b  = (const float*)d_in[22];
  const float* fc2_w  = (const float*)d_in[23];
  const float* fc2_b  = (const float*)d_in[24];
  const float* out_w  = (const float*)d_in[25];
  const float* out_b  = (const float*)d_in[26];
  float* out = (float*)d_out;

  const size_t M = M_ROWS;
  float* ws = (float*)d_ws;
  float* T   = ws;             // [0,256)
  float* G1  = ws + M * 256;   // [256,320)
  float* X1  = ws + M * 320;   // [320,384)
  float* X2  = ws + M * 384;   // [384,512)
  float* H2  = ws + M * 512;   // [512,640)
  __hip_bfloat16* H3b16 = (__hip_bfloat16*)(ws + M * 640);  // [640,768)
  unsigned long long* MASK = (unsigned long long*)(ws + M * 896);  // [896,960)
  __hip_bfloat16* X1b = (__hip_bfloat16*)(ws + M * 960);    // [960,992)
  __hip_bfloat16* X2b = (__hip_bfloat16*)(ws + M * 992);    // [992,1056)
  __hip_bfloat16* TB0 = (__hip_bfloat16*)(ws + M * 1056);   // [1056,1184)
  __hip_bfloat16* TB1 = (__hip_bfloat16*)(ws + M * 1184);   // [1184,1440)
  __hip_bfloat16* TB2 = (__hip_bfloat16*)(ws + M * 1440);   // [1440,1568)
  __hip_bfloat16* G   = (__hip_bfloat16*)(ws + M * 1568);   // [1568,2080)
  __hip_bfloat16* H3b = (__hip_bfloat16*)(ws + M * 2080);   // [2080,2208)
  __hip_bfloat16* WB  = (__hip_bfloat16*)(ws + M * 2208);   // weights
  __hip_bfloat16* X1lo = (__hip_bfloat16*)(ws + M * 2240);  // [2240,2272)
  __hip_bfloat16* X2lo = (__hip_bfloat16*)(ws + M * 2272);  // [2272,2336)
  float* nrmX1 = ws + M * 2336;                             // [2336,2337)
  float* nrmX2 = ws + M * 2337;                             // [2337,2338)
  if (ws_size < (size_t)M * 2340 * sizeof(float)) return;   // <= proven 159MB
  __hip_bfloat16* w_sa3_0 = WB;               // 256x128
  __hip_bfloat16* w_sa3_1 = w_sa3_0 + 32768;  // 256x256
  __hip_bfloat16* w_fp1_0 = w_sa3_1 + 65536;  // 512x128
  __hip_bfloat16* w_fp1_1 = w_fp1_0 + 65536;  // 512x512
  __hip_bfloat16* w_fp2_0 = w_fp1_1 + 262144; // 256x64
  __hip_bfloat16* w_fp2_1 = w_fp2_0 + 16384;  // 256x256
  __hip_bfloat16* w_fc1   = w_fp2_1 + 65536;  // 256x1024
  __hip_bfloat16* w_fc2   = w_fc1 + 262144;   // 128x256

  dim3 blk(256);
  TJobs jb;
  const float* srcs[8] = {sa3_w0, sa3_w1, fp1_w0, fp1_w1, fp2_w0, fp2_w1, fc1_w, fc2_w};
  __hip_bfloat16* dsts[8] = {w_sa3_0, w_sa3_1, w_fp1_0, w_fp1_1, w_fp2_0, w_fp2_1, w_fc1, w_fc2};
  int Ks[8] = {128, 256, 128, 512, 64, 256, 1024, 256};
  int Ns[8] = {256, 256, 512, 512, 256, 256, 256, 128};
  int off = 0;
  for (int i = 0; i < 8; i++) {
    jb.W[i] = srcs[i]; jb.Wt[i] = dsts[i];
    jb.K[i] = Ks[i]; jb.N[i] = Ns[i];
    jb.bx[i] = Ns[i] >> 5;
    jb.off[i] = off;
    off += (Ns[i] >> 5) * (Ks[i] >> 5);
  }
  transpose_cast_all<<<off, blk, 0, stream>>>(jb);

  // SA1 (fp32 exact) + knn (emits X1, X1b=hi, X1lo, nrmX1).
  gemm_bias_relu<<<dim3(1, 256), blk, 0, stream>>>(x, 2, sa1_w0, sa1_b0, T, 64, 64, 2);
  gemm_bias_relu<<<dim3(1, 256), blk, 0, stream>>>(T, 64, sa1_w1, sa1_b1, G1, 64, 64, 64);
  knn_mean_kernel<<<16384, 256, 0, stream>>>(x, G1, X1, X1b, X1lo, nrmX1);
  // SA2 (fp32 exact) + ball64 (MFMA gram) + gather2 (emits X2 hi/lo/norm).
  gemm_bias_relu<<<dim3(2, 256), blk, 0, stream>>>(X1, 64, sa2_w0, sa2_b0, T, 128, 128, 64);
  gemm_bias_relu<<<dim3(2, 256), blk, 0, stream>>>(T, 128, sa2_w1, sa2_b1, H2, 128, 128, 128);
  ball_mask_mfma<64><<<dim3(136, 8), blk, 0, stream>>>(X1, X1b, X1lo, nrmX1, MASK, 0.2f * 0.2f);
  ball_gather_kernel<float><<<16384, 128, 0, stream>>>(MASK, H2, 128, X2, X2b, X2lo, nrmX2, 128, 32);
  // ball128 (MFMA gram), then the fused layer-1 and layer-2 GEMM triples.
  ball_mask_mfma<128><<<dim3(136, 8), blk, 0, stream>>>(X2, X2b, X2lo, nrmX2, MASK, 0.4f * 0.4f);
  {
    GJobs g1;
    g1.A[0] = (const short*)X2b; g1.W[0] = (const short*)w_sa3_0; g1.bias[0] = sa3_b0;
    g1.Y[0] = TB0; g1.lda[0] = 128; g1.ldw[0] = 128; g1.ldy[0] = 256; g1.N[0] = 256; g1.K[0] = 128;
    g1.A[1] = (const short*)X2b; g1.W[1] = (const short*)w_fp1_0; g1.bias[1] = fp1_b0;
    g1.Y[1] = TB1; g1.lda[1] = 128; g1.ldw[1] = 128; g1.ldy[1] = 512; g1.N[1] = 512; g1.K[1] = 128;
    g1.A[2] = (const short*)X1b; g1.W[2] = (const short*)w_fp2_0; g1.bias[2] = fp2_b0;
    g1.Y[2] = TB2; g1.lda[2] = 64; g1.ldw[2] = 64; g1.ldy[2] = 256; g1.N[2] = 256; g1.K[2] = 64;
    int tot1 = 0;
    for (int i = 0; i < 3; i++) {
      g1.xt[i] = g1.N[i] >> 7;
      g1.off[i] = tot1;
      tot1 += g1.xt[i] * 128;
    }
    gemm_mfma_multi<<<tot1, blk, 0, stream>>>(g1);

    GJobs g2;
    g2.A[0] = (const short*)TB0; g2.W[0] = (const short*)w_sa3_1; g2.bias[0] = sa3_b1;
    g2.Y[0] = H3b16; g2.lda[0] = 256; g2.ldw[0] = 256; g2.ldy[0] = 256; g2.N[0] = 256; g2.K[0] = 256;
    g2.A[1] = (const short*)TB1; g2.W[1] = (const short*)w_fp1_1; g2.bias[1] = fp1_b1;
    g2.Y[1] = G + 256; g2.lda[1] = 512; g2.ldw[1] = 512; g2.ldy[1] = 1024; g2.N[1] = 512; g2.K[1] = 512;
    g2.A[2] = (const short*)TB2; g2.W[2] = (const short*)w_fp2_1; g2.bias[2] = fp2_b1;
    g2.Y[2] = G; g2.lda[2] = 256; g2.ldw[2] = 256; g2.ldy[2] = 1024; g2.N[2] = 256; g2.K[2] = 256;
    int tot2 = 0;
    for (int i = 0; i < 3; i++) {
      g2.xt[i] = g2.N[i] >> 7;
      g2.off[i] = tot2;
      tot2 += g2.xt[i] * 128;
    }
    gemm_mfma_multi<<<tot2, blk, 0, stream>>>(g2);
  }
  // gather3 fills G[768:1024] from sa3 output (no hi/lo/norm emission).
  ball_gather_kernel<__hip_bfloat16><<<16384, 256, 0, stream>>>(
      MASK, H3b16, 256, nullptr, G + 768, nullptr, nullptr, 1024, 64);
  // Head: fc1 (bf16), then fc2+out fused.
  gemm_mfma<true><<<dim3(2, 128), blk, 0, stream>>>(G, 1024, w_fc1, 1024, fc1_b, H3b, 256, 256, 1024);
  gemm_fc2_out<<<dim3(1, 128), blk, 0, stream>>>(H3b, w_fc2, fc2_b, out_w, out_b, out);
}

// Round 13
// 391.068 us; speedup vs baseline: 1.2573x; 1.0296x over previous
//
#include <hip/hip_runtime.h>
#include <hip/hip_bf16.h>
#include <cstdint>

#define M_ROWS 16384

typedef __attribute__((ext_vector_type(8))) short short8;
typedef __attribute__((ext_vector_type(4))) float f32x4;

__device__ __forceinline__ unsigned long long umin64(unsigned long long a,
                                                     unsigned long long b) {
  return a < b ? a : b;
}

// ---------------------------------------------------------------------------
// fp32 GEMM (SA1/SA2 — feeds masks, bit-identical path).
// ---------------------------------------------------------------------------
__global__ __launch_bounds__(256) void gemm_bias_relu(
    const float* __restrict__ X, int ldx,
    const float* __restrict__ W,
    const float* __restrict__ bias,
    float* __restrict__ Y, int ldy,
    int N, int K)
{
  __shared__ __align__(16) float As[16][68];
  __shared__ __align__(16) float Bs[16][68];
  int tid = threadIdx.x;
  int tx = tid & 15, ty = tid >> 4;
  int m0 = blockIdx.y << 6, n0 = blockIdx.x << 6;
  float acc[4][4] = {};
  for (int k0 = 0; k0 < K; k0 += 16) {
#pragma unroll
    for (int i = 0; i < 4; i++) {
      int idx = tid + (i << 8);
      int m = idx >> 4, k = idx & 15;
      As[k][m] = (k0 + k < K) ? X[(size_t)(m0 + m) * ldx + k0 + k] : 0.f;
    }
#pragma unroll
    for (int i = 0; i < 4; i++) {
      int idx = tid + (i << 8);
      int n = idx & 63, k = idx >> 6;
      Bs[k][n] = (k0 + k < K) ? W[(size_t)(k0 + k) * N + n0 + n] : 0.f;
    }
    __syncthreads();
#pragma unroll
    for (int k = 0; k < 16; k++) {
      float4 a4 = *(const float4*)&As[k][ty << 2];
      float4 b4 = *(const float4*)&Bs[k][tx << 2];
      float av[4] = {a4.x, a4.y, a4.z, a4.w};
      float bv[4] = {b4.x, b4.y, b4.z, b4.w};
#pragma unroll
      for (int i = 0; i < 4; i++)
#pragma unroll
        for (int j = 0; j < 4; j++)
          acc[i][j] += av[i] * bv[j];
    }
    __syncthreads();
  }
  float4 bb = *(const float4*)&bias[n0 + (tx << 2)];
  float bv[4] = {bb.x, bb.y, bb.z, bb.w};
#pragma unroll
  for (int i = 0; i < 4; i++) {
    int m = m0 + (ty << 2) + i;
    float4 o;
    o.x = fmaxf(acc[i][0] + bv[0], 0.f);
    o.y = fmaxf(acc[i][1] + bv[1], 0.f);
    o.z = fmaxf(acc[i][2] + bv[2], 0.f);
    o.w = fmaxf(acc[i][3] + bv[3], 0.f);
    *(float4*)&Y[(size_t)m * ldy + n0 + (tx << 2)] = o;
  }
}

// ---------------------------------------------------------------------------
// Fused weight prep: 8 transposes (W KxN fp32 -> Wt NxK bf16) in one dispatch.
// ---------------------------------------------------------------------------
struct TJobs {
  const float* W[8];
  __hip_bfloat16* Wt[8];
  int K[8], N[8], bx[8], off[8];
};

__global__ __launch_bounds__(256) void transpose_cast_all(TJobs jb)
{
  __shared__ float tile[32][33];
  int bid = blockIdx.x;
  int j = 0;
#pragma unroll
  for (int t = 1; t < 8; t++)
    if (bid >= jb.off[t]) j = t;
  int rel = bid - jb.off[j];
  int K = jb.K[j], N = jb.N[j];
  const float* W = jb.W[j];
  __hip_bfloat16* Wt = jb.Wt[j];
  int n0 = (rel % jb.bx[j]) << 5, k0 = (rel / jb.bx[j]) << 5;
  int c = threadIdx.x & 31, i0 = threadIdx.x >> 5;
#pragma unroll
  for (int p = 0; p < 4; p++) {
    int i = i0 + p * 8;
    tile[i][c] = W[(size_t)(k0 + i) * N + n0 + c];
  }
  __syncthreads();
#pragma unroll
  for (int p = 0; p < 4; p++) {
    int r = i0 + p * 8;
    Wt[(size_t)(n0 + r) * K + k0 + c] = (__hip_bfloat16)tile[c][r];
  }
}

// ---------------------------------------------------------------------------
// bf16 MFMA GEMM (single-job; used for fc1).
// ---------------------------------------------------------------------------
template <bool OUT_BF16>
__global__ __launch_bounds__(256) void gemm_mfma(
    const __hip_bfloat16* __restrict__ A, int lda,
    const __hip_bfloat16* __restrict__ Wt, int ldw,
    const float* __restrict__ bias,
    void* __restrict__ Y, int ldy, int N, int K)
{
  __shared__ __align__(16) short As[128][40];
  __shared__ __align__(16) short Bs[128][40];
  int tid = threadIdx.x;
  int wave = tid >> 6, lane = tid & 63;
  int quad = lane >> 4, l16 = lane & 15;
  int m0 = blockIdx.y << 7, n0 = blockIdx.x << 7;
  int wm = (wave >> 1) << 6, wn = (wave & 1) << 6;
  f32x4 acc[4][4] = {};
  const short* Ag = (const short*)A;
  const short* Bg = (const short*)Wt;
  int srow = tid >> 2, sq = tid & 3;
  for (int k0 = 0; k0 < K; k0 += 32) {
#pragma unroll
    for (int h = 0; h < 2; h++) {
      int r = srow + (h << 6);
      uint4 va = *(const uint4*)&Ag[(size_t)(m0 + r) * lda + k0 + sq * 8];
      *(uint4*)&As[r][sq * 8] = va;
      uint4 vb = *(const uint4*)&Bg[(size_t)(n0 + r) * ldw + k0 + sq * 8];
      *(uint4*)&Bs[r][sq * 8] = vb;
    }
    __syncthreads();
    short8 a[4], b[4];
#pragma unroll
    for (int mi = 0; mi < 4; mi++)
      a[mi] = *(const short8*)&As[wm + mi * 16 + l16][quad * 8];
#pragma unroll
    for (int ni = 0; ni < 4; ni++)
      b[ni] = *(const short8*)&Bs[wn + ni * 16 + l16][quad * 8];
#pragma unroll
    for (int mi = 0; mi < 4; mi++)
#pragma unroll
      for (int ni = 0; ni < 4; ni++)
        acc[mi][ni] = __builtin_amdgcn_mfma_f32_16x16x32_bf16(
            a[mi], b[ni], acc[mi][ni], 0, 0, 0);
    __syncthreads();
  }
  float bn[4];
#pragma unroll
  for (int ni = 0; ni < 4; ni++) bn[ni] = bias[n0 + wn + ni * 16 + l16];
#pragma unroll
  for (int mi = 0; mi < 4; mi++)
#pragma unroll
    for (int ni = 0; ni < 4; ni++) {
      int n = n0 + wn + ni * 16 + l16;
#pragma unroll
      for (int r = 0; r < 4; r++) {
        int m = m0 + wm + mi * 16 + quad * 4 + r;
        float v = fmaxf(acc[mi][ni][r] + bn[ni], 0.f);
        if (OUT_BF16)
          ((__hip_bfloat16*)Y)[(size_t)m * ldy + n] = (__hip_bfloat16)v;
        else
          ((float*)Y)[(size_t)m * ldy + n] = v;
      }
    }
}

// ---------------------------------------------------------------------------
// Multi-job bf16 MFMA GEMM (bit-identical outputs; merges small dispatches).
// ---------------------------------------------------------------------------
struct GJobs {
  const short* A[3];
  const short* W[3];
  const float* bias[3];
  __hip_bfloat16* Y[3];
  int lda[3], ldw[3], ldy[3], N[3], K[3], xt[3], off[3];
};

__global__ __launch_bounds__(256) void gemm_mfma_multi(GJobs g)
{
  __shared__ __align__(16) short As[128][40];
  __shared__ __align__(16) short Bs[128][40];
  int bid = blockIdx.x;
  int j = 0;
#pragma unroll
  for (int t = 1; t < 3; t++)
    if (bid >= g.off[t]) j = t;
  int rel = bid - g.off[j];
  int xt = g.xt[j];
  int m0 = (rel / xt) << 7, n0 = (rel % xt) << 7;
  int lda = g.lda[j], ldw = g.ldw[j], ldy = g.ldy[j], K = g.K[j];
  const short* Ag = g.A[j];
  const short* Bg = g.W[j];
  const float* bias = g.bias[j];
  __hip_bfloat16* Y = g.Y[j];

  int tid = threadIdx.x;
  int wave = tid >> 6, lane = tid & 63;
  int quad = lane >> 4, l16 = lane & 15;
  int wm = (wave >> 1) << 6, wn = (wave & 1) << 6;
  f32x4 acc[4][4] = {};
  int srow = tid >> 2, sq = tid & 3;
  for (int k0 = 0; k0 < K; k0 += 32) {
#pragma unroll
    for (int h = 0; h < 2; h++) {
      int r = srow + (h << 6);
      uint4 va = *(const uint4*)&Ag[(size_t)(m0 + r) * lda + k0 + sq * 8];
      *(uint4*)&As[r][sq * 8] = va;
      uint4 vb = *(const uint4*)&Bg[(size_t)(n0 + r) * ldw + k0 + sq * 8];
      *(uint4*)&Bs[r][sq * 8] = vb;
    }
    __syncthreads();
    short8 a[4], b[4];
#pragma unroll
    for (int mi = 0; mi < 4; mi++)
      a[mi] = *(const short8*)&As[wm + mi * 16 + l16][quad * 8];
#pragma unroll
    for (int ni = 0; ni < 4; ni++)
      b[ni] = *(const short8*)&Bs[wn + ni * 16 + l16][quad * 8];
#pragma unroll
    for (int mi = 0; mi < 4; mi++)
#pragma unroll
      for (int ni = 0; ni < 4; ni++)
        acc[mi][ni] = __builtin_amdgcn_mfma_f32_16x16x32_bf16(
            a[mi], b[ni], acc[mi][ni], 0, 0, 0);
    __syncthreads();
  }
  float bn[4];
#pragma unroll
  for (int ni = 0; ni < 4; ni++) bn[ni] = bias[n0 + wn + ni * 16 + l16];
#pragma unroll
  for (int mi = 0; mi < 4; mi++)
#pragma unroll
    for (int ni = 0; ni < 4; ni++) {
      int n = n0 + wn + ni * 16 + l16;
#pragma unroll
      for (int r = 0; r < 4; r++) {
        int m = m0 + wm + mi * 16 + quad * 4 + r;
        float v = fmaxf(acc[mi][ni][r] + bn[ni], 0.f);
        Y[(size_t)m * ldy + n] = (__hip_bfloat16)v;
      }
    }
}

// ---------------------------------------------------------------------------
// fc2 + out head fused.
// ---------------------------------------------------------------------------
__global__ __launch_bounds__(256) void gemm_fc2_out(
    const __hip_bfloat16* __restrict__ A,
    const __hip_bfloat16* __restrict__ Wt,
    const float* __restrict__ bias,
    const float* __restrict__ wout,
    const float* __restrict__ bout,
    float* __restrict__ out)
{
  __shared__ __align__(16) short As[128][40];
  __shared__ __align__(16) short Bs[128][40];
  __shared__ float red[128][2];
  const int N = 128, K = 256, lda = 256, ldw = 256;
  int tid = threadIdx.x;
  int wave = tid >> 6, lane = tid & 63;
  int quad = lane >> 4, l16 = lane & 15;
  int m0 = blockIdx.y << 7;
  int wm = (wave >> 1) << 6, wn = (wave & 1) << 6;
  f32x4 acc[4][4] = {};
  const short* Ag = (const short*)A;
  const short* Bg = (const short*)Wt;
  int srow = tid >> 2, sq = tid & 3;
  for (int k0 = 0; k0 < K; k0 += 32) {
#pragma unroll
    for (int h = 0; h < 2; h++) {
      int r = srow + (h << 6);
      uint4 va = *(const uint4*)&Ag[(size_t)(m0 + r) * lda + k0 + sq * 8];
      *(uint4*)&As[r][sq * 8] = va;
      uint4 vb = *(const uint4*)&Bg[(size_t)(r % N) * ldw + k0 + sq * 8];
      *(uint4*)&Bs[r][sq * 8] = vb;
    }
    __syncthreads();
    short8 a[4], b[4];
#pragma unroll
    for (int mi = 0; mi < 4; mi++)
      a[mi] = *(const short8*)&As[wm + mi * 16 + l16][quad * 8];
#pragma unroll
    for (int ni = 0; ni < 4; ni++)
      b[ni] = *(const short8*)&Bs[wn + ni * 16 + l16][quad * 8];
#pragma unroll
    for (int mi = 0; mi < 4; mi++)
#pragma unroll
      for (int ni = 0; ni < 4; ni++)
        acc[mi][ni] = __builtin_amdgcn_mfma_f32_16x16x32_bf16(
            a[mi], b[ni], acc[mi][ni], 0, 0, 0);
    __syncthreads();
  }
  float bn[4], wo[4];
#pragma unroll
  for (int ni = 0; ni < 4; ni++) {
    int n = wn + ni * 16 + l16;
    bn[ni] = bias[n];
    wo[ni] = wout[n];
  }
  float sacc[4][4];
#pragma unroll
  for (int mi = 0; mi < 4; mi++)
#pragma unroll
    for (int r = 0; r < 4; r++) {
      float s = 0.f;
#pragma unroll
      for (int ni = 0; ni < 4; ni++)
        s += fmaxf(acc[mi][ni][r] + bn[ni], 0.f) * wo[ni];
      sacc[mi][r] = s;
    }
#pragma unroll
  for (int off = 1; off < 16; off <<= 1)
#pragma unroll
    for (int mi = 0; mi < 4; mi++)
#pragma unroll
      for (int r = 0; r < 4; r++)
        sacc[mi][r] += __shfl_xor(sacc[mi][r], off);
  int wp = wave & 1;
  if (l16 == 0) {
#pragma unroll
    for (int mi = 0; mi < 4; mi++)
#pragma unroll
      for (int r = 0; r < 4; r++)
        red[wm + mi * 16 + quad * 4 + r][wp] = sacc[mi][r];
  }
  __syncthreads();
  if (tid < 128) {
    float s = red[tid][0] + red[tid][1] + bout[0];
    out[(size_t)(m0 + tid)] = 1.f / (1.f + expf(-s));
  }
}

// ---------------------------------------------------------------------------
// SA1 KNN v7 — 4 queries per block. Same thread->candidate mapping, same
// quad grouping (j == t mod 64) -> same threshold T -> same survivor set ->
// bit-identical selection vs v5. All 32 keys kept in registers (no
// recompute hazard). Rank phase: wave g ranks query g (4x parallel).
// Survivor+merge per query over a SHARED 2048-entry buffer (worst-case
// safe). Gather: wave g does query g's 64 channels, ascending-s exact.
// ---------------------------------------------------------------------------
__global__ __launch_bounds__(256) void knn_mean4(
    const float* __restrict__ X,
    const float* __restrict__ G1,
    float* __restrict__ X1,
    __hip_bfloat16* __restrict__ X1b,
    __hip_bfloat16* __restrict__ X1lo,
    float* __restrict__ nrmX1)
{
  int qb = blockIdx.x << 2;
  int base = qb & ~2047;
  int tid = threadIdx.x;
  int wave = tid >> 6, lane = tid & 63;
  __shared__ unsigned long long lmins[4][256];
  __shared__ unsigned long long qmins[4][64];
  __shared__ unsigned long long thr[4];
  __shared__ unsigned long long surv[2048];
  __shared__ int scnt;
  __shared__ int selidx[4][32];
  float xj[8], yj[8];
#pragma unroll
  for (int u = 0; u < 8; u++) {
    int j = (u << 8) + tid;
    float2 c = *(const float2*)&X[(size_t)(base + j) * 2];
    xj[u] = c.x;
    yj[u] = c.y;
  }
  unsigned long long key[4][8];
#pragma unroll
  for (int g = 0; g < 4; g++) {
    float qx = X[(size_t)(qb + g) * 2];
    float qy = X[(size_t)(qb + g) * 2 + 1];
    unsigned long long lm = ~0ull;
#pragma unroll
    for (int u = 0; u < 8; u++) {
      float dx = xj[u] - qx;
      float dy = yj[u] - qy;
      float d2 = dx * dx + dy * dy;
      key[g][u] = ((unsigned long long)__float_as_uint(d2) << 32) |
                  (unsigned)((u << 8) + tid);
      lm = umin64(lm, key[g][u]);
    }
    lmins[g][tid] = lm;
  }
  __syncthreads();
  {
    int g = wave;
    unsigned long long qm =
        umin64(umin64(lmins[g][lane], lmins[g][lane + 64]),
               umin64(lmins[g][lane + 128], lmins[g][lane + 192]));
    qmins[g][lane] = qm;
    int rank = 0;
    for (int i = 0; i < 64; i++) rank += (qmins[g][i] < qm);
    if (rank == 31) thr[g] = qm;  // exactly one lane (unique keys)
  }
  __syncthreads();
  for (int g = 0; g < 4; g++) {
    if (tid == 0) scnt = 0;
    __syncthreads();
    unsigned long long T = thr[g];
#pragma unroll
    for (int u = 0; u < 8; u++) {
      if (key[g][u] <= T) {
        int p = atomicAdd(&scnt, 1);
        surv[p] = key[g][u];
      }
    }
    __syncthreads();
    int s = scnt;  // >= 32 guaranteed (argmin quads contribute 32 keys <= T)
    for (int i = tid; i < s; i += 256) {
      unsigned long long c = surv[i];
      int r = 0;
      for (int j2 = 0; j2 < s; j2++) r += (surv[j2] < c);
      if (r < 32) selidx[g][r] = (int)(c & 0xffffffffULL);
    }
    __syncthreads();
  }
  {
    int g = wave;
    float acc = 0.f;
#pragma unroll 4
    for (int sI = 0; sI < 32; sI++)
      acc += G1[(size_t)(base + selidx[g][sI]) * 64 + lane];
    float v = acc * (1.0f / 32.0f);
    int q = qb + g;
    X1[(size_t)q * 64 + lane] = v;
    __hip_bfloat16 hi = (__hip_bfloat16)v;
    X1b[(size_t)q * 64 + lane] = hi;
    X1lo[(size_t)q * 64 + lane] = (__hip_bfloat16)(v - (float)hi);
    float nv = v * v;
#pragma unroll
    for (int off = 32; off > 0; off >>= 1) nv += __shfl_down(nv, off);
    if (lane == 0) nrmX1[q] = nv;
  }
}

// ---------------------------------------------------------------------------
// Ball-query pass 1 v6 — split-bf16 MFMA gram + exact-decision guard band
// (round-12 version, passing; masks bit-identical).
// ---------------------------------------------------------------------------
template <int C>
__global__ __launch_bounds__(256) void ball_mask_mfma(
    const float* __restrict__ F32,
    const __hip_bfloat16* __restrict__ Fhi,
    const __hip_bfloat16* __restrict__ Flo,
    const float* __restrict__ nrm,
    unsigned long long* __restrict__ mask,
    float r2)
{
  __shared__ __align__(16) short Qh[128][40];
  __shared__ __align__(16) short Ql[128][40];
  __shared__ __align__(16) short Ch[128][40];
  __shared__ __align__(16) short Cl[128][40];
  __shared__ unsigned int tw[128][4];
  __shared__ float nqs[128], ncs[128];
  int tid = threadIdx.x;
  int p = blockIdx.x;
  int qt = 0;
  while (p >= 16 - qt) { p -= 16 - qt; qt++; }
  int ct = qt + p;
  int b0 = blockIdx.y << 11;
  int q0 = b0 + (qt << 7), c0 = b0 + (ct << 7);
  tw[tid >> 1][(tid & 1) * 2] = 0;
  tw[tid >> 1][(tid & 1) * 2 + 1] = 0;
  if (tid < 128) nqs[tid] = nrm[q0 + tid];
  else ncs[tid - 128] = nrm[c0 + tid - 128];

  int wave = tid >> 6, lane = tid & 63;
  int quad = lane >> 4, l16 = lane & 15;
  int wm = (wave >> 1) << 6, wn = (wave & 1) << 6;
  f32x4 acc[4][4] = {};
  const short* QH = (const short*)Fhi;
  const short* QL = (const short*)Flo;
  int srow = tid >> 2, sq = tid & 3;
  for (int k0 = 0; k0 < C; k0 += 32) {
#pragma unroll
    for (int h = 0; h < 2; h++) {
      int r = srow + (h << 6);
      *(uint4*)&Qh[r][sq * 8] = *(const uint4*)&QH[(size_t)(q0 + r) * C + k0 + sq * 8];
      *(uint4*)&Ql[r][sq * 8] = *(const uint4*)&QL[(size_t)(q0 + r) * C + k0 + sq * 8];
      *(uint4*)&Ch[r][sq * 8] = *(const uint4*)&QH[(size_t)(c0 + r) * C + k0 + sq * 8];
      *(uint4*)&Cl[r][sq * 8] = *(const uint4*)&QL[(size_t)(c0 + r) * C + k0 + sq * 8];
    }
    __syncthreads();
    short8 ah[4], al[4];
#pragma unroll
    for (int mi = 0; mi < 4; mi++) {
      ah[mi] = *(const short8*)&Qh[wm + mi * 16 + l16][quad * 8];
      al[mi] = *(const short8*)&Ql[wm + mi * 16 + l16][quad * 8];
    }
#pragma unroll
    for (int ni = 0; ni < 4; ni++) {
      short8 bh = *(const short8*)&Ch[wn + ni * 16 + l16][quad * 8];
      short8 bl = *(const short8*)&Cl[wn + ni * 16 + l16][quad * 8];
#pragma unroll
      for (int mi = 0; mi < 4; mi++) {
        acc[mi][ni] = __builtin_amdgcn_mfma_f32_16x16x32_bf16(ah[mi], bh, acc[mi][ni], 0, 0, 0);
        acc[mi][ni] = __builtin_amdgcn_mfma_f32_16x16x32_bf16(ah[mi], bl, acc[mi][ni], 0, 0, 0);
        acc[mi][ni] = __builtin_amdgcn_mfma_f32_16x16x32_bf16(al[mi], bh, acc[mi][ni], 0, 0, 0);
      }
    }
    __syncthreads();
  }
  unsigned long long memb = 0, fb = 0;
#pragma unroll
  for (int mi = 0; mi < 4; mi++)
#pragma unroll
    for (int ni = 0; ni < 4; ni++)
#pragma unroll
      for (int r = 0; r < 4; r++) {
        int e = (mi << 4) | (ni << 2) | r;
        float nqv = nqs[wm + mi * 16 + quad * 4 + r];
        float ncv = ncs[wn + ni * 16 + l16];
        float d2a = nqv + ncv - 2.f * acc[mi][ni][r];
        float eps = 4.0e-5f * (nqv + ncv) + 1.0e-6f;
        if (d2a < r2 - eps) memb |= 1ull << e;
        else if (d2a <= r2 + eps) fb |= 1ull << e;
      }
  while (fb) {
    int e = __builtin_ctzll(fb);
    fb &= fb - 1;
    int mi = e >> 4, ni = (e >> 2) & 3, r = e & 3;
    int qrow = q0 + wm + mi * 16 + quad * 4 + r;
    int ccol = c0 + wn + ni * 16 + l16;
    float a2 = 0.f;
    for (int k = 0; k < C; k++) {
      float d = F32[(size_t)qrow * C + k] - F32[(size_t)ccol * C + k];
      a2 = fmaf(d, d, a2);
    }
    if (a2 <= r2) memb |= 1ull << e;
  }
#pragma unroll
  for (int ni = 0; ni < 4; ni++) {
    int cl = wn + ni * 16 + l16;
    unsigned int w0b = 0, w1b = 0;
#pragma unroll
    for (int mi = 0; mi < 4; mi++)
#pragma unroll
      for (int r = 0; r < 4; r++)
        if (memb & (1ull << ((mi << 4) | (ni << 2) | r))) {
          unsigned int bitpos = ((mi & 1) << 4) | (quad << 2) | r;
          if (mi < 2) w0b |= 1u << bitpos;
          else w1b |= 1u << bitpos;
        }
    if (w0b) atomicOr(&tw[cl][(wm >> 5)], w0b);
    if (w1b) atomicOr(&tw[cl][(wm >> 5) + 1], w1b);
  }
  __syncthreads();
  {
    int row = tid >> 1, half = tid & 1;
    int wq = row >> 5, sb = row & 31;
    unsigned int lo = 0, hi = 0;
    for (int j = 0; j < 32; j++) {
      lo |= ((tw[half * 64 + j][wq] >> sb) & 1u) << j;
      hi |= ((tw[half * 64 + 32 + j][wq] >> sb) & 1u) << j;
    }
    mask[(size_t)(q0 + row) * 32 + (ct << 1) + half] =
        ((unsigned long long)hi << 32) | lo;
  }
  if (qt != ct) {
    int row = tid >> 1, word = tid & 1;
    unsigned long long v = (unsigned long long)tw[row][word * 2] |
                           ((unsigned long long)tw[row][word * 2 + 1] << 32);
    mask[(size_t)(c0 + row) * 32 + (qt << 1) + word] = v;
  }
}

// ---------------------------------------------------------------------------
// Ball-query pass 2 (templated input dtype; fp32 accumulate; unroll 8).
// ---------------------------------------------------------------------------
template <typename TIn>
__global__ void ball_gather_kernel(
    const unsigned long long* __restrict__ mask,
    const TIn* __restrict__ H, int CH,
    float* __restrict__ Yf, __hip_bfloat16* __restrict__ Yb,
    __hip_bfloat16* __restrict__ Ylo, float* __restrict__ nrm,
    int ldy, int S)
{
  int q = blockIdx.x;
  int base = q & ~2047;
  int tid = threadIdx.x;
  __shared__ int idxl[64];
  __shared__ float wtab[64];
  __shared__ float npart[4];
  __shared__ int scount;
  if (tid < 32) {
    unsigned long long w = mask[(size_t)q * 32 + tid];
    int cnt = __popcll(w);
    int inc = cnt;
#pragma unroll
    for (int off = 1; off < 32; off <<= 1) {
      int o = __shfl_up(inc, off);
      if (tid >= off) inc += o;
    }
    if (tid == 31) scount = inc;
    int p = inc - cnt;
    while (w && p < 64) {
      int j = (tid << 6) + __builtin_ctzll(w);
      w &= w - 1;
      idxl[p++] = j;
    }
  }
  __syncthreads();
  int c = scount;
  if (tid < 64) {
    int p = tid;
    int cnt = (p < c && p < S) ? ((S - 1 - p) / c + 1) : 0;
    wtab[p] = (float)cnt / (float)S;
  }
  __syncthreads();
  float acc = 0.f;
  int lim = c < S ? c : S;
#pragma unroll 8
  for (int s = 0; s < lim; s++)
    acc += wtab[s] * (float)H[(size_t)(base + idxl[s]) * CH + tid];
  if (Yf) Yf[(size_t)q * ldy + tid] = acc;
  if (Yb) Yb[(size_t)q * ldy + tid] = (__hip_bfloat16)acc;
  if (Ylo) {
    __hip_bfloat16 hi = (__hip_bfloat16)acc;
    Ylo[(size_t)q * ldy + tid] = (__hip_bfloat16)(acc - (float)hi);
  }
  if (nrm) {
    float nv = acc * acc;
#pragma unroll
    for (int off = 32; off > 0; off >>= 1) nv += __shfl_down(nv, off);
    if ((tid & 63) == 0) npart[tid >> 6] = nv;
    __syncthreads();
    if (tid == 0) {
      float t = 0.f;
      for (int w = 0; w < (blockDim.x >> 6); w++) t += npart[w];
      nrm[q] = t;
    }
  }
}

// ---------------------------------------------------------------------------
extern "C" void kernel_launch(void* const* d_in, const int* in_sizes, int n_in,
                              void* d_out, int out_size, void* d_ws,
                              size_t ws_size, hipStream_t stream)
{
  const float* x      = (const float*)d_in[0];
  const float* sa1_w0 = (const float*)d_in[1];
  const float* sa1_b0 = (const float*)d_in[2];
  const float* sa1_w1 = (const float*)d_in[3];
  const float* sa1_b1 = (const float*)d_in[4];
  const float* sa2_w0 = (const float*)d_in[5];
  const float* sa2_b0 = (const float*)d_in[6];
  const float* sa2_w1 = (const float*)d_in[7];
  const float* sa2_b1 = (const float*)d_in[8];
  const float* sa3_w0 = (const float*)d_in[9];
  const float* sa3_b0 = (const float*)d_in[10];
  const float* sa3_w1 = (const float*)d_in[11];
  const float* sa3_b1 = (const float*)d_in[12];
  const float* fp1_w0 = (const float*)d_in[13];
  const float* fp1_b0 = (const float*)d_in[14];
  const float* fp1_w1 = (const float*)d_in[15];
  const float* fp1_b1 = (const float*)d_in[16];
  const float* fp2_w0 = (const float*)d_in[17];
  const float* fp2_b0 = (const float*)d_in[18];
  const float* fp2_w1 = (const float*)d_in[19];
  const float* fp2_b1 = (const float*)d_in[20];
  const float* fc1_w  = (const float*)d_in[21];
  const float* fc1_b  = (const float*)d_in[22];
  const float* fc2_w  = (const float*)d_in[23];
  const float* fc2_b  = (const float*)d_in[24];
  const float* out_w  = (const float*)d_in[25];
  const float* out_b  = (const float*)d_in[26];
  float* out = (float*)d_out;

  const size_t M = M_ROWS;
  float* ws = (float*)d_ws;
  float* T   = ws;             // [0,256)
  float* G1  = ws + M * 256;   // [256,320)
  float* X1  = ws + M * 320;   // [320,384)
  float* X2  = ws + M * 384;   // [384,512)
  float* H2  = ws + M * 512;   // [512,640)
  __hip_bfloat16* H3b16 = (__hip_bfloat16*)(ws + M * 640);  // [640,768)
  unsigned long long* MASK = (unsigned long long*)(ws + M * 896);  // [896,960)
  __hip_bfloat16* X1b = (__hip_bfloat16*)(ws + M * 960);    // [960,992)
  __hip_bfloat16* X2b = (__hip_bfloat16*)(ws + M * 992);    // [992,1056)
  __hip_bfloat16* TB0 = (__hip_bfloat16*)(ws + M * 1056);   // [1056,1184)
  __hip_bfloat16* TB1 = (__hip_bfloat16*)(ws + M * 1184);   // [1184,1440)
  __hip_bfloat16* TB2 = (__hip_bfloat16*)(ws + M * 1440);   // [1440,1568)
  __hip_bfloat16* G   = (__hip_bfloat16*)(ws + M * 1568);   // [1568,2080)
  __hip_bfloat16* H3b = (__hip_bfloat16*)(ws + M * 2080);   // [2080,2208)
  __hip_bfloat16* WB  = (__hip_bfloat16*)(ws + M * 2208);   // weights
  __hip_bfloat16* X1lo = (__hip_bfloat16*)(ws + M * 2240);  // [2240,2272)
  __hip_bfloat16* X2lo = (__hip_bfloat16*)(ws + M * 2272);  // [2272,2336)
  float* nrmX1 = ws + M * 2336;                             // [2336,2337)
  float* nrmX2 = ws + M * 2337;                             // [2337,2338)
  if (ws_size < (size_t)M * 2340 * sizeof(float)) return;
  __hip_bfloat16* w_sa3_0 = WB;               // 256x128
  __hip_bfloat16* w_sa3_1 = w_sa3_0 + 32768;  // 256x256
  __hip_bfloat16* w_fp1_0 = w_sa3_1 + 65536;  // 512x128
  __hip_bfloat16* w_fp1_1 = w_fp1_0 + 65536;  // 512x512
  __hip_bfloat16* w_fp2_0 = w_fp1_1 + 262144; // 256x64
  __hip_bfloat16* w_fp2_1 = w_fp2_0 + 16384;  // 256x256
  __hip_bfloat16* w_fc1   = w_fp2_1 + 65536;  // 256x1024
  __hip_bfloat16* w_fc2   = w_fc1 + 262144;   // 128x256

  dim3 blk(256);
  TJobs jb;
  const float* srcs[8] = {sa3_w0, sa3_w1, fp1_w0, fp1_w1, fp2_w0, fp2_w1, fc1_w, fc2_w};
  __hip_bfloat16* dsts[8] = {w_sa3_0, w_sa3_1, w_fp1_0, w_fp1_1, w_fp2_0, w_fp2_1, w_fc1, w_fc2};
  int Ks[8] = {128, 256, 128, 512, 64, 256, 1024, 256};
  int Ns[8] = {256, 256, 512, 512, 256, 256, 256, 128};
  int off = 0;
  for (int i = 0; i < 8; i++) {
    jb.W[i] = srcs[i]; jb.Wt[i] = dsts[i];
    jb.K[i] = Ks[i]; jb.N[i] = Ns[i];
    jb.bx[i] = Ns[i] >> 5;
    jb.off[i] = off;
    off += (Ns[i] >> 5) * (Ks[i] >> 5);
  }
  transpose_cast_all<<<off, blk, 0, stream>>>(jb);

  // SA1 (fp32 exact) + knn v7 (4 queries/block).
  gemm_bias_relu<<<dim3(1, 256), blk, 0, stream>>>(x, 2, sa1_w0, sa1_b0, T, 64, 64, 2);
  gemm_bias_relu<<<dim3(1, 256), blk, 0, stream>>>(T, 64, sa1_w1, sa1_b1, G1, 64, 64, 64);
  knn_mean4<<<4096, 256, 0, stream>>>(x, G1, X1, X1b, X1lo, nrmX1);
  // SA2 (fp32 exact) + ball64 (MFMA gram) + gather2.
  gemm_bias_relu<<<dim3(2, 256), blk, 0, stream>>>(X1, 64, sa2_w0, sa2_b0, T, 128, 128, 64);
  gemm_bias_relu<<<dim3(2, 256), blk, 0, stream>>>(T, 128, sa2_w1, sa2_b1, H2, 128, 128, 128);
  ball_mask_mfma<64><<<dim3(136, 8), blk, 0, stream>>>(X1, X1b, X1lo, nrmX1, MASK, 0.2f * 0.2f);
  ball_gather_kernel<float><<<16384, 128, 0, stream>>>(MASK, H2, 128, X2, X2b, X2lo, nrmX2, 128, 32);
  // ball128 (MFMA gram), then the fused layer-1 and layer-2 GEMM triples.
  ball_mask_mfma<128><<<dim3(136, 8), blk, 0, stream>>>(X2, X2b, X2lo, nrmX2, MASK, 0.4f * 0.4f);
  {
    GJobs g1;
    g1.A[0] = (const short*)X2b; g1.W[0] = (const short*)w_sa3_0; g1.bias[0] = sa3_b0;
    g1.Y[0] = TB0; g1.lda[0] = 128; g1.ldw[0] = 128; g1.ldy[0] = 256; g1.N[0] = 256; g1.K[0] = 128;
    g1.A[1] = (const short*)X2b; g1.W[1] = (const short*)w_fp1_0; g1.bias[1] = fp1_b0;
    g1.Y[1] = TB1; g1.lda[1] = 128; g1.ldw[1] = 128; g1.ldy[1] = 512; g1.N[1] = 512; g1.K[1] = 128;
    g1.A[2] = (const short*)X1b; g1.W[2] = (const short*)w_fp2_0; g1.bias[2] = fp2_b0;
    g1.Y[2] = TB2; g1.lda[2] = 64; g1.ldw[2] = 64; g1.ldy[2] = 256; g1.N[2] = 256; g1.K[2] = 64;
    int tot1 = 0;
    for (int i = 0; i < 3; i++) {
      g1.xt[i] = g1.N[i] >> 7;
      g1.off[i] = tot1;
      tot1 += g1.xt[i] * 128;
    }
    gemm_mfma_multi<<<tot1, blk, 0, stream>>>(g1);

    GJobs g2;
    g2.A[0] = (const short*)TB0; g2.W[0] = (const short*)w_sa3_1; g2.bias[0] = sa3_b1;
    g2.Y[0] = H3b16; g2.lda[0] = 256; g2.ldw[0] = 256; g2.ldy[0] = 256; g2.N[0] = 256; g2.K[0] = 256;
    g2.A[1] = (const short*)TB1; g2.W[1] = (const short*)w_fp1_1; g2.bias[1] = fp1_b1;
    g2.Y[1] = G + 256; g2.lda[1] = 512; g2.ldw[1] = 512; g2.ldy[1] = 1024; g2.N[1] = 512; g2.K[1] = 512;
    g2.A[2] = (const short*)TB2; g2.W[2] = (const short*)w_fp2_1; g2.bias[2] = fp2_b1;
    g2.Y[2] = G; g2.lda[2] = 256; g2.ldw[2] = 256; g2.ldy[2] = 1024; g2.N[2] = 256; g2.K[2] = 256;
    int tot2 = 0;
    for (int i = 0; i < 3; i++) {
      g2.xt[i] = g2.N[i] >> 7;
      g2.off[i] = tot2;
      tot2 += g2.xt[i] * 128;
    }
    gemm_mfma_multi<<<tot2, blk, 0, stream>>>(g2);
  }
  // gather3 fills G[768:1024] from sa3 output.
  ball_gather_kernel<__hip_bfloat16><<<16384, 256, 0, stream>>>(
      MASK, H3b16, 256, nullptr, G + 768, nullptr, nullptr, 1024, 64);
  // Head: fc1 (bf16), then fc2+out fused.
  gemm_mfma<true><<<dim3(2, 128), blk, 0, stream>>>(G, 1024, w_fc1, 1024, fc1_b, H3b, 256, 256, 1024);
  gemm_fc2_out<<<dim3(1, 128), blk, 0, stream>>>(H3b, w_fc2, fc2_b, out_w, out_b, out);
}

// Round 14
// 383.120 us; speedup vs baseline: 1.2833x; 1.0207x over previous
//
#include <hip/hip_runtime.h>
#include <hip/hip_bf16.h>
#include <cstdint>

#define M_ROWS 16384

typedef __attribute__((ext_vector_type(8))) short short8;
typedef __attribute__((ext_vector_type(4))) float f32x4;

__device__ __forceinline__ unsigned long long umin64(unsigned long long a,
                                                     unsigned long long b) {
  return a < b ? a : b;
}

// ---------------------------------------------------------------------------
// fp32 GEMM (SA2 — feeds masks, bit-identical path).
// ---------------------------------------------------------------------------
__global__ __launch_bounds__(256) void gemm_bias_relu(
    const float* __restrict__ X, int ldx,
    const float* __restrict__ W,
    const float* __restrict__ bias,
    float* __restrict__ Y, int ldy,
    int N, int K)
{
  __shared__ __align__(16) float As[16][68];
  __shared__ __align__(16) float Bs[16][68];
  int tid = threadIdx.x;
  int tx = tid & 15, ty = tid >> 4;
  int m0 = blockIdx.y << 6, n0 = blockIdx.x << 6;
  float acc[4][4] = {};
  for (int k0 = 0; k0 < K; k0 += 16) {
#pragma unroll
    for (int i = 0; i < 4; i++) {
      int idx = tid + (i << 8);
      int m = idx >> 4, k = idx & 15;
      As[k][m] = (k0 + k < K) ? X[(size_t)(m0 + m) * ldx + k0 + k] : 0.f;
    }
#pragma unroll
    for (int i = 0; i < 4; i++) {
      int idx = tid + (i << 8);
      int n = idx & 63, k = idx >> 6;
      Bs[k][n] = (k0 + k < K) ? W[(size_t)(k0 + k) * N + n0 + n] : 0.f;
    }
    __syncthreads();
#pragma unroll
    for (int k = 0; k < 16; k++) {
      float4 a4 = *(const float4*)&As[k][ty << 2];
      float4 b4 = *(const float4*)&Bs[k][tx << 2];
      float av[4] = {a4.x, a4.y, a4.z, a4.w};
      float bv[4] = {b4.x, b4.y, b4.z, b4.w};
#pragma unroll
      for (int i = 0; i < 4; i++)
#pragma unroll
        for (int j = 0; j < 4; j++)
          acc[i][j] += av[i] * bv[j];
    }
    __syncthreads();
  }
  float4 bb = *(const float4*)&bias[n0 + (tx << 2)];
  float bv[4] = {bb.x, bb.y, bb.z, bb.w};
#pragma unroll
  for (int i = 0; i < 4; i++) {
    int m = m0 + (ty << 2) + i;
    float4 o;
    o.x = fmaxf(acc[i][0] + bv[0], 0.f);
    o.y = fmaxf(acc[i][1] + bv[1], 0.f);
    o.z = fmaxf(acc[i][2] + bv[2], 0.f);
    o.w = fmaxf(acc[i][3] + bv[3], 0.f);
    *(float4*)&Y[(size_t)m * ldy + n0 + (tx << 2)] = o;
  }
}

// ---------------------------------------------------------------------------
// SA1 fused: G1 = relu(relu(x@w0+b0)@w1+b1) for a 64-row tile per block.
// l1 (K=2) and l2 (K=64, ascending-k) use the same fmac chains as the
// two-gemm version -> bit-identical G1. Saves a dispatch + 8MB T traffic.
// ---------------------------------------------------------------------------
__global__ __launch_bounds__(256) void sa1_fused(
    const float* __restrict__ x,      // (16384,2)
    const float* __restrict__ w0,     // (2,64)
    const float* __restrict__ b0,     // 64
    const float* __restrict__ w1,     // (64,64)
    const float* __restrict__ b1,     // 64
    float* __restrict__ G1)           // (16384,64)
{
  __shared__ __align__(16) float Ts[64][68];   // T^T: [k][m]
  __shared__ __align__(16) float Ws[64][68];   // w1: [k][n]
  __shared__ float xs[64][2];
  __shared__ float w0s[2][64];
  __shared__ float b0s[64];
  int tid = threadIdx.x;
  int m0 = blockIdx.x << 6;
  if (tid < 128) {
    ((float*)xs)[tid] = x[(size_t)m0 * 2 + tid];
  } else if (tid < 192) {
    int n = tid - 128;
    w0s[0][n] = w0[n];
    b0s[n] = b0[n];
  } else {
    int n = tid - 192;
    w0s[1][n] = w0[64 + n];
  }
#pragma unroll
  for (int i = 0; i < 16; i++) {
    int idx = tid + (i << 8);
    int k = idx >> 6, n = idx & 63;
    Ws[k][n] = w1[(size_t)k * 64 + n];
  }
  __syncthreads();
#pragma unroll
  for (int i = 0; i < 16; i++) {
    int idx = tid + (i << 8);
    int m = idx >> 6, n = idx & 63;
    float acc = 0.f;
    acc += xs[m][0] * w0s[0][n];
    acc += xs[m][1] * w0s[1][n];
    Ts[n][m] = fmaxf(acc + b0s[n], 0.f);
  }
  __syncthreads();
  int tx = tid & 15, ty = tid >> 4;
  float acc[4][4] = {};
  for (int k = 0; k < 64; k++) {
    float4 a4 = *(const float4*)&Ts[k][ty << 2];
    float4 b4 = *(const float4*)&Ws[k][tx << 2];
    float av[4] = {a4.x, a4.y, a4.z, a4.w};
    float bv[4] = {b4.x, b4.y, b4.z, b4.w};
#pragma unroll
    for (int i = 0; i < 4; i++)
#pragma unroll
      for (int j = 0; j < 4; j++)
        acc[i][j] += av[i] * bv[j];
  }
  float4 bb = *(const float4*)&b1[tx << 2];
  float bv[4] = {bb.x, bb.y, bb.z, bb.w};
#pragma unroll
  for (int i = 0; i < 4; i++) {
    int m = m0 + (ty << 2) + i;
    float4 o;
    o.x = fmaxf(acc[i][0] + bv[0], 0.f);
    o.y = fmaxf(acc[i][1] + bv[1], 0.f);
    o.z = fmaxf(acc[i][2] + bv[2], 0.f);
    o.w = fmaxf(acc[i][3] + bv[3], 0.f);
    *(float4*)&G1[(size_t)m * 64 + (tx << 2)] = o;
  }
}

// ---------------------------------------------------------------------------
// Fused weight prep: 8 transposes (W KxN fp32 -> Wt NxK bf16) in one dispatch.
// ---------------------------------------------------------------------------
struct TJobs {
  const float* W[8];
  __hip_bfloat16* Wt[8];
  int K[8], N[8], bx[8], off[8];
};

__global__ __launch_bounds__(256) void transpose_cast_all(TJobs jb)
{
  __shared__ float tile[32][33];
  int bid = blockIdx.x;
  int j = 0;
#pragma unroll
  for (int t = 1; t < 8; t++)
    if (bid >= jb.off[t]) j = t;
  int rel = bid - jb.off[j];
  int K = jb.K[j], N = jb.N[j];
  const float* W = jb.W[j];
  __hip_bfloat16* Wt = jb.Wt[j];
  int n0 = (rel % jb.bx[j]) << 5, k0 = (rel / jb.bx[j]) << 5;
  int c = threadIdx.x & 31, i0 = threadIdx.x >> 5;
#pragma unroll
  for (int p = 0; p < 4; p++) {
    int i = i0 + p * 8;
    tile[i][c] = W[(size_t)(k0 + i) * N + n0 + c];
  }
  __syncthreads();
#pragma unroll
  for (int p = 0; p < 4; p++) {
    int r = i0 + p * 8;
    Wt[(size_t)(n0 + r) * K + k0 + c] = (__hip_bfloat16)tile[c][r];
  }
}

// ---------------------------------------------------------------------------
// bf16 MFMA GEMM (single-job; used for fc1).
// ---------------------------------------------------------------------------
template <bool OUT_BF16>
__global__ __launch_bounds__(256) void gemm_mfma(
    const __hip_bfloat16* __restrict__ A, int lda,
    const __hip_bfloat16* __restrict__ Wt, int ldw,
    const float* __restrict__ bias,
    void* __restrict__ Y, int ldy, int N, int K)
{
  __shared__ __align__(16) short As[128][40];
  __shared__ __align__(16) short Bs[128][40];
  int tid = threadIdx.x;
  int wave = tid >> 6, lane = tid & 63;
  int quad = lane >> 4, l16 = lane & 15;
  int m0 = blockIdx.y << 7, n0 = blockIdx.x << 7;
  int wm = (wave >> 1) << 6, wn = (wave & 1) << 6;
  f32x4 acc[4][4] = {};
  const short* Ag = (const short*)A;
  const short* Bg = (const short*)Wt;
  int srow = tid >> 2, sq = tid & 3;
  for (int k0 = 0; k0 < K; k0 += 32) {
#pragma unroll
    for (int h = 0; h < 2; h++) {
      int r = srow + (h << 6);
      uint4 va = *(const uint4*)&Ag[(size_t)(m0 + r) * lda + k0 + sq * 8];
      *(uint4*)&As[r][sq * 8] = va;
      uint4 vb = *(const uint4*)&Bg[(size_t)(n0 + r) * ldw + k0 + sq * 8];
      *(uint4*)&Bs[r][sq * 8] = vb;
    }
    __syncthreads();
    short8 a[4], b[4];
#pragma unroll
    for (int mi = 0; mi < 4; mi++)
      a[mi] = *(const short8*)&As[wm + mi * 16 + l16][quad * 8];
#pragma unroll
    for (int ni = 0; ni < 4; ni++)
      b[ni] = *(const short8*)&Bs[wn + ni * 16 + l16][quad * 8];
#pragma unroll
    for (int mi = 0; mi < 4; mi++)
#pragma unroll
      for (int ni = 0; ni < 4; ni++)
        acc[mi][ni] = __builtin_amdgcn_mfma_f32_16x16x32_bf16(
            a[mi], b[ni], acc[mi][ni], 0, 0, 0);
    __syncthreads();
  }
  float bn[4];
#pragma unroll
  for (int ni = 0; ni < 4; ni++) bn[ni] = bias[n0 + wn + ni * 16 + l16];
#pragma unroll
  for (int mi = 0; mi < 4; mi++)
#pragma unroll
    for (int ni = 0; ni < 4; ni++) {
      int n = n0 + wn + ni * 16 + l16;
#pragma unroll
      for (int r = 0; r < 4; r++) {
        int m = m0 + wm + mi * 16 + quad * 4 + r;
        float v = fmaxf(acc[mi][ni][r] + bn[ni], 0.f);
        if (OUT_BF16)
          ((__hip_bfloat16*)Y)[(size_t)m * ldy + n] = (__hip_bfloat16)v;
        else
          ((float*)Y)[(size_t)m * ldy + n] = v;
      }
    }
}

// ---------------------------------------------------------------------------
// Multi-job bf16 MFMA GEMM (bit-identical outputs; merges small dispatches).
// ---------------------------------------------------------------------------
struct GJobs {
  const short* A[3];
  const short* W[3];
  const float* bias[3];
  __hip_bfloat16* Y[3];
  int lda[3], ldw[3], ldy[3], N[3], K[3], xt[3], off[3];
};

__global__ __launch_bounds__(256) void gemm_mfma_multi(GJobs g)
{
  __shared__ __align__(16) short As[128][40];
  __shared__ __align__(16) short Bs[128][40];
  int bid = blockIdx.x;
  int j = 0;
#pragma unroll
  for (int t = 1; t < 3; t++)
    if (bid >= g.off[t]) j = t;
  int rel = bid - g.off[j];
  int xt = g.xt[j];
  int m0 = (rel / xt) << 7, n0 = (rel % xt) << 7;
  int lda = g.lda[j], ldw = g.ldw[j], ldy = g.ldy[j], K = g.K[j];
  const short* Ag = g.A[j];
  const short* Bg = g.W[j];
  const float* bias = g.bias[j];
  __hip_bfloat16* Y = g.Y[j];

  int tid = threadIdx.x;
  int wave = tid >> 6, lane = tid & 63;
  int quad = lane >> 4, l16 = lane & 15;
  int wm = (wave >> 1) << 6, wn = (wave & 1) << 6;
  f32x4 acc[4][4] = {};
  int srow = tid >> 2, sq = tid & 3;
  for (int k0 = 0; k0 < K; k0 += 32) {
#pragma unroll
    for (int h = 0; h < 2; h++) {
      int r = srow + (h << 6);
      uint4 va = *(const uint4*)&Ag[(size_t)(m0 + r) * lda + k0 + sq * 8];
      *(uint4*)&As[r][sq * 8] = va;
      uint4 vb = *(const uint4*)&Bg[(size_t)(n0 + r) * ldw + k0 + sq * 8];
      *(uint4*)&Bs[r][sq * 8] = vb;
    }
    __syncthreads();
    short8 a[4], b[4];
#pragma unroll
    for (int mi = 0; mi < 4; mi++)
      a[mi] = *(const short8*)&As[wm + mi * 16 + l16][quad * 8];
#pragma unroll
    for (int ni = 0; ni < 4; ni++)
      b[ni] = *(const short8*)&Bs[wn + ni * 16 + l16][quad * 8];
#pragma unroll
    for (int mi = 0; mi < 4; mi++)
#pragma unroll
      for (int ni = 0; ni < 4; ni++)
        acc[mi][ni] = __builtin_amdgcn_mfma_f32_16x16x32_bf16(
            a[mi], b[ni], acc[mi][ni], 0, 0, 0);
    __syncthreads();
  }
  float bn[4];
#pragma unroll
  for (int ni = 0; ni < 4; ni++) bn[ni] = bias[n0 + wn + ni * 16 + l16];
#pragma unroll
  for (int mi = 0; mi < 4; mi++)
#pragma unroll
    for (int ni = 0; ni < 4; ni++) {
      int n = n0 + wn + ni * 16 + l16;
#pragma unroll
      for (int r = 0; r < 4; r++) {
        int m = m0 + wm + mi * 16 + quad * 4 + r;
        float v = fmaxf(acc[mi][ni][r] + bn[ni], 0.f);
        Y[(size_t)m * ldy + n] = (__hip_bfloat16)v;
      }
    }
}

// ---------------------------------------------------------------------------
// fc2 + out head fused.
// ---------------------------------------------------------------------------
__global__ __launch_bounds__(256) void gemm_fc2_out(
    const __hip_bfloat16* __restrict__ A,
    const __hip_bfloat16* __restrict__ Wt,
    const float* __restrict__ bias,
    const float* __restrict__ wout,
    const float* __restrict__ bout,
    float* __restrict__ out)
{
  __shared__ __align__(16) short As[128][40];
  __shared__ __align__(16) short Bs[128][40];
  __shared__ float red[128][2];
  const int N = 128, K = 256, lda = 256, ldw = 256;
  int tid = threadIdx.x;
  int wave = tid >> 6, lane = tid & 63;
  int quad = lane >> 4, l16 = lane & 15;
  int m0 = blockIdx.y << 7;
  int wm = (wave >> 1) << 6, wn = (wave & 1) << 6;
  f32x4 acc[4][4] = {};
  const short* Ag = (const short*)A;
  const short* Bg = (const short*)Wt;
  int srow = tid >> 2, sq = tid & 3;
  for (int k0 = 0; k0 < K; k0 += 32) {
#pragma unroll
    for (int h = 0; h < 2; h++) {
      int r = srow + (h << 6);
      uint4 va = *(const uint4*)&Ag[(size_t)(m0 + r) * lda + k0 + sq * 8];
      *(uint4*)&As[r][sq * 8] = va;
      uint4 vb = *(const uint4*)&Bg[(size_t)(r % N) * ldw + k0 + sq * 8];
      *(uint4*)&Bs[r][sq * 8] = vb;
    }
    __syncthreads();
    short8 a[4], b[4];
#pragma unroll
    for (int mi = 0; mi < 4; mi++)
      a[mi] = *(const short8*)&As[wm + mi * 16 + l16][quad * 8];
#pragma unroll
    for (int ni = 0; ni < 4; ni++)
      b[ni] = *(const short8*)&Bs[wn + ni * 16 + l16][quad * 8];
#pragma unroll
    for (int mi = 0; mi < 4; mi++)
#pragma unroll
      for (int ni = 0; ni < 4; ni++)
        acc[mi][ni] = __builtin_amdgcn_mfma_f32_16x16x32_bf16(
            a[mi], b[ni], acc[mi][ni], 0, 0, 0);
    __syncthreads();
  }
  float bn[4], wo[4];
#pragma unroll
  for (int ni = 0; ni < 4; ni++) {
    int n = wn + ni * 16 + l16;
    bn[ni] = bias[n];
    wo[ni] = wout[n];
  }
  float sacc[4][4];
#pragma unroll
  for (int mi = 0; mi < 4; mi++)
#pragma unroll
    for (int r = 0; r < 4; r++) {
      float s = 0.f;
#pragma unroll
      for (int ni = 0; ni < 4; ni++)
        s += fmaxf(acc[mi][ni][r] + bn[ni], 0.f) * wo[ni];
      sacc[mi][r] = s;
    }
#pragma unroll
  for (int off = 1; off < 16; off <<= 1)
#pragma unroll
    for (int mi = 0; mi < 4; mi++)
#pragma unroll
      for (int r = 0; r < 4; r++)
        sacc[mi][r] += __shfl_xor(sacc[mi][r], off);
  int wp = wave & 1;
  if (l16 == 0) {
#pragma unroll
    for (int mi = 0; mi < 4; mi++)
#pragma unroll
      for (int r = 0; r < 4; r++)
        red[wm + mi * 16 + quad * 4 + r][wp] = sacc[mi][r];
  }
  __syncthreads();
  if (tid < 128) {
    float s = red[tid][0] + red[tid][1] + bout[0];
    out[(size_t)(m0 + tid)] = 1.f / (1.f + expf(-s));
  }
}

// ---------------------------------------------------------------------------
// SA1 KNN v8 — 4 queries/block, keys pinned in registers (fully unrolled
// scatter), per-query survivor buffers (provable bound: survivors come
// only from the 32 quads with qmin <= T -> <= 32*32 = 1024), single
// scatter pass + per-wave parallel merge. Same T/survivor sets as v5/v7
// -> bit-identical selection.
// ---------------------------------------------------------------------------
__global__ __launch_bounds__(256) void knn_mean4(
    const float* __restrict__ X,
    const float* __restrict__ G1,
    float* __restrict__ X1,
    __hip_bfloat16* __restrict__ X1b,
    __hip_bfloat16* __restrict__ X1lo,
    float* __restrict__ nrmX1)
{
  int qb = blockIdx.x << 2;
  int base = qb & ~2047;
  int tid = threadIdx.x;
  int wave = tid >> 6, lane = tid & 63;
  __shared__ unsigned long long lmins[4][256];
  __shared__ unsigned long long qmins[4][64];
  __shared__ unsigned long long thr[4];
  __shared__ unsigned long long surv[4][1024];
  __shared__ int scnt[4];
  __shared__ int selidx[4][32];
  if (tid < 4) scnt[tid] = 0;
  float xj[8], yj[8];
#pragma unroll
  for (int u = 0; u < 8; u++) {
    int j = (u << 8) + tid;
    float2 c = *(const float2*)&X[(size_t)(base + j) * 2];
    xj[u] = c.x;
    yj[u] = c.y;
  }
  unsigned long long key[4][8];
#pragma unroll
  for (int g = 0; g < 4; g++) {
    float qx = X[(size_t)(qb + g) * 2];
    float qy = X[(size_t)(qb + g) * 2 + 1];
    unsigned long long lm = ~0ull;
#pragma unroll
    for (int u = 0; u < 8; u++) {
      float dx = xj[u] - qx;
      float dy = yj[u] - qy;
      float d2 = dx * dx + dy * dy;
      key[g][u] = ((unsigned long long)__float_as_uint(d2) << 32) |
                  (unsigned)((u << 8) + tid);
      lm = umin64(lm, key[g][u]);
    }
    lmins[g][tid] = lm;
  }
  __syncthreads();
  {
    int g = wave;
    unsigned long long qm =
        umin64(umin64(lmins[g][lane], lmins[g][lane + 64]),
               umin64(lmins[g][lane + 128], lmins[g][lane + 192]));
    qmins[g][lane] = qm;
    int rank = 0;
    for (int i = 0; i < 64; i++) rank += (qmins[g][i] < qm);
    if (rank == 31) thr[g] = qm;  // exactly one lane (unique keys)
  }
  __syncthreads();
#pragma unroll
  for (int g = 0; g < 4; g++) {
    unsigned long long T = thr[g];
#pragma unroll
    for (int u = 0; u < 8; u++) {
      if (key[g][u] <= T) {
        int p = atomicAdd(&scnt[g], 1);
        surv[g][p] = key[g][u];
      }
    }
  }
  __syncthreads();
  {
    int g = wave;
    int s = scnt[g];  // >= 32 guaranteed
    for (int i = lane; i < s; i += 64) {
      unsigned long long c = surv[g][i];
      int r = 0;
      for (int j2 = 0; j2 < s; j2++) r += (surv[g][j2] < c);
      if (r < 32) selidx[g][r] = (int)(c & 0xffffffffULL);
    }
  }
  __syncthreads();
  {
    int g = wave;
    float acc = 0.f;
#pragma unroll 8
    for (int sI = 0; sI < 32; sI++)
      acc += G1[(size_t)(base + selidx[g][sI]) * 64 + lane];
    float v = acc * (1.0f / 32.0f);
    int q = qb + g;
    X1[(size_t)q * 64 + lane] = v;
    __hip_bfloat16 hi = (__hip_bfloat16)v;
    X1b[(size_t)q * 64 + lane] = hi;
    X1lo[(size_t)q * 64 + lane] = (__hip_bfloat16)(v - (float)hi);
    float nv = v * v;
#pragma unroll
    for (int off = 32; off > 0; off >>= 1) nv += __shfl_down(nv, off);
    if (lane == 0) nrmX1[q] = nv;
  }
}

// ---------------------------------------------------------------------------
// Ball-query pass 1 v6 — split-bf16 MFMA gram + exact-decision guard band
// (round-12 version, passing; masks bit-identical).
// ---------------------------------------------------------------------------
template <int C>
__global__ __launch_bounds__(256) void ball_mask_mfma(
    const float* __restrict__ F32,
    const __hip_bfloat16* __restrict__ Fhi,
    const __hip_bfloat16* __restrict__ Flo,
    const float* __restrict__ nrm,
    unsigned long long* __restrict__ mask,
    float r2)
{
  __shared__ __align__(16) short Qh[128][40];
  __shared__ __align__(16) short Ql[128][40];
  __shared__ __align__(16) short Ch[128][40];
  __shared__ __align__(16) short Cl[128][40];
  __shared__ unsigned int tw[128][4];
  __shared__ float nqs[128], ncs[128];
  int tid = threadIdx.x;
  int p = blockIdx.x;
  int qt = 0;
  while (p >= 16 - qt) { p -= 16 - qt; qt++; }
  int ct = qt + p;
  int b0 = blockIdx.y << 11;
  int q0 = b0 + (qt << 7), c0 = b0 + (ct << 7);
  tw[tid >> 1][(tid & 1) * 2] = 0;
  tw[tid >> 1][(tid & 1) * 2 + 1] = 0;
  if (tid < 128) nqs[tid] = nrm[q0 + tid];
  else ncs[tid - 128] = nrm[c0 + tid - 128];

  int wave = tid >> 6, lane = tid & 63;
  int quad = lane >> 4, l16 = lane & 15;
  int wm = (wave >> 1) << 6, wn = (wave & 1) << 6;
  f32x4 acc[4][4] = {};
  const short* QH = (const short*)Fhi;
  const short* QL = (const short*)Flo;
  int srow = tid >> 2, sq = tid & 3;
  for (int k0 = 0; k0 < C; k0 += 32) {
#pragma unroll
    for (int h = 0; h < 2; h++) {
      int r = srow + (h << 6);
      *(uint4*)&Qh[r][sq * 8] = *(const uint4*)&QH[(size_t)(q0 + r) * C + k0 + sq * 8];
      *(uint4*)&Ql[r][sq * 8] = *(const uint4*)&QL[(size_t)(q0 + r) * C + k0 + sq * 8];
      *(uint4*)&Ch[r][sq * 8] = *(const uint4*)&QH[(size_t)(c0 + r) * C + k0 + sq * 8];
      *(uint4*)&Cl[r][sq * 8] = *(const uint4*)&QL[(size_t)(c0 + r) * C + k0 + sq * 8];
    }
    __syncthreads();
    short8 ah[4], al[4];
#pragma unroll
    for (int mi = 0; mi < 4; mi++) {
      ah[mi] = *(const short8*)&Qh[wm + mi * 16 + l16][quad * 8];
      al[mi] = *(const short8*)&Ql[wm + mi * 16 + l16][quad * 8];
    }
#pragma unroll
    for (int ni = 0; ni < 4; ni++) {
      short8 bh = *(const short8*)&Ch[wn + ni * 16 + l16][quad * 8];
      short8 bl = *(const short8*)&Cl[wn + ni * 16 + l16][quad * 8];
#pragma unroll
      for (int mi = 0; mi < 4; mi++) {
        acc[mi][ni] = __builtin_amdgcn_mfma_f32_16x16x32_bf16(ah[mi], bh, acc[mi][ni], 0, 0, 0);
        acc[mi][ni] = __builtin_amdgcn_mfma_f32_16x16x32_bf16(ah[mi], bl, acc[mi][ni], 0, 0, 0);
        acc[mi][ni] = __builtin_amdgcn_mfma_f32_16x16x32_bf16(al[mi], bh, acc[mi][ni], 0, 0, 0);
      }
    }
    __syncthreads();
  }
  unsigned long long memb = 0, fb = 0;
#pragma unroll
  for (int mi = 0; mi < 4; mi++)
#pragma unroll
    for (int ni = 0; ni < 4; ni++)
#pragma unroll
      for (int r = 0; r < 4; r++) {
        int e = (mi << 4) | (ni << 2) | r;
        float nqv = nqs[wm + mi * 16 + quad * 4 + r];
        float ncv = ncs[wn + ni * 16 + l16];
        float d2a = nqv + ncv - 2.f * acc[mi][ni][r];
        float eps = 4.0e-5f * (nqv + ncv) + 1.0e-6f;
        if (d2a < r2 - eps) memb |= 1ull << e;
        else if (d2a <= r2 + eps) fb |= 1ull << e;
      }
  while (fb) {
    int e = __builtin_ctzll(fb);
    fb &= fb - 1;
    int mi = e >> 4, ni = (e >> 2) & 3, r = e & 3;
    int qrow = q0 + wm + mi * 16 + quad * 4 + r;
    int ccol = c0 + wn + ni * 16 + l16;
    float a2 = 0.f;
    for (int k = 0; k < C; k++) {
      float d = F32[(size_t)qrow * C + k] - F32[(size_t)ccol * C + k];
      a2 = fmaf(d, d, a2);
    }
    if (a2 <= r2) memb |= 1ull << e;
  }
#pragma unroll
  for (int ni = 0; ni < 4; ni++) {
    int cl = wn + ni * 16 + l16;
    unsigned int w0b = 0, w1b = 0;
#pragma unroll
    for (int mi = 0; mi < 4; mi++)
#pragma unroll
      for (int r = 0; r < 4; r++)
        if (memb & (1ull << ((mi << 4) | (ni << 2) | r))) {
          unsigned int bitpos = ((mi & 1) << 4) | (quad << 2) | r;
          if (mi < 2) w0b |= 1u << bitpos;
          else w1b |= 1u << bitpos;
        }
    if (w0b) atomicOr(&tw[cl][(wm >> 5)], w0b);
    if (w1b) atomicOr(&tw[cl][(wm >> 5) + 1], w1b);
  }
  __syncthreads();
  {
    int row = tid >> 1, half = tid & 1;
    int wq = row >> 5, sb = row & 31;
    unsigned int lo = 0, hi = 0;
    for (int j = 0; j < 32; j++) {
      lo |= ((tw[half * 64 + j][wq] >> sb) & 1u) << j;
      hi |= ((tw[half * 64 + 32 + j][wq] >> sb) & 1u) << j;
    }
    mask[(size_t)(q0 + row) * 32 + (ct << 1) + half] =
        ((unsigned long long)hi << 32) | lo;
  }
  if (qt != ct) {
    int row = tid >> 1, word = tid & 1;
    unsigned long long v = (unsigned long long)tw[row][word * 2] |
                           ((unsigned long long)tw[row][word * 2 + 1] << 32);
    mask[(size_t)(c0 + row) * 32 + (qt << 1) + word] = v;
  }
}

// ---------------------------------------------------------------------------
// Ball-query pass 2 (templated input dtype; fp32 accumulate; unroll 8).
// ---------------------------------------------------------------------------
template <typename TIn>
__global__ void ball_gather_kernel(
    const unsigned long long* __restrict__ mask,
    const TIn* __restrict__ H, int CH,
    float* __restrict__ Yf, __hip_bfloat16* __restrict__ Yb,
    __hip_bfloat16* __restrict__ Ylo, float* __restrict__ nrm,
    int ldy, int S)
{
  int q = blockIdx.x;
  int base = q & ~2047;
  int tid = threadIdx.x;
  __shared__ int idxl[64];
  __shared__ float wtab[64];
  __shared__ float npart[4];
  __shared__ int scount;
  if (tid < 32) {
    unsigned long long w = mask[(size_t)q * 32 + tid];
    int cnt = __popcll(w);
    int inc = cnt;
#pragma unroll
    for (int off = 1; off < 32; off <<= 1) {
      int o = __shfl_up(inc, off);
      if (tid >= off) inc += o;
    }
    if (tid == 31) scount = inc;
    int p = inc - cnt;
    while (w && p < 64) {
      int j = (tid << 6) + __builtin_ctzll(w);
      w &= w - 1;
      idxl[p++] = j;
    }
  }
  __syncthreads();
  int c = scount;
  if (tid < 64) {
    int p = tid;
    int cnt = (p < c && p < S) ? ((S - 1 - p) / c + 1) : 0;
    wtab[p] = (float)cnt / (float)S;
  }
  __syncthreads();
  float acc = 0.f;
  int lim = c < S ? c : S;
#pragma unroll 8
  for (int s = 0; s < lim; s++)
    acc += wtab[s] * (float)H[(size_t)(base + idxl[s]) * CH + tid];
  if (Yf) Yf[(size_t)q * ldy + tid] = acc;
  if (Yb) Yb[(size_t)q * ldy + tid] = (__hip_bfloat16)acc;
  if (Ylo) {
    __hip_bfloat16 hi = (__hip_bfloat16)acc;
    Ylo[(size_t)q * ldy + tid] = (__hip_bfloat16)(acc - (float)hi);
  }
  if (nrm) {
    float nv = acc * acc;
#pragma unroll
    for (int off = 32; off > 0; off >>= 1) nv += __shfl_down(nv, off);
    if ((tid & 63) == 0) npart[tid >> 6] = nv;
    __syncthreads();
    if (tid == 0) {
      float t = 0.f;
      for (int w = 0; w < (blockDim.x >> 6); w++) t += npart[w];
      nrm[q] = t;
    }
  }
}

// ---------------------------------------------------------------------------
extern "C" void kernel_launch(void* const* d_in, const int* in_sizes, int n_in,
                              void* d_out, int out_size, void* d_ws,
                              size_t ws_size, hipStream_t stream)
{
  const float* x      = (const float*)d_in[0];
  const float* sa1_w0 = (const float*)d_in[1];
  const float* sa1_b0 = (const float*)d_in[2];
  const float* sa1_w1 = (const float*)d_in[3];
  const float* sa1_b1 = (const float*)d_in[4];
  const float* sa2_w0 = (const float*)d_in[5];
  const float* sa2_b0 = (const float*)d_in[6];
  const float* sa2_w1 = (const float*)d_in[7];
  const float* sa2_b1 = (const float*)d_in[8];
  const float* sa3_w0 = (const float*)d_in[9];
  const float* sa3_b0 = (const float*)d_in[10];
  const float* sa3_w1 = (const float*)d_in[11];
  const float* sa3_b1 = (const float*)d_in[12];
  const float* fp1_w0 = (const float*)d_in[13];
  const float* fp1_b0 = (const float*)d_in[14];
  const float* fp1_w1 = (const float*)d_in[15];
  const float* fp1_b1 = (const float*)d_in[16];
  const float* fp2_w0 = (const float*)d_in[17];
  const float* fp2_b0 = (const float*)d_in[18];
  const float* fp2_w1 = (const float*)d_in[19];
  const float* fp2_b1 = (const float*)d_in[20];
  const float* fc1_w  = (const float*)d_in[21];
  const float* fc1_b  = (const float*)d_in[22];
  const float* fc2_w  = (const float*)d_in[23];
  const float* fc2_b  = (const float*)d_in[24];
  const float* out_w  = (const float*)d_in[25];
  const float* out_b  = (const float*)d_in[26];
  float* out = (float*)d_out;

  const size_t M = M_ROWS;
  float* ws = (float*)d_ws;
  float* T   = ws;             // [0,256)
  float* G1  = ws + M * 256;   // [256,320)
  float* X1  = ws + M * 320;   // [320,384)
  float* X2  = ws + M * 384;   // [384,512)
  float* H2  = ws + M * 512;   // [512,640)
  __hip_bfloat16* H3b16 = (__hip_bfloat16*)(ws + M * 640);  // [640,768)
  unsigned long long* MASK = (unsigned long long*)(ws + M * 896);  // [896,960)
  __hip_bfloat16* X1b = (__hip_bfloat16*)(ws + M * 960);    // [960,992)
  __hip_bfloat16* X2b = (__hip_bfloat16*)(ws + M * 992);    // [992,1056)
  __hip_bfloat16* TB0 = (__hip_bfloat16*)(ws + M * 1056);   // [1056,1184)
  __hip_bfloat16* TB1 = (__hip_bfloat16*)(ws + M * 1184);   // [1184,1440)
  __hip_bfloat16* TB2 = (__hip_bfloat16*)(ws + M * 1440);   // [1440,1568)
  __hip_bfloat16* G   = (__hip_bfloat16*)(ws + M * 1568);   // [1568,2080)
  __hip_bfloat16* H3b = (__hip_bfloat16*)(ws + M * 2080);   // [2080,2208)
  __hip_bfloat16* WB  = (__hip_bfloat16*)(ws + M * 2208);   // weights
  __hip_bfloat16* X1lo = (__hip_bfloat16*)(ws + M * 2240);  // [2240,2272)
  __hip_bfloat16* X2lo = (__hip_bfloat16*)(ws + M * 2272);  // [2272,2336)
  float* nrmX1 = ws + M * 2336;                             // [2336,2337)
  float* nrmX2 = ws + M * 2337;                             // [2337,2338)
  if (ws_size < (size_t)M * 2340 * sizeof(float)) return;
  __hip_bfloat16* w_sa3_0 = WB;               // 256x128
  __hip_bfloat16* w_sa3_1 = w_sa3_0 + 32768;  // 256x256
  __hip_bfloat16* w_fp1_0 = w_sa3_1 + 65536;  // 512x128
  __hip_bfloat16* w_fp1_1 = w_fp1_0 + 65536;  // 512x512
  __hip_bfloat16* w_fp2_0 = w_fp1_1 + 262144; // 256x64
  __hip_bfloat16* w_fp2_1 = w_fp2_0 + 16384;  // 256x256
  __hip_bfloat16* w_fc1   = w_fp2_1 + 65536;  // 256x1024
  __hip_bfloat16* w_fc2   = w_fc1 + 262144;   // 128x256

  dim3 blk(256);
  TJobs jb;
  const float* srcs[8] = {sa3_w0, sa3_w1, fp1_w0, fp1_w1, fp2_w0, fp2_w1, fc1_w, fc2_w};
  __hip_bfloat16* dsts[8] = {w_sa3_0, w_sa3_1, w_fp1_0, w_fp1_1, w_fp2_0, w_fp2_1, w_fc1, w_fc2};
  int Ks[8] = {128, 256, 128, 512, 64, 256, 1024, 256};
  int Ns[8] = {256, 256, 512, 512, 256, 256, 256, 128};
  int off = 0;
  for (int i = 0; i < 8; i++) {
    jb.W[i] = srcs[i]; jb.Wt[i] = dsts[i];
    jb.K[i] = Ks[i]; jb.N[i] = Ns[i];
    jb.bx[i] = Ns[i] >> 5;
    jb.off[i] = off;
    off += (Ns[i] >> 5) * (Ks[i] >> 5);
  }
  transpose_cast_all<<<off, blk, 0, stream>>>(jb);

  // SA1 fused (bit-identical G1) + knn v8.
  sa1_fused<<<256, blk, 0, stream>>>(x, sa1_w0, sa1_b0, sa1_w1, sa1_b1, G1);
  knn_mean4<<<4096, 256, 0, stream>>>(x, G1, X1, X1b, X1lo, nrmX1);
  // SA2 (fp32 exact) + ball64 (MFMA gram) + gather2.
  gemm_bias_relu<<<dim3(2, 256), blk, 0, stream>>>(X1, 64, sa2_w0, sa2_b0, T, 128, 128, 64);
  gemm_bias_relu<<<dim3(2, 256), blk, 0, stream>>>(T, 128, sa2_w1, sa2_b1, H2, 128, 128, 128);
  ball_mask_mfma<64><<<dim3(136, 8), blk, 0, stream>>>(X1, X1b, X1lo, nrmX1, MASK, 0.2f * 0.2f);
  ball_gather_kernel<float><<<16384, 128, 0, stream>>>(MASK, H2, 128, X2, X2b, X2lo, nrmX2, 128, 32);
  // ball128 (MFMA gram), then the fused layer-1 and layer-2 GEMM triples.
  ball_mask_mfma<128><<<dim3(136, 8), blk, 0, stream>>>(X2, X2b, X2lo, nrmX2, MASK, 0.4f * 0.4f);
  {
    GJobs g1;
    g1.A[0] = (const short*)X2b; g1.W[0] = (const short*)w_sa3_0; g1.bias[0] = sa3_b0;
    g1.Y[0] = TB0; g1.lda[0] = 128; g1.ldw[0] = 128; g1.ldy[0] = 256; g1.N[0] = 256; g1.K[0] = 128;
    g1.A[1] = (const short*)X2b; g1.W[1] = (const short*)w_fp1_0; g1.bias[1] = fp1_b0;
    g1.Y[1] = TB1; g1.lda[1] = 128; g1.ldw[1] = 128; g1.ldy[1] = 512; g1.N[1] = 512; g1.K[1] = 128;
    g1.A[2] = (const short*)X1b; g1.W[2] = (const short*)w_fp2_0; g1.bias[2] = fp2_b0;
    g1.Y[2] = TB2; g1.lda[2] = 64; g1.ldw[2] = 64; g1.ldy[2] = 256; g1.N[2] = 256; g1.K[2] = 64;
    int tot1 = 0;
    for (int i = 0; i < 3; i++) {
      g1.xt[i] = g1.N[i] >> 7;
      g1.off[i] = tot1;
      tot1 += g1.xt[i] * 128;
    }
    gemm_mfma_multi<<<tot1, blk, 0, stream>>>(g1);

    GJobs g2;
    g2.A[0] = (const short*)TB0; g2.W[0] = (const short*)w_sa3_1; g2.bias[0] = sa3_b1;
    g2.Y[0] = H3b16; g2.lda[0] = 256; g2.ldw[0] = 256; g2.ldy[0] = 256; g2.N[0] = 256; g2.K[0] = 256;
    g2.A[1] = (const short*)TB1; g2.W[1] = (const short*)w_fp1_1; g2.bias[1] = fp1_b1;
    g2.Y[1] = G + 256; g2.lda[1] = 512; g2.ldw[1] = 512; g2.ldy[1] = 1024; g2.N[1] = 512; g2.K[1] = 512;
    g2.A[2] = (const short*)TB2; g2.W[2] = (const short*)w_fp2_1; g2.bias[2] = fp2_b1;
    g2.Y[2] = G; g2.lda[2] = 256; g2.ldw[2] = 256; g2.ldy[2] = 1024; g2.N[2] = 256; g2.K[2] = 256;
    int tot2 = 0;
    for (int i = 0; i < 3; i++) {
      g2.xt[i] = g2.N[i] >> 7;
      g2.off[i] = tot2;
      tot2 += g2.xt[i] * 128;
    }
    gemm_mfma_multi<<<tot2, blk, 0, stream>>>(g2);
  }
  // gather3 fills G[768:1024] from sa3 output.
  ball_gather_kernel<__hip_bfloat16><<<16384, 256, 0, stream>>>(
      MASK, H3b16, 256, nullptr, G + 768, nullptr, nullptr, 1024, 64);
  // Head: fc1 (bf16), then fc2+out fused.
  gemm_mfma<true><<<dim3(2, 128), blk, 0, stream>>>(G, 1024, w_fc1, 1024, fc1_b, H3b, 256, 256, 1024);
  gemm_fc2_out<<<dim3(1, 128), blk, 0, stream>>>(H3b, w_fc2, fc2_b, out_w, out_b, out);
}

// Round 15
// 369.364 us; speedup vs baseline: 1.3311x; 1.0372x over previous
//
#include <hip/hip_runtime.h>
#include <hip/hip_bf16.h>
#include <cstdint>

#define M_ROWS 16384

typedef __attribute__((ext_vector_type(8))) short short8;
typedef __attribute__((ext_vector_type(4))) float f32x4;

__device__ __forceinline__ unsigned long long umin64(unsigned long long a,
                                                     unsigned long long b) {
  return a < b ? a : b;
}

// ---------------------------------------------------------------------------
// fp32 GEMM (SA2 — feeds masks, bit-identical path).
// ---------------------------------------------------------------------------
__global__ __launch_bounds__(256) void gemm_bias_relu(
    const float* __restrict__ X, int ldx,
    const float* __restrict__ W,
    const float* __restrict__ bias,
    float* __restrict__ Y, int ldy,
    int N, int K)
{
  __shared__ __align__(16) float As[16][68];
  __shared__ __align__(16) float Bs[16][68];
  int tid = threadIdx.x;
  int tx = tid & 15, ty = tid >> 4;
  int m0 = blockIdx.y << 6, n0 = blockIdx.x << 6;
  float acc[4][4] = {};
  for (int k0 = 0; k0 < K; k0 += 16) {
#pragma unroll
    for (int i = 0; i < 4; i++) {
      int idx = tid + (i << 8);
      int m = idx >> 4, k = idx & 15;
      As[k][m] = (k0 + k < K) ? X[(size_t)(m0 + m) * ldx + k0 + k] : 0.f;
    }
#pragma unroll
    for (int i = 0; i < 4; i++) {
      int idx = tid + (i << 8);
      int n = idx & 63, k = idx >> 6;
      Bs[k][n] = (k0 + k < K) ? W[(size_t)(k0 + k) * N + n0 + n] : 0.f;
    }
    __syncthreads();
#pragma unroll
    for (int k = 0; k < 16; k++) {
      float4 a4 = *(const float4*)&As[k][ty << 2];
      float4 b4 = *(const float4*)&Bs[k][tx << 2];
      float av[4] = {a4.x, a4.y, a4.z, a4.w};
      float bv[4] = {b4.x, b4.y, b4.z, b4.w};
#pragma unroll
      for (int i = 0; i < 4; i++)
#pragma unroll
        for (int j = 0; j < 4; j++)
          acc[i][j] += av[i] * bv[j];
    }
    __syncthreads();
  }
  float4 bb = *(const float4*)&bias[n0 + (tx << 2)];
  float bv[4] = {bb.x, bb.y, bb.z, bb.w};
#pragma unroll
  for (int i = 0; i < 4; i++) {
    int m = m0 + (ty << 2) + i;
    float4 o;
    o.x = fmaxf(acc[i][0] + bv[0], 0.f);
    o.y = fmaxf(acc[i][1] + bv[1], 0.f);
    o.z = fmaxf(acc[i][2] + bv[2], 0.f);
    o.w = fmaxf(acc[i][3] + bv[3], 0.f);
    *(float4*)&Y[(size_t)m * ldy + n0 + (tx << 2)] = o;
  }
}

// ---------------------------------------------------------------------------
// SA1 fused: G1 = relu(relu(x@w0+b0)@w1+b1), bit-identical chains.
// ---------------------------------------------------------------------------
__global__ __launch_bounds__(256) void sa1_fused(
    const float* __restrict__ x,
    const float* __restrict__ w0,
    const float* __restrict__ b0,
    const float* __restrict__ w1,
    const float* __restrict__ b1,
    float* __restrict__ G1)
{
  __shared__ __align__(16) float Ts[64][68];
  __shared__ __align__(16) float Ws[64][68];
  __shared__ float xs[64][2];
  __shared__ float w0s[2][64];
  __shared__ float b0s[64];
  int tid = threadIdx.x;
  int m0 = blockIdx.x << 6;
  if (tid < 128) {
    ((float*)xs)[tid] = x[(size_t)m0 * 2 + tid];
  } else if (tid < 192) {
    int n = tid - 128;
    w0s[0][n] = w0[n];
    b0s[n] = b0[n];
  } else {
    int n = tid - 192;
    w0s[1][n] = w0[64 + n];
  }
#pragma unroll
  for (int i = 0; i < 16; i++) {
    int idx = tid + (i << 8);
    int k = idx >> 6, n = idx & 63;
    Ws[k][n] = w1[(size_t)k * 64 + n];
  }
  __syncthreads();
#pragma unroll
  for (int i = 0; i < 16; i++) {
    int idx = tid + (i << 8);
    int m = idx >> 6, n = idx & 63;
    float acc = 0.f;
    acc += xs[m][0] * w0s[0][n];
    acc += xs[m][1] * w0s[1][n];
    Ts[n][m] = fmaxf(acc + b0s[n], 0.f);
  }
  __syncthreads();
  int tx = tid & 15, ty = tid >> 4;
  float acc[4][4] = {};
  for (int k = 0; k < 64; k++) {
    float4 a4 = *(const float4*)&Ts[k][ty << 2];
    float4 b4 = *(const float4*)&Ws[k][tx << 2];
    float av[4] = {a4.x, a4.y, a4.z, a4.w};
    float bv[4] = {b4.x, b4.y, b4.z, b4.w};
#pragma unroll
    for (int i = 0; i < 4; i++)
#pragma unroll
      for (int j = 0; j < 4; j++)
        acc[i][j] += av[i] * bv[j];
  }
  float4 bb = *(const float4*)&b1[tx << 2];
  float bv[4] = {bb.x, bb.y, bb.z, bb.w};
#pragma unroll
  for (int i = 0; i < 4; i++) {
    int m = m0 + (ty << 2) + i;
    float4 o;
    o.x = fmaxf(acc[i][0] + bv[0], 0.f);
    o.y = fmaxf(acc[i][1] + bv[1], 0.f);
    o.z = fmaxf(acc[i][2] + bv[2], 0.f);
    o.w = fmaxf(acc[i][3] + bv[3], 0.f);
    *(float4*)&G1[(size_t)m * 64 + (tx << 2)] = o;
  }
}

// ---------------------------------------------------------------------------
// Fused weight prep.
// ---------------------------------------------------------------------------
struct TJobs {
  const float* W[8];
  __hip_bfloat16* Wt[8];
  int K[8], N[8], bx[8], off[8];
};

__global__ __launch_bounds__(256) void transpose_cast_all(TJobs jb)
{
  __shared__ float tile[32][33];
  int bid = blockIdx.x;
  int j = 0;
#pragma unroll
  for (int t = 1; t < 8; t++)
    if (bid >= jb.off[t]) j = t;
  int rel = bid - jb.off[j];
  int K = jb.K[j], N = jb.N[j];
  const float* W = jb.W[j];
  __hip_bfloat16* Wt = jb.Wt[j];
  int n0 = (rel % jb.bx[j]) << 5, k0 = (rel / jb.bx[j]) << 5;
  int c = threadIdx.x & 31, i0 = threadIdx.x >> 5;
#pragma unroll
  for (int p = 0; p < 4; p++) {
    int i = i0 + p * 8;
    tile[i][c] = W[(size_t)(k0 + i) * N + n0 + c];
  }
  __syncthreads();
#pragma unroll
  for (int p = 0; p < 4; p++) {
    int r = i0 + p * 8;
    Wt[(size_t)(n0 + r) * K + k0 + c] = (__hip_bfloat16)tile[c][r];
  }
}

// ---------------------------------------------------------------------------
// bf16 MFMA GEMM (single-job; used for fc1).
// ---------------------------------------------------------------------------
template <bool OUT_BF16>
__global__ __launch_bounds__(256) void gemm_mfma(
    const __hip_bfloat16* __restrict__ A, int lda,
    const __hip_bfloat16* __restrict__ Wt, int ldw,
    const float* __restrict__ bias,
    void* __restrict__ Y, int ldy, int N, int K)
{
  __shared__ __align__(16) short As[128][40];
  __shared__ __align__(16) short Bs[128][40];
  int tid = threadIdx.x;
  int wave = tid >> 6, lane = tid & 63;
  int quad = lane >> 4, l16 = lane & 15;
  int m0 = blockIdx.y << 7, n0 = blockIdx.x << 7;
  int wm = (wave >> 1) << 6, wn = (wave & 1) << 6;
  f32x4 acc[4][4] = {};
  const short* Ag = (const short*)A;
  const short* Bg = (const short*)Wt;
  int srow = tid >> 2, sq = tid & 3;
  for (int k0 = 0; k0 < K; k0 += 32) {
#pragma unroll
    for (int h = 0; h < 2; h++) {
      int r = srow + (h << 6);
      uint4 va = *(const uint4*)&Ag[(size_t)(m0 + r) * lda + k0 + sq * 8];
      *(uint4*)&As[r][sq * 8] = va;
      uint4 vb = *(const uint4*)&Bg[(size_t)(n0 + r) * ldw + k0 + sq * 8];
      *(uint4*)&Bs[r][sq * 8] = vb;
    }
    __syncthreads();
    short8 a[4], b[4];
#pragma unroll
    for (int mi = 0; mi < 4; mi++)
      a[mi] = *(const short8*)&As[wm + mi * 16 + l16][quad * 8];
#pragma unroll
    for (int ni = 0; ni < 4; ni++)
      b[ni] = *(const short8*)&Bs[wn + ni * 16 + l16][quad * 8];
#pragma unroll
    for (int mi = 0; mi < 4; mi++)
#pragma unroll
      for (int ni = 0; ni < 4; ni++)
        acc[mi][ni] = __builtin_amdgcn_mfma_f32_16x16x32_bf16(
            a[mi], b[ni], acc[mi][ni], 0, 0, 0);
    __syncthreads();
  }
  float bn[4];
#pragma unroll
  for (int ni = 0; ni < 4; ni++) bn[ni] = bias[n0 + wn + ni * 16 + l16];
#pragma unroll
  for (int mi = 0; mi < 4; mi++)
#pragma unroll
    for (int ni = 0; ni < 4; ni++) {
      int n = n0 + wn + ni * 16 + l16;
#pragma unroll
      for (int r = 0; r < 4; r++) {
        int m = m0 + wm + mi * 16 + quad * 4 + r;
        float v = fmaxf(acc[mi][ni][r] + bn[ni], 0.f);
        if (OUT_BF16)
          ((__hip_bfloat16*)Y)[(size_t)m * ldy + n] = (__hip_bfloat16)v;
        else
          ((float*)Y)[(size_t)m * ldy + n] = v;
      }
    }
}

// ---------------------------------------------------------------------------
// Multi-job bf16 MFMA GEMM.
// ---------------------------------------------------------------------------
struct GJobs {
  const short* A[3];
  const short* W[3];
  const float* bias[3];
  __hip_bfloat16* Y[3];
  int lda[3], ldw[3], ldy[3], N[3], K[3], xt[3], off[3];
};

__global__ __launch_bounds__(256) void gemm_mfma_multi(GJobs g)
{
  __shared__ __align__(16) short As[128][40];
  __shared__ __align__(16) short Bs[128][40];
  int bid = blockIdx.x;
  int j = 0;
#pragma unroll
  for (int t = 1; t < 3; t++)
    if (bid >= g.off[t]) j = t;
  int rel = bid - g.off[j];
  int xt = g.xt[j];
  int m0 = (rel / xt) << 7, n0 = (rel % xt) << 7;
  int lda = g.lda[j], ldw = g.ldw[j], ldy = g.ldy[j], K = g.K[j];
  const short* Ag = g.A[j];
  const short* Bg = g.W[j];
  const float* bias = g.bias[j];
  __hip_bfloat16* Y = g.Y[j];

  int tid = threadIdx.x;
  int wave = tid >> 6, lane = tid & 63;
  int quad = lane >> 4, l16 = lane & 15;
  int wm = (wave >> 1) << 6, wn = (wave & 1) << 6;
  f32x4 acc[4][4] = {};
  int srow = tid >> 2, sq = tid & 3;
  for (int k0 = 0; k0 < K; k0 += 32) {
#pragma unroll
    for (int h = 0; h < 2; h++) {
      int r = srow + (h << 6);
      uint4 va = *(const uint4*)&Ag[(size_t)(m0 + r) * lda + k0 + sq * 8];
      *(uint4*)&As[r][sq * 8] = va;
      uint4 vb = *(const uint4*)&Bg[(size_t)(n0 + r) * ldw + k0 + sq * 8];
      *(uint4*)&Bs[r][sq * 8] = vb;
    }
    __syncthreads();
    short8 a[4], b[4];
#pragma unroll
    for (int mi = 0; mi < 4; mi++)
      a[mi] = *(const short8*)&As[wm + mi * 16 + l16][quad * 8];
#pragma unroll
    for (int ni = 0; ni < 4; ni++)
      b[ni] = *(const short8*)&Bs[wn + ni * 16 + l16][quad * 8];
#pragma unroll
    for (int mi = 0; mi < 4; mi++)
#pragma unroll
      for (int ni = 0; ni < 4; ni++)
        acc[mi][ni] = __builtin_amdgcn_mfma_f32_16x16x32_bf16(
            a[mi], b[ni], acc[mi][ni], 0, 0, 0);
    __syncthreads();
  }
  float bn[4];
#pragma unroll
  for (int ni = 0; ni < 4; ni++) bn[ni] = bias[n0 + wn + ni * 16 + l16];
#pragma unroll
  for (int mi = 0; mi < 4; mi++)
#pragma unroll
    for (int ni = 0; ni < 4; ni++) {
      int n = n0 + wn + ni * 16 + l16;
#pragma unroll
      for (int r = 0; r < 4; r++) {
        int m = m0 + wm + mi * 16 + quad * 4 + r;
        float v = fmaxf(acc[mi][ni][r] + bn[ni], 0.f);
        Y[(size_t)m * ldy + n] = (__hip_bfloat16)v;
      }
    }
}

// ---------------------------------------------------------------------------
// fc2 + out head fused.
// ---------------------------------------------------------------------------
__global__ __launch_bounds__(256) void gemm_fc2_out(
    const __hip_bfloat16* __restrict__ A,
    const __hip_bfloat16* __restrict__ Wt,
    const float* __restrict__ bias,
    const float* __restrict__ wout,
    const float* __restrict__ bout,
    float* __restrict__ out)
{
  __shared__ __align__(16) short As[128][40];
  __shared__ __align__(16) short Bs[128][40];
  __shared__ float red[128][2];
  const int N = 128, K = 256, lda = 256, ldw = 256;
  int tid = threadIdx.x;
  int wave = tid >> 6, lane = tid & 63;
  int quad = lane >> 4, l16 = lane & 15;
  int m0 = blockIdx.y << 7;
  int wm = (wave >> 1) << 6, wn = (wave & 1) << 6;
  f32x4 acc[4][4] = {};
  const short* Ag = (const short*)A;
  const short* Bg = (const short*)Wt;
  int srow = tid >> 2, sq = tid & 3;
  for (int k0 = 0; k0 < K; k0 += 32) {
#pragma unroll
    for (int h = 0; h < 2; h++) {
      int r = srow + (h << 6);
      uint4 va = *(const uint4*)&Ag[(size_t)(m0 + r) * lda + k0 + sq * 8];
      *(uint4*)&As[r][sq * 8] = va;
      uint4 vb = *(const uint4*)&Bg[(size_t)(r % N) * ldw + k0 + sq * 8];
      *(uint4*)&Bs[r][sq * 8] = vb;
    }
    __syncthreads();
    short8 a[4], b[4];
#pragma unroll
    for (int mi = 0; mi < 4; mi++)
      a[mi] = *(const short8*)&As[wm + mi * 16 + l16][quad * 8];
#pragma unroll
    for (int ni = 0; ni < 4; ni++)
      b[ni] = *(const short8*)&Bs[wn + ni * 16 + l16][quad * 8];
#pragma unroll
    for (int mi = 0; mi < 4; mi++)
#pragma unroll
      for (int ni = 0; ni < 4; ni++)
        acc[mi][ni] = __builtin_amdgcn_mfma_f32_16x16x32_bf16(
            a[mi], b[ni], acc[mi][ni], 0, 0, 0);
    __syncthreads();
  }
  float bn[4], wo[4];
#pragma unroll
  for (int ni = 0; ni < 4; ni++) {
    int n = wn + ni * 16 + l16;
    bn[ni] = bias[n];
    wo[ni] = wout[n];
  }
  float sacc[4][4];
#pragma unroll
  for (int mi = 0; mi < 4; mi++)
#pragma unroll
    for (int r = 0; r < 4; r++) {
      float s = 0.f;
#pragma unroll
      for (int ni = 0; ni < 4; ni++)
        s += fmaxf(acc[mi][ni][r] + bn[ni], 0.f) * wo[ni];
      sacc[mi][r] = s;
    }
#pragma unroll
  for (int off = 1; off < 16; off <<= 1)
#pragma unroll
    for (int mi = 0; mi < 4; mi++)
#pragma unroll
      for (int r = 0; r < 4; r++)
        sacc[mi][r] += __shfl_xor(sacc[mi][r], off);
  int wp = wave & 1;
  if (l16 == 0) {
#pragma unroll
    for (int mi = 0; mi < 4; mi++)
#pragma unroll
      for (int r = 0; r < 4; r++)
        red[wm + mi * 16 + quad * 4 + r][wp] = sacc[mi][r];
  }
  __syncthreads();
  if (tid < 128) {
    float s = red[tid][0] + red[tid][1] + bout[0];
    out[(size_t)(m0 + tid)] = 1.f / (1.f + expf(-s));
  }
}

// ---------------------------------------------------------------------------
// SA1 KNN v9 — v8 + (a) surv capped at 256/query (expected ~38; provable
// overflow fallback re-scatters into the then-dead lmins region whose 1024
// entries are the worst case: 32 quads <= T x 32 keys) -> LDS 44->19 KB,
// occupancy ~3->7 blocks/CU; (b) XCD-aware swizzle: batch = blk&7 so each
// XCD's blocks touch one batch's G1 slice (0.5 MB << 4 MB L2). Same T,
// same survivor sets, exact ranks -> bit-identical selection & X1.
// ---------------------------------------------------------------------------
__global__ __launch_bounds__(256) void knn_mean4(
    const float* __restrict__ X,
    const float* __restrict__ G1,
    float* __restrict__ X1,
    __hip_bfloat16* __restrict__ X1b,
    __hip_bfloat16* __restrict__ X1lo,
    float* __restrict__ nrmX1)
{
  int blk = blockIdx.x;
  int qb = ((blk & 7) << 11) + ((blk >> 3) << 2);
  int base = qb & ~2047;
  int tid = threadIdx.x;
  int wave = tid >> 6, lane = tid & 63;
  __shared__ unsigned long long lmins[4][256];  // dead after thr; reused as ovbuf
  __shared__ unsigned long long qmins[4][64];
  __shared__ unsigned long long thr[4];
  __shared__ unsigned long long surv[4][256];
  __shared__ int scnt[4];
  __shared__ int selidx[4][32];
  if (tid < 4) scnt[tid] = 0;
  float xj[8], yj[8];
#pragma unroll
  for (int u = 0; u < 8; u++) {
    int j = (u << 8) + tid;
    float2 c = *(const float2*)&X[(size_t)(base + j) * 2];
    xj[u] = c.x;
    yj[u] = c.y;
  }
  unsigned long long key[4][8];
#pragma unroll
  for (int g = 0; g < 4; g++) {
    float qx = X[(size_t)(qb + g) * 2];
    float qy = X[(size_t)(qb + g) * 2 + 1];
    unsigned long long lm = ~0ull;
#pragma unroll
    for (int u = 0; u < 8; u++) {
      float dx = xj[u] - qx;
      float dy = yj[u] - qy;
      float d2 = dx * dx + dy * dy;
      key[g][u] = ((unsigned long long)__float_as_uint(d2) << 32) |
                  (unsigned)((u << 8) + tid);
      lm = umin64(lm, key[g][u]);
    }
    lmins[g][tid] = lm;
  }
  __syncthreads();
  {
    int g = wave;
    unsigned long long qm =
        umin64(umin64(lmins[g][lane], lmins[g][lane + 64]),
               umin64(lmins[g][lane + 128], lmins[g][lane + 192]));
    qmins[g][lane] = qm;
    int rank = 0;
    for (int i = 0; i < 64; i++) rank += (qmins[g][i] < qm);
    if (rank == 31) thr[g] = qm;  // exactly one lane (unique keys)
  }
  __syncthreads();
#pragma unroll
  for (int g = 0; g < 4; g++) {
    unsigned long long T = thr[g];
#pragma unroll
    for (int u = 0; u < 8; u++) {
      if (key[g][u] <= T) {
        int p = atomicAdd(&scnt[g], 1);
        if (p < 256) surv[g][p] = key[g][u];
      }
    }
  }
  __syncthreads();
  int ovf[4] = {scnt[0], scnt[1], scnt[2], scnt[3]};  // uniform snapshot
  {
    int g = wave;
    int s = ovf[g];
    if (s <= 256) {
      for (int i = lane; i < s; i += 64) {
        unsigned long long c = surv[g][i];
        int r = 0;
        for (int j2 = 0; j2 < s; j2++) r += (surv[g][j2] < c);
        if (r < 32) selidx[g][r] = (int)(c & 0xffffffffULL);
      }
    }
  }
  if (ovf[0] > 256 || ovf[1] > 256 || ovf[2] > 256 || ovf[3] > 256) {
    // Rare exact fallback: full re-scatter into lmins region (<=1024).
    unsigned long long* ob = &lmins[0][0];
    for (int g = 0; g < 4; g++) {
      if (ovf[g] <= 256) continue;
      __syncthreads();
      if (tid == 0) scnt[g] = 0;
      __syncthreads();
      unsigned long long T = thr[g];
#pragma unroll
      for (int u = 0; u < 8; u++) {
        if (key[g][u] <= T) {
          int p = atomicAdd(&scnt[g], 1);
          ob[p] = key[g][u];
        }
      }
      __syncthreads();
      int s2 = scnt[g];
      for (int i = tid; i < s2; i += 256) {
        unsigned long long c = ob[i];
        int r = 0;
        for (int j2 = 0; j2 < s2; j2++) r += (ob[j2] < c);
        if (r < 32) selidx[g][r] = (int)(c & 0xffffffffULL);
      }
    }
    __syncthreads();
  }
  {
    int g = wave;
    float acc = 0.f;
#pragma unroll 8
    for (int sI = 0; sI < 32; sI++)
      acc += G1[(size_t)(base + selidx[g][sI]) * 64 + lane];
    float v = acc * (1.0f / 32.0f);
    int q = qb + g;
    X1[(size_t)q * 64 + lane] = v;
    __hip_bfloat16 hi = (__hip_bfloat16)v;
    X1b[(size_t)q * 64 + lane] = hi;
    X1lo[(size_t)q * 64 + lane] = (__hip_bfloat16)(v - (float)hi);
    float nv = v * v;
#pragma unroll
    for (int off = 32; off > 0; off >>= 1) nv += __shfl_down(nv, off);
    if (lane == 0) nrmX1[q] = nv;
  }
}

// ---------------------------------------------------------------------------
// Ball-query pass 1 v6 — split-bf16 MFMA gram + exact-decision guard band
// (round-12 version, passing; masks bit-identical).
// ---------------------------------------------------------------------------
template <int C>
__global__ __launch_bounds__(256) void ball_mask_mfma(
    const float* __restrict__ F32,
    const __hip_bfloat16* __restrict__ Fhi,
    const __hip_bfloat16* __restrict__ Flo,
    const float* __restrict__ nrm,
    unsigned long long* __restrict__ mask,
    float r2)
{
  __shared__ __align__(16) short Qh[128][40];
  __shared__ __align__(16) short Ql[128][40];
  __shared__ __align__(16) short Ch[128][40];
  __shared__ __align__(16) short Cl[128][40];
  __shared__ unsigned int tw[128][4];
  __shared__ float nqs[128], ncs[128];
  int tid = threadIdx.x;
  int p = blockIdx.x;
  int qt = 0;
  while (p >= 16 - qt) { p -= 16 - qt; qt++; }
  int ct = qt + p;
  int b0 = blockIdx.y << 11;
  int q0 = b0 + (qt << 7), c0 = b0 + (ct << 7);
  tw[tid >> 1][(tid & 1) * 2] = 0;
  tw[tid >> 1][(tid & 1) * 2 + 1] = 0;
  if (tid < 128) nqs[tid] = nrm[q0 + tid];
  else ncs[tid - 128] = nrm[c0 + tid - 128];

  int wave = tid >> 6, lane = tid & 63;
  int quad = lane >> 4, l16 = lane & 15;
  int wm = (wave >> 1) << 6, wn = (wave & 1) << 6;
  f32x4 acc[4][4] = {};
  const short* QH = (const short*)Fhi;
  const short* QL = (const short*)Flo;
  int srow = tid >> 2, sq = tid & 3;
  for (int k0 = 0; k0 < C; k0 += 32) {
#pragma unroll
    for (int h = 0; h < 2; h++) {
      int r = srow + (h << 6);
      *(uint4*)&Qh[r][sq * 8] = *(const uint4*)&QH[(size_t)(q0 + r) * C + k0 + sq * 8];
      *(uint4*)&Ql[r][sq * 8] = *(const uint4*)&QL[(size_t)(q0 + r) * C + k0 + sq * 8];
      *(uint4*)&Ch[r][sq * 8] = *(const uint4*)&QH[(size_t)(c0 + r) * C + k0 + sq * 8];
      *(uint4*)&Cl[r][sq * 8] = *(const uint4*)&QL[(size_t)(c0 + r) * C + k0 + sq * 8];
    }
    __syncthreads();
    short8 ah[4], al[4];
#pragma unroll
    for (int mi = 0; mi < 4; mi++) {
      ah[mi] = *(const short8*)&Qh[wm + mi * 16 + l16][quad * 8];
      al[mi] = *(const short8*)&Ql[wm + mi * 16 + l16][quad * 8];
    }
#pragma unroll
    for (int ni = 0; ni < 4; ni++) {
      short8 bh = *(const short8*)&Ch[wn + ni * 16 + l16][quad * 8];
      short8 bl = *(const short8*)&Cl[wn + ni * 16 + l16][quad * 8];
#pragma unroll
      for (int mi = 0; mi < 4; mi++) {
        acc[mi][ni] = __builtin_amdgcn_mfma_f32_16x16x32_bf16(ah[mi], bh, acc[mi][ni], 0, 0, 0);
        acc[mi][ni] = __builtin_amdgcn_mfma_f32_16x16x32_bf16(ah[mi], bl, acc[mi][ni], 0, 0, 0);
        acc[mi][ni] = __builtin_amdgcn_mfma_f32_16x16x32_bf16(al[mi], bh, acc[mi][ni], 0, 0, 0);
      }
    }
    __syncthreads();
  }
  unsigned long long memb = 0, fb = 0;
#pragma unroll
  for (int mi = 0; mi < 4; mi++)
#pragma unroll
    for (int ni = 0; ni < 4; ni++)
#pragma unroll
      for (int r = 0; r < 4; r++) {
        int e = (mi << 4) | (ni << 2) | r;
        float nqv = nqs[wm + mi * 16 + quad * 4 + r];
        float ncv = ncs[wn + ni * 16 + l16];
        float d2a = nqv + ncv - 2.f * acc[mi][ni][r];
        float eps = 4.0e-5f * (nqv + ncv) + 1.0e-6f;
        if (d2a < r2 - eps) memb |= 1ull << e;
        else if (d2a <= r2 + eps) fb |= 1ull << e;
      }
  while (fb) {
    int e = __builtin_ctzll(fb);
    fb &= fb - 1;
    int mi = e >> 4, ni = (e >> 2) & 3, r = e & 3;
    int qrow = q0 + wm + mi * 16 + quad * 4 + r;
    int ccol = c0 + wn + ni * 16 + l16;
    float a2 = 0.f;
    for (int k = 0; k < C; k++) {
      float d = F32[(size_t)qrow * C + k] - F32[(size_t)ccol * C + k];
      a2 = fmaf(d, d, a2);
    }
    if (a2 <= r2) memb |= 1ull << e;
  }
#pragma unroll
  for (int ni = 0; ni < 4; ni++) {
    int cl = wn + ni * 16 + l16;
    unsigned int w0b = 0, w1b = 0;
#pragma unroll
    for (int mi = 0; mi < 4; mi++)
#pragma unroll
      for (int r = 0; r < 4; r++)
        if (memb & (1ull << ((mi << 4) | (ni << 2) | r))) {
          unsigned int bitpos = ((mi & 1) << 4) | (quad << 2) | r;
          if (mi < 2) w0b |= 1u << bitpos;
          else w1b |= 1u << bitpos;
        }
    if (w0b) atomicOr(&tw[cl][(wm >> 5)], w0b);
    if (w1b) atomicOr(&tw[cl][(wm >> 5) + 1], w1b);
  }
  __syncthreads();
  {
    int row = tid >> 1, half = tid & 1;
    int wq = row >> 5, sb = row & 31;
    unsigned int lo = 0, hi = 0;
    for (int j = 0; j < 32; j++) {
      lo |= ((tw[half * 64 + j][wq] >> sb) & 1u) << j;
      hi |= ((tw[half * 64 + 32 + j][wq] >> sb) & 1u) << j;
    }
    mask[(size_t)(q0 + row) * 32 + (ct << 1) + half] =
        ((unsigned long long)hi << 32) | lo;
  }
  if (qt != ct) {
    int row = tid >> 1, word = tid & 1;
    unsigned long long v = (unsigned long long)tw[row][word * 2] |
                           ((unsigned long long)tw[row][word * 2 + 1] << 32);
    mask[(size_t)(c0 + row) * 32 + (qt << 1) + word] = v;
  }
}

// ---------------------------------------------------------------------------
// Ball-query pass 2 (XCD-swizzled block->query mapping; fp32 accumulate).
// ---------------------------------------------------------------------------
template <typename TIn>
__global__ void ball_gather_kernel(
    const unsigned long long* __restrict__ mask,
    const TIn* __restrict__ H, int CH,
    float* __restrict__ Yf, __hip_bfloat16* __restrict__ Yb,
    __hip_bfloat16* __restrict__ Ylo, float* __restrict__ nrm,
    int ldy, int S)
{
  int blk = blockIdx.x;
  int q = ((blk & 7) << 11) + (blk >> 3);  // XCD-local batch slice
  int base = q & ~2047;
  int tid = threadIdx.x;
  __shared__ int idxl[64];
  __shared__ float wtab[64];
  __shared__ float npart[4];
  __shared__ int scount;
  if (tid < 32) {
    unsigned long long w = mask[(size_t)q * 32 + tid];
    int cnt = __popcll(w);
    int inc = cnt;
#pragma unroll
    for (int off = 1; off < 32; off <<= 1) {
      int o = __shfl_up(inc, off);
      if (tid >= off) inc += o;
    }
    if (tid == 31) scount = inc;
    int p = inc - cnt;
    while (w && p < 64) {
      int j = (tid << 6) + __builtin_ctzll(w);
      w &= w - 1;
      idxl[p++] = j;
    }
  }
  __syncthreads();
  int c = scount;
  if (tid < 64) {
    int p = tid;
    int cnt = (p < c && p < S) ? ((S - 1 - p) / c + 1) : 0;
    wtab[p] = (float)cnt / (float)S;
  }
  __syncthreads();
  float acc = 0.f;
  int lim = c < S ? c : S;
#pragma unroll 8
  for (int s = 0; s < lim; s++)
    acc += wtab[s] * (float)H[(size_t)(base + idxl[s]) * CH + tid];
  if (Yf) Yf[(size_t)q * ldy + tid] = acc;
  if (Yb) Yb[(size_t)q * ldy + tid] = (__hip_bfloat16)acc;
  if (Ylo) {
    __hip_bfloat16 hi = (__hip_bfloat16)acc;
    Ylo[(size_t)q * ldy + tid] = (__hip_bfloat16)(acc - (float)hi);
  }
  if (nrm) {
    float nv = acc * acc;
#pragma unroll
    for (int off = 32; off > 0; off >>= 1) nv += __shfl_down(nv, off);
    if ((tid & 63) == 0) npart[tid >> 6] = nv;
    __syncthreads();
    if (tid == 0) {
      float t = 0.f;
      for (int w = 0; w < (blockDim.x >> 6); w++) t += npart[w];
      nrm[q] = t;
    }
  }
}

// ---------------------------------------------------------------------------
extern "C" void kernel_launch(void* const* d_in, const int* in_sizes, int n_in,
                              void* d_out, int out_size, void* d_ws,
                              size_t ws_size, hipStream_t stream)
{
  const float* x      = (const float*)d_in[0];
  const float* sa1_w0 = (const float*)d_in[1];
  const float* sa1_b0 = (const float*)d_in[2];
  const float* sa1_w1 = (const float*)d_in[3];
  const float* sa1_b1 = (const float*)d_in[4];
  const float* sa2_w0 = (const float*)d_in[5];
  const float* sa2_b0 = (const float*)d_in[6];
  const float* sa2_w1 = (const float*)d_in[7];
  const float* sa2_b1 = (const float*)d_in[8];
  const float* sa3_w0 = (const float*)d_in[9];
  const float* sa3_b0 = (const float*)d_in[10];
  const float* sa3_w1 = (const float*)d_in[11];
  const float* sa3_b1 = (const float*)d_in[12];
  const float* fp1_w0 = (const float*)d_in[13];
  const float* fp1_b0 = (const float*)d_in[14];
  const float* fp1_w1 = (const float*)d_in[15];
  const float* fp1_b1 = (const float*)d_in[16];
  const float* fp2_w0 = (const float*)d_in[17];
  const float* fp2_b0 = (const float*)d_in[18];
  const float* fp2_w1 = (const float*)d_in[19];
  const float* fp2_b1 = (const float*)d_in[20];
  const float* fc1_w  = (const float*)d_in[21];
  const float* fc1_b  = (const float*)d_in[22];
  const float* fc2_w  = (const float*)d_in[23];
  const float* fc2_b  = (const float*)d_in[24];
  const float* out_w  = (const float*)d_in[25];
  const float* out_b  = (const float*)d_in[26];
  float* out = (float*)d_out;

  const size_t M = M_ROWS;
  float* ws = (float*)d_ws;
  float* T   = ws;             // [0,256)
  float* G1  = ws + M * 256;   // [256,320)
  float* X1  = ws + M * 320;   // [320,384)
  float* X2  = ws + M * 384;   // [384,512)
  float* H2  = ws + M * 512;   // [512,640)
  __hip_bfloat16* H3b16 = (__hip_bfloat16*)(ws + M * 640);  // [640,768)
  unsigned long long* MASK = (unsigned long long*)(ws + M * 896);  // [896,960)
  __hip_bfloat16* X1b = (__hip_bfloat16*)(ws + M * 960);    // [960,992)
  __hip_bfloat16* X2b = (__hip_bfloat16*)(ws + M * 992);    // [992,1056)
  __hip_bfloat16* TB0 = (__hip_bfloat16*)(ws + M * 1056);   // [1056,1184)
  __hip_bfloat16* TB1 = (__hip_bfloat16*)(ws + M * 1184);   // [1184,1440)
  __hip_bfloat16* TB2 = (__hip_bfloat16*)(ws + M * 1440);   // [1440,1568)
  __hip_bfloat16* G   = (__hip_bfloat16*)(ws + M * 1568);   // [1568,2080)
  __hip_bfloat16* H3b = (__hip_bfloat16*)(ws + M * 2080);   // [2080,2208)
  __hip_bfloat16* WB  = (__hip_bfloat16*)(ws + M * 2208);   // weights
  __hip_bfloat16* X1lo = (__hip_bfloat16*)(ws + M * 2240);  // [2240,2272)
  __hip_bfloat16* X2lo = (__hip_bfloat16*)(ws + M * 2272);  // [2272,2336)
  float* nrmX1 = ws + M * 2336;                             // [2336,2337)
  float* nrmX2 = ws + M * 2337;                             // [2337,2338)
  if (ws_size < (size_t)M * 2340 * sizeof(float)) return;
  __hip_bfloat16* w_sa3_0 = WB;               // 256x128
  __hip_bfloat16* w_sa3_1 = w_sa3_0 + 32768;  // 256x256
  __hip_bfloat16* w_fp1_0 = w_sa3_1 + 65536;  // 512x128
  __hip_bfloat16* w_fp1_1 = w_fp1_0 + 65536;  // 512x512
  __hip_bfloat16* w_fp2_0 = w_fp1_1 + 262144; // 256x64
  __hip_bfloat16* w_fp2_1 = w_fp2_0 + 16384;  // 256x256
  __hip_bfloat16* w_fc1   = w_fp2_1 + 65536;  // 256x1024
  __hip_bfloat16* w_fc2   = w_fc1 + 262144;   // 128x256

  dim3 blk(256);
  TJobs jb;
  const float* srcs[8] = {sa3_w0, sa3_w1, fp1_w0, fp1_w1, fp2_w0, fp2_w1, fc1_w, fc2_w};
  __hip_bfloat16* dsts[8] = {w_sa3_0, w_sa3_1, w_fp1_0, w_fp1_1, w_fp2_0, w_fp2_1, w_fc1, w_fc2};
  int Ks[8] = {128, 256, 128, 512, 64, 256, 1024, 256};
  int Ns[8] = {256, 256, 512, 512, 256, 256, 256, 128};
  int off = 0;
  for (int i = 0; i < 8; i++) {
    jb.W[i] = srcs[i]; jb.Wt[i] = dsts[i];
    jb.K[i] = Ks[i]; jb.N[i] = Ns[i];
    jb.bx[i] = Ns[i] >> 5;
    jb.off[i] = off;
    off += (Ns[i] >> 5) * (Ks[i] >> 5);
  }
  transpose_cast_all<<<off, blk, 0, stream>>>(jb);

  // SA1 fused (bit-identical G1) + knn v9.
  sa1_fused<<<256, blk, 0, stream>>>(x, sa1_w0, sa1_b0, sa1_w1, sa1_b1, G1);
  knn_mean4<<<4096, 256, 0, stream>>>(x, G1, X1, X1b, X1lo, nrmX1);
  // SA2 (fp32 exact) + ball64 (MFMA gram) + gather2.
  gemm_bias_relu<<<dim3(2, 256), blk, 0, stream>>>(X1, 64, sa2_w0, sa2_b0, T, 128, 128, 64);
  gemm_bias_relu<<<dim3(2, 256), blk, 0, stream>>>(T, 128, sa2_w1, sa2_b1, H2, 128, 128, 128);
  ball_mask_mfma<64><<<dim3(136, 8), blk, 0, stream>>>(X1, X1b, X1lo, nrmX1, MASK, 0.2f * 0.2f);
  ball_gather_kernel<float><<<16384, 128, 0, stream>>>(MASK, H2, 128, X2, X2b, X2lo, nrmX2, 128, 32);
  // ball128 (MFMA gram), then the fused layer-1 and layer-2 GEMM triples.
  ball_mask_mfma<128><<<dim3(136, 8), blk, 0, stream>>>(X2, X2b, X2lo, nrmX2, MASK, 0.4f * 0.4f);
  {
    GJobs g1;
    g1.A[0] = (const short*)X2b; g1.W[0] = (const short*)w_sa3_0; g1.bias[0] = sa3_b0;
    g1.Y[0] = TB0; g1.lda[0] = 128; g1.ldw[0] = 128; g1.ldy[0] = 256; g1.N[0] = 256; g1.K[0] = 128;
    g1.A[1] = (const short*)X2b; g1.W[1] = (const short*)w_fp1_0; g1.bias[1] = fp1_b0;
    g1.Y[1] = TB1; g1.lda[1] = 128; g1.ldw[1] = 128; g1.ldy[1] = 512; g1.N[1] = 512; g1.K[1] = 128;
    g1.A[2] = (const short*)X1b; g1.W[2] = (const short*)w_fp2_0; g1.bias[2] = fp2_b0;
    g1.Y[2] = TB2; g1.lda[2] = 64; g1.ldw[2] = 64; g1.ldy[2] = 256; g1.N[2] = 256; g1.K[2] = 64;
    int tot1 = 0;
    for (int i = 0; i < 3; i++) {
      g1.xt[i] = g1.N[i] >> 7;
      g1.off[i] = tot1;
      tot1 += g1.xt[i] * 128;
    }
    gemm_mfma_multi<<<tot1, blk, 0, stream>>>(g1);

    GJobs g2;
    g2.A[0] = (const short*)TB0; g2.W[0] = (const short*)w_sa3_1; g2.bias[0] = sa3_b1;
    g2.Y[0] = H3b16; g2.lda[0] = 256; g2.ldw[0] = 256; g2.ldy[0] = 256; g2.N[0] = 256; g2.K[0] = 256;
    g2.A[1] = (const short*)TB1; g2.W[1] = (const short*)w_fp1_1; g2.bias[1] = fp1_b1;
    g2.Y[1] = G + 256; g2.lda[1] = 512; g2.ldw[1] = 512; g2.ldy[1] = 1024; g2.N[1] = 512; g2.K[1] = 512;
    g2.A[2] = (const short*)TB2; g2.W[2] = (const short*)w_fp2_1; g2.bias[2] = fp2_b1;
    g2.Y[2] = G; g2.lda[2] = 256; g2.ldw[2] = 256; g2.ldy[2] = 1024; g2.N[2] = 256; g2.K[2] = 256;
    int tot2 = 0;
    for (int i = 0; i < 3; i++) {
      g2.xt[i] = g2.N[i] >> 7;
      g2.off[i] = tot2;
      tot2 += g2.xt[i] * 128;
    }
    gemm_mfma_multi<<<tot2, blk, 0, stream>>>(g2);
  }
  // gather3 fills G[768:1024] from sa3 output.
  ball_gather_kernel<__hip_bfloat16><<<16384, 256, 0, stream>>>(
      MASK, H3b16, 256, nullptr, G + 768, nullptr, nullptr, 1024, 64);
  // Head: fc1 (bf16), then fc2+out fused.
  gemm_mfma<true><<<dim3(2, 128), blk, 0, stream>>>(G, 1024, w_fc1, 1024, fc1_b, H3b, 256, 256, 1024);
  gemm_fc2_out<<<dim3(1, 128), blk, 0, stream>>>(H3b, w_fc2, fc2_b, out_w, out_b, out);
}

// Round 16
// 355.498 us; speedup vs baseline: 1.3831x; 1.0390x over previous
//
#include <hip/hip_runtime.h>
#include <hip/hip_bf16.h>
#include <cstdint>

#define M_ROWS 16384

typedef __attribute__((ext_vector_type(8))) short short8;
typedef __attribute__((ext_vector_type(4))) float f32x4;

__device__ __forceinline__ unsigned long long umin64(unsigned long long a,
                                                     unsigned long long b) {
  return a < b ? a : b;
}

// ---------------------------------------------------------------------------
// PROLOGUE: 8 weight transposes (fp32 KxN -> bf16 NxK) + SA1 fused MLP in
// one dispatch (independent start-of-graph work; blockIdx-branched).
// SA1 chains identical to the two-gemm version -> bit-identical G1.
// ---------------------------------------------------------------------------
struct TJobs {
  const float* W[8];
  __hip_bfloat16* Wt[8];
  int K[8], N[8], bx[8], off[8];
};

__global__ __launch_bounds__(256) void prologue_kernel(
    TJobs jb, int toff,
    const float* __restrict__ x,
    const float* __restrict__ w0,
    const float* __restrict__ b0,
    const float* __restrict__ w1,
    const float* __restrict__ b1,
    float* __restrict__ G1)
{
  __shared__ float tile[32][33];
  __shared__ __align__(16) float Ts[64][68];
  __shared__ __align__(16) float Ws[64][68];
  __shared__ float xs[64][2];
  __shared__ float w0s[2][64];
  __shared__ float b0s[64];
  int bid = blockIdx.x;
  int tid = threadIdx.x;
  if (bid < toff) {
    int j = 0;
#pragma unroll
    for (int t = 1; t < 8; t++)
      if (bid >= jb.off[t]) j = t;
    int rel = bid - jb.off[j];
    int K = jb.K[j], N = jb.N[j];
    const float* W = jb.W[j];
    __hip_bfloat16* Wt = jb.Wt[j];
    int n0 = (rel % jb.bx[j]) << 5, k0 = (rel / jb.bx[j]) << 5;
    int c = tid & 31, i0 = tid >> 5;
#pragma unroll
    for (int p = 0; p < 4; p++) {
      int i = i0 + p * 8;
      tile[i][c] = W[(size_t)(k0 + i) * N + n0 + c];
    }
    __syncthreads();
#pragma unroll
    for (int p = 0; p < 4; p++) {
      int r = i0 + p * 8;
      Wt[(size_t)(n0 + r) * K + k0 + c] = (__hip_bfloat16)tile[c][r];
    }
    return;
  }
  // SA1 path
  int m0 = (bid - toff) << 6;
  if (tid < 128) {
    ((float*)xs)[tid] = x[(size_t)m0 * 2 + tid];
  } else if (tid < 192) {
    int n = tid - 128;
    w0s[0][n] = w0[n];
    b0s[n] = b0[n];
  } else {
    int n = tid - 192;
    w0s[1][n] = w0[64 + n];
  }
#pragma unroll
  for (int i = 0; i < 16; i++) {
    int idx = tid + (i << 8);
    int k = idx >> 6, n = idx & 63;
    Ws[k][n] = w1[(size_t)k * 64 + n];
  }
  __syncthreads();
#pragma unroll
  for (int i = 0; i < 16; i++) {
    int idx = tid + (i << 8);
    int m = idx >> 6, n = idx & 63;
    float acc = 0.f;
    acc += xs[m][0] * w0s[0][n];
    acc += xs[m][1] * w0s[1][n];
    Ts[n][m] = fmaxf(acc + b0s[n], 0.f);
  }
  __syncthreads();
  int tx = tid & 15, ty = tid >> 4;
  float acc[4][4] = {};
  for (int k = 0; k < 64; k++) {
    float4 a4 = *(const float4*)&Ts[k][ty << 2];
    float4 b4 = *(const float4*)&Ws[k][tx << 2];
    float av[4] = {a4.x, a4.y, a4.z, a4.w};
    float bv[4] = {b4.x, b4.y, b4.z, b4.w};
#pragma unroll
    for (int i = 0; i < 4; i++)
#pragma unroll
      for (int j = 0; j < 4; j++)
        acc[i][j] += av[i] * bv[j];
  }
  float4 bb = *(const float4*)&b1[tx << 2];
  float bv[4] = {bb.x, bb.y, bb.z, bb.w};
#pragma unroll
  for (int i = 0; i < 4; i++) {
    int m = m0 + (ty << 2) + i;
    float4 o;
    o.x = fmaxf(acc[i][0] + bv[0], 0.f);
    o.y = fmaxf(acc[i][1] + bv[1], 0.f);
    o.z = fmaxf(acc[i][2] + bv[2], 0.f);
    o.w = fmaxf(acc[i][3] + bv[3], 0.f);
    *(float4*)&G1[(size_t)m * 64 + (tx << 2)] = o;
  }
}

// ---------------------------------------------------------------------------
// SA2 fused: H2 = relu(relu(X1@w0+b0)@w1+b1) for a 64-row tile per block.
// Stage 1 (K=64, ascending-k) -> T in registers -> bias+relu -> LDS Ts[k][m].
// Stage 2 (K=128, ascending-k) streams w1 k-chunks vs LDS-resident T.
// Per-element fma chains identical to the two-GEMM version -> H2
// bit-identical; kills one dispatch + 16 MB of T round-trip.
// ---------------------------------------------------------------------------
__global__ __launch_bounds__(256) void sa2_fused(
    const float* __restrict__ X1,   // (16384,64)
    const float* __restrict__ w0,   // (64,128)
    const float* __restrict__ b0,   // 128
    const float* __restrict__ w1,   // (128,128)
    const float* __restrict__ b1,   // 128
    float* __restrict__ H2)         // (16384,128)
{
  __shared__ __align__(16) float Ts[128][68];  // stage-2 A: Ts[k][m]
  __shared__ __align__(16) float Bs[16][132];  // w0/w1 k-chunk staging
  __shared__ __align__(16) float Xs[16][68];   // X1 k-slice [k][m]
  int tid = threadIdx.x;
  int tx = tid & 15, ty = tid >> 4;  // n-group (8 wide), m-group (4)
  int m0 = blockIdx.x << 6;
  float acc1[4][8] = {};
  for (int k0 = 0; k0 < 64; k0 += 16) {
#pragma unroll
    for (int i = 0; i < 4; i++) {
      int idx = tid + (i << 8);
      int m = idx >> 4, k = idx & 15;
      Xs[k][m] = X1[(size_t)(m0 + m) * 64 + k0 + k];
    }
#pragma unroll
    for (int i = 0; i < 8; i++) {
      int idx = tid + (i << 8);
      int n = idx & 127, k = idx >> 7;
      Bs[k][n] = w0[(size_t)(k0 + k) * 128 + n];
    }
    __syncthreads();
#pragma unroll
    for (int k = 0; k < 16; k++) {
      float av[4], bv[8];
#pragma unroll
      for (int i = 0; i < 4; i++) av[i] = Xs[k][ty * 4 + i];
#pragma unroll
      for (int j = 0; j < 8; j++) bv[j] = Bs[k][tx * 8 + j];
#pragma unroll
      for (int i = 0; i < 4; i++)
#pragma unroll
        for (int j = 0; j < 8; j++)
          acc1[i][j] += av[i] * bv[j];
    }
    __syncthreads();
  }
#pragma unroll
  for (int j = 0; j < 8; j++) {
    float bbv = b0[tx * 8 + j];
#pragma unroll
    for (int i = 0; i < 4; i++)
      Ts[tx * 8 + j][ty * 4 + i] = fmaxf(acc1[i][j] + bbv, 0.f);
  }
  __syncthreads();
  float acc2[4][8] = {};
  for (int k0 = 0; k0 < 128; k0 += 16) {
#pragma unroll
    for (int i = 0; i < 8; i++) {
      int idx = tid + (i << 8);
      int n = idx & 127, k = idx >> 7;
      Bs[k][n] = w1[(size_t)(k0 + k) * 128 + n];
    }
    __syncthreads();
#pragma unroll
    for (int k = 0; k < 16; k++) {
      float av[4], bv[8];
#pragma unroll
      for (int i = 0; i < 4; i++) av[i] = Ts[k0 + k][ty * 4 + i];
#pragma unroll
      for (int j = 0; j < 8; j++) bv[j] = Bs[k][tx * 8 + j];
#pragma unroll
      for (int i = 0; i < 4; i++)
#pragma unroll
        for (int j = 0; j < 8; j++)
          acc2[i][j] += av[i] * bv[j];
    }
    __syncthreads();
  }
#pragma unroll
  for (int i = 0; i < 4; i++) {
    int m = m0 + ty * 4 + i;
#pragma unroll
    for (int j = 0; j < 8; j++) {
      int n = tx * 8 + j;
      H2[(size_t)m * 128 + n] = fmaxf(acc2[i][j] + b1[n], 0.f);
    }
  }
}

// ---------------------------------------------------------------------------
// bf16 MFMA GEMM (single-job; used for fc1).
// ---------------------------------------------------------------------------
template <bool OUT_BF16>
__global__ __launch_bounds__(256) void gemm_mfma(
    const __hip_bfloat16* __restrict__ A, int lda,
    const __hip_bfloat16* __restrict__ Wt, int ldw,
    const float* __restrict__ bias,
    void* __restrict__ Y, int ldy, int N, int K)
{
  __shared__ __align__(16) short As[128][40];
  __shared__ __align__(16) short Bs[128][40];
  int tid = threadIdx.x;
  int wave = tid >> 6, lane = tid & 63;
  int quad = lane >> 4, l16 = lane & 15;
  int m0 = blockIdx.y << 7, n0 = blockIdx.x << 7;
  int wm = (wave >> 1) << 6, wn = (wave & 1) << 6;
  f32x4 acc[4][4] = {};
  const short* Ag = (const short*)A;
  const short* Bg = (const short*)Wt;
  int srow = tid >> 2, sq = tid & 3;
  for (int k0 = 0; k0 < K; k0 += 32) {
#pragma unroll
    for (int h = 0; h < 2; h++) {
      int r = srow + (h << 6);
      uint4 va = *(const uint4*)&Ag[(size_t)(m0 + r) * lda + k0 + sq * 8];
      *(uint4*)&As[r][sq * 8] = va;
      uint4 vb = *(const uint4*)&Bg[(size_t)(n0 + r) * ldw + k0 + sq * 8];
      *(uint4*)&Bs[r][sq * 8] = vb;
    }
    __syncthreads();
    short8 a[4], b[4];
#pragma unroll
    for (int mi = 0; mi < 4; mi++)
      a[mi] = *(const short8*)&As[wm + mi * 16 + l16][quad * 8];
#pragma unroll
    for (int ni = 0; ni < 4; ni++)
      b[ni] = *(const short8*)&Bs[wn + ni * 16 + l16][quad * 8];
#pragma unroll
    for (int mi = 0; mi < 4; mi++)
#pragma unroll
      for (int ni = 0; ni < 4; ni++)
        acc[mi][ni] = __builtin_amdgcn_mfma_f32_16x16x32_bf16(
            a[mi], b[ni], acc[mi][ni], 0, 0, 0);
    __syncthreads();
  }
  float bn[4];
#pragma unroll
  for (int ni = 0; ni < 4; ni++) bn[ni] = bias[n0 + wn + ni * 16 + l16];
#pragma unroll
  for (int mi = 0; mi < 4; mi++)
#pragma unroll
    for (int ni = 0; ni < 4; ni++) {
      int n = n0 + wn + ni * 16 + l16;
#pragma unroll
      for (int r = 0; r < 4; r++) {
        int m = m0 + wm + mi * 16 + quad * 4 + r;
        float v = fmaxf(acc[mi][ni][r] + bn[ni], 0.f);
        if (OUT_BF16)
          ((__hip_bfloat16*)Y)[(size_t)m * ldy + n] = (__hip_bfloat16)v;
        else
          ((float*)Y)[(size_t)m * ldy + n] = v;
      }
    }
}

// ---------------------------------------------------------------------------
// Multi-job bf16 MFMA GEMM.
// ---------------------------------------------------------------------------
struct GJobs {
  const short* A[3];
  const short* W[3];
  const float* bias[3];
  __hip_bfloat16* Y[3];
  int lda[3], ldw[3], ldy[3], N[3], K[3], xt[3], off[3];
};

__global__ __launch_bounds__(256) void gemm_mfma_multi(GJobs g)
{
  __shared__ __align__(16) short As[128][40];
  __shared__ __align__(16) short Bs[128][40];
  int bid = blockIdx.x;
  int j = 0;
#pragma unroll
  for (int t = 1; t < 3; t++)
    if (bid >= g.off[t]) j = t;
  int rel = bid - g.off[j];
  int xt = g.xt[j];
  int m0 = (rel / xt) << 7, n0 = (rel % xt) << 7;
  int lda = g.lda[j], ldw = g.ldw[j], ldy = g.ldy[j], K = g.K[j];
  const short* Ag = g.A[j];
  const short* Bg = g.W[j];
  const float* bias = g.bias[j];
  __hip_bfloat16* Y = g.Y[j];

  int tid = threadIdx.x;
  int wave = tid >> 6, lane = tid & 63;
  int quad = lane >> 4, l16 = lane & 15;
  int wm = (wave >> 1) << 6, wn = (wave & 1) << 6;
  f32x4 acc[4][4] = {};
  int srow = tid >> 2, sq = tid & 3;
  for (int k0 = 0; k0 < K; k0 += 32) {
#pragma unroll
    for (int h = 0; h < 2; h++) {
      int r = srow + (h << 6);
      uint4 va = *(const uint4*)&Ag[(size_t)(m0 + r) * lda + k0 + sq * 8];
      *(uint4*)&As[r][sq * 8] = va;
      uint4 vb = *(const uint4*)&Bg[(size_t)(n0 + r) * ldw + k0 + sq * 8];
      *(uint4*)&Bs[r][sq * 8] = vb;
    }
    __syncthreads();
    short8 a[4], b[4];
#pragma unroll
    for (int mi = 0; mi < 4; mi++)
      a[mi] = *(const short8*)&As[wm + mi * 16 + l16][quad * 8];
#pragma unroll
    for (int ni = 0; ni < 4; ni++)
      b[ni] = *(const short8*)&Bs[wn + ni * 16 + l16][quad * 8];
#pragma unroll
    for (int mi = 0; mi < 4; mi++)
#pragma unroll
      for (int ni = 0; ni < 4; ni++)
        acc[mi][ni] = __builtin_amdgcn_mfma_f32_16x16x32_bf16(
            a[mi], b[ni], acc[mi][ni], 0, 0, 0);
    __syncthreads();
  }
  float bn[4];
#pragma unroll
  for (int ni = 0; ni < 4; ni++) bn[ni] = bias[n0 + wn + ni * 16 + l16];
#pragma unroll
  for (int mi = 0; mi < 4; mi++)
#pragma unroll
    for (int ni = 0; ni < 4; ni++) {
      int n = n0 + wn + ni * 16 + l16;
#pragma unroll
      for (int r = 0; r < 4; r++) {
        int m = m0 + wm + mi * 16 + quad * 4 + r;
        float v = fmaxf(acc[mi][ni][r] + bn[ni], 0.f);
        Y[(size_t)m * ldy + n] = (__hip_bfloat16)v;
      }
    }
}

// ---------------------------------------------------------------------------
// fc2 + out head fused.
// ---------------------------------------------------------------------------
__global__ __launch_bounds__(256) void gemm_fc2_out(
    const __hip_bfloat16* __restrict__ A,
    const __hip_bfloat16* __restrict__ Wt,
    const float* __restrict__ bias,
    const float* __restrict__ wout,
    const float* __restrict__ bout,
    float* __restrict__ out)
{
  __shared__ __align__(16) short As[128][40];
  __shared__ __align__(16) short Bs[128][40];
  __shared__ float red[128][2];
  const int N = 128, K = 256, lda = 256, ldw = 256;
  int tid = threadIdx.x;
  int wave = tid >> 6, lane = tid & 63;
  int quad = lane >> 4, l16 = lane & 15;
  int m0 = blockIdx.y << 7;
  int wm = (wave >> 1) << 6, wn = (wave & 1) << 6;
  f32x4 acc[4][4] = {};
  const short* Ag = (const short*)A;
  const short* Bg = (const short*)Wt;
  int srow = tid >> 2, sq = tid & 3;
  for (int k0 = 0; k0 < K; k0 += 32) {
#pragma unroll
    for (int h = 0; h < 2; h++) {
      int r = srow + (h << 6);
      uint4 va = *(const uint4*)&Ag[(size_t)(m0 + r) * lda + k0 + sq * 8];
      *(uint4*)&As[r][sq * 8] = va;
      uint4 vb = *(const uint4*)&Bg[(size_t)(r % N) * ldw + k0 + sq * 8];
      *(uint4*)&Bs[r][sq * 8] = vb;
    }
    __syncthreads();
    short8 a[4], b[4];
#pragma unroll
    for (int mi = 0; mi < 4; mi++)
      a[mi] = *(const short8*)&As[wm + mi * 16 + l16][quad * 8];
#pragma unroll
    for (int ni = 0; ni < 4; ni++)
      b[ni] = *(const short8*)&Bs[wn + ni * 16 + l16][quad * 8];
#pragma unroll
    for (int mi = 0; mi < 4; mi++)
#pragma unroll
      for (int ni = 0; ni < 4; ni++)
        acc[mi][ni] = __builtin_amdgcn_mfma_f32_16x16x32_bf16(
            a[mi], b[ni], acc[mi][ni], 0, 0, 0);
    __syncthreads();
  }
  float bn[4], wo[4];
#pragma unroll
  for (int ni = 0; ni < 4; ni++) {
    int n = wn + ni * 16 + l16;
    bn[ni] = bias[n];
    wo[ni] = wout[n];
  }
  float sacc[4][4];
#pragma unroll
  for (int mi = 0; mi < 4; mi++)
#pragma unroll
    for (int r = 0; r < 4; r++) {
      float s = 0.f;
#pragma unroll
      for (int ni = 0; ni < 4; ni++)
        s += fmaxf(acc[mi][ni][r] + bn[ni], 0.f) * wo[ni];
      sacc[mi][r] = s;
    }
#pragma unroll
  for (int off = 1; off < 16; off <<= 1)
#pragma unroll
    for (int mi = 0; mi < 4; mi++)
#pragma unroll
      for (int r = 0; r < 4; r++)
        sacc[mi][r] += __shfl_xor(sacc[mi][r], off);
  int wp = wave & 1;
  if (l16 == 0) {
#pragma unroll
    for (int mi = 0; mi < 4; mi++)
#pragma unroll
      for (int r = 0; r < 4; r++)
        red[wm + mi * 16 + quad * 4 + r][wp] = sacc[mi][r];
  }
  __syncthreads();
  if (tid < 128) {
    float s = red[tid][0] + red[tid][1] + bout[0];
    out[(size_t)(m0 + tid)] = 1.f / (1.f + expf(-s));
  }
}

// ---------------------------------------------------------------------------
// SA1 KNN v9 (round-15 version, passing — bit-identical selection).
// ---------------------------------------------------------------------------
__global__ __launch_bounds__(256) void knn_mean4(
    const float* __restrict__ X,
    const float* __restrict__ G1,
    float* __restrict__ X1,
    __hip_bfloat16* __restrict__ X1b,
    __hip_bfloat16* __restrict__ X1lo,
    float* __restrict__ nrmX1)
{
  int blk = blockIdx.x;
  int qb = ((blk & 7) << 11) + ((blk >> 3) << 2);
  int base = qb & ~2047;
  int tid = threadIdx.x;
  int wave = tid >> 6, lane = tid & 63;
  __shared__ unsigned long long lmins[4][256];
  __shared__ unsigned long long qmins[4][64];
  __shared__ unsigned long long thr[4];
  __shared__ unsigned long long surv[4][256];
  __shared__ int scnt[4];
  __shared__ int selidx[4][32];
  if (tid < 4) scnt[tid] = 0;
  float xj[8], yj[8];
#pragma unroll
  for (int u = 0; u < 8; u++) {
    int j = (u << 8) + tid;
    float2 c = *(const float2*)&X[(size_t)(base + j) * 2];
    xj[u] = c.x;
    yj[u] = c.y;
  }
  unsigned long long key[4][8];
#pragma unroll
  for (int g = 0; g < 4; g++) {
    float qx = X[(size_t)(qb + g) * 2];
    float qy = X[(size_t)(qb + g) * 2 + 1];
    unsigned long long lm = ~0ull;
#pragma unroll
    for (int u = 0; u < 8; u++) {
      float dx = xj[u] - qx;
      float dy = yj[u] - qy;
      float d2 = dx * dx + dy * dy;
      key[g][u] = ((unsigned long long)__float_as_uint(d2) << 32) |
                  (unsigned)((u << 8) + tid);
      lm = umin64(lm, key[g][u]);
    }
    lmins[g][tid] = lm;
  }
  __syncthreads();
  {
    int g = wave;
    unsigned long long qm =
        umin64(umin64(lmins[g][lane], lmins[g][lane + 64]),
               umin64(lmins[g][lane + 128], lmins[g][lane + 192]));
    qmins[g][lane] = qm;
    int rank = 0;
    for (int i = 0; i < 64; i++) rank += (qmins[g][i] < qm);
    if (rank == 31) thr[g] = qm;
  }
  __syncthreads();
#pragma unroll
  for (int g = 0; g < 4; g++) {
    unsigned long long T = thr[g];
#pragma unroll
    for (int u = 0; u < 8; u++) {
      if (key[g][u] <= T) {
        int p = atomicAdd(&scnt[g], 1);
        if (p < 256) surv[g][p] = key[g][u];
      }
    }
  }
  __syncthreads();
  int ovf[4] = {scnt[0], scnt[1], scnt[2], scnt[3]};
  {
    int g = wave;
    int s = ovf[g];
    if (s <= 256) {
      for (int i = lane; i < s; i += 64) {
        unsigned long long c = surv[g][i];
        int r = 0;
        for (int j2 = 0; j2 < s; j2++) r += (surv[g][j2] < c);
        if (r < 32) selidx[g][r] = (int)(c & 0xffffffffULL);
      }
    }
  }
  if (ovf[0] > 256 || ovf[1] > 256 || ovf[2] > 256 || ovf[3] > 256) {
    unsigned long long* ob = &lmins[0][0];
    for (int g = 0; g < 4; g++) {
      if (ovf[g] <= 256) continue;
      __syncthreads();
      if (tid == 0) scnt[g] = 0;
      __syncthreads();
      unsigned long long T = thr[g];
#pragma unroll
      for (int u = 0; u < 8; u++) {
        if (key[g][u] <= T) {
          int p = atomicAdd(&scnt[g], 1);
          ob[p] = key[g][u];
        }
      }
      __syncthreads();
      int s2 = scnt[g];
      for (int i = tid; i < s2; i += 256) {
        unsigned long long c = ob[i];
        int r = 0;
        for (int j2 = 0; j2 < s2; j2++) r += (ob[j2] < c);
        if (r < 32) selidx[g][r] = (int)(c & 0xffffffffULL);
      }
    }
    __syncthreads();
  }
  {
    int g = wave;
    float acc = 0.f;
#pragma unroll 8
    for (int sI = 0; sI < 32; sI++)
      acc += G1[(size_t)(base + selidx[g][sI]) * 64 + lane];
    float v = acc * (1.0f / 32.0f);
    int q = qb + g;
    X1[(size_t)q * 64 + lane] = v;
    __hip_bfloat16 hi = (__hip_bfloat16)v;
    X1b[(size_t)q * 64 + lane] = hi;
    X1lo[(size_t)q * 64 + lane] = (__hip_bfloat16)(v - (float)hi);
    float nv = v * v;
#pragma unroll
    for (int off = 32; off > 0; off >>= 1) nv += __shfl_down(nv, off);
    if (lane == 0) nrmX1[q] = nv;
  }
}

// ---------------------------------------------------------------------------
// Ball-query pass 1 — split-bf16 MFMA gram + exact-decision guard band
// (round-12 version, passing; masks bit-identical).
// ---------------------------------------------------------------------------
template <int C>
__global__ __launch_bounds__(256) void ball_mask_mfma(
    const float* __restrict__ F32,
    const __hip_bfloat16* __restrict__ Fhi,
    const __hip_bfloat16* __restrict__ Flo,
    const float* __restrict__ nrm,
    unsigned long long* __restrict__ mask,
    float r2)
{
  __shared__ __align__(16) short Qh[128][40];
  __shared__ __align__(16) short Ql[128][40];
  __shared__ __align__(16) short Ch[128][40];
  __shared__ __align__(16) short Cl[128][40];
  __shared__ unsigned int tw[128][4];
  __shared__ float nqs[128], ncs[128];
  int tid = threadIdx.x;
  int p = blockIdx.x;
  int qt = 0;
  while (p >= 16 - qt) { p -= 16 - qt; qt++; }
  int ct = qt + p;
  int b0 = blockIdx.y << 11;
  int q0 = b0 + (qt << 7), c0 = b0 + (ct << 7);
  tw[tid >> 1][(tid & 1) * 2] = 0;
  tw[tid >> 1][(tid & 1) * 2 + 1] = 0;
  if (tid < 128) nqs[tid] = nrm[q0 + tid];
  else ncs[tid - 128] = nrm[c0 + tid - 128];

  int wave = tid >> 6, lane = tid & 63;
  int quad = lane >> 4, l16 = lane & 15;
  int wm = (wave >> 1) << 6, wn = (wave & 1) << 6;
  f32x4 acc[4][4] = {};
  const short* QH = (const short*)Fhi;
  const short* QL = (const short*)Flo;
  int srow = tid >> 2, sq = tid & 3;
  for (int k0 = 0; k0 < C; k0 += 32) {
#pragma unroll
    for (int h = 0; h < 2; h++) {
      int r = srow + (h << 6);
      *(uint4*)&Qh[r][sq * 8] = *(const uint4*)&QH[(size_t)(q0 + r) * C + k0 + sq * 8];
      *(uint4*)&Ql[r][sq * 8] = *(const uint4*)&QL[(size_t)(q0 + r) * C + k0 + sq * 8];
      *(uint4*)&Ch[r][sq * 8] = *(const uint4*)&QH[(size_t)(c0 + r) * C + k0 + sq * 8];
      *(uint4*)&Cl[r][sq * 8] = *(const uint4*)&QL[(size_t)(c0 + r) * C + k0 + sq * 8];
    }
    __syncthreads();
    short8 ah[4], al[4];
#pragma unroll
    for (int mi = 0; mi < 4; mi++) {
      ah[mi] = *(const short8*)&Qh[wm + mi * 16 + l16][quad * 8];
      al[mi] = *(const short8*)&Ql[wm + mi * 16 + l16][quad * 8];
    }
#pragma unroll
    for (int ni = 0; ni < 4; ni++) {
      short8 bh = *(const short8*)&Ch[wn + ni * 16 + l16][quad * 8];
      short8 bl = *(const short8*)&Cl[wn + ni * 16 + l16][quad * 8];
#pragma unroll
      for (int mi = 0; mi < 4; mi++) {
        acc[mi][ni] = __builtin_amdgcn_mfma_f32_16x16x32_bf16(ah[mi], bh, acc[mi][ni], 0, 0, 0);
        acc[mi][ni] = __builtin_amdgcn_mfma_f32_16x16x32_bf16(ah[mi], bl, acc[mi][ni], 0, 0, 0);
        acc[mi][ni] = __builtin_amdgcn_mfma_f32_16x16x32_bf16(al[mi], bh, acc[mi][ni], 0, 0, 0);
      }
    }
    __syncthreads();
  }
  unsigned long long memb = 0, fb = 0;
#pragma unroll
  for (int mi = 0; mi < 4; mi++)
#pragma unroll
    for (int ni = 0; ni < 4; ni++)
#pragma unroll
      for (int r = 0; r < 4; r++) {
        int e = (mi << 4) | (ni << 2) | r;
        float nqv = nqs[wm + mi * 16 + quad * 4 + r];
        float ncv = ncs[wn + ni * 16 + l16];
        float d2a = nqv + ncv - 2.f * acc[mi][ni][r];
        float eps = 4.0e-5f * (nqv + ncv) + 1.0e-6f;
        if (d2a < r2 - eps) memb |= 1ull << e;
        else if (d2a <= r2 + eps) fb |= 1ull << e;
      }
  while (fb) {
    int e = __builtin_ctzll(fb);
    fb &= fb - 1;
    int mi = e >> 4, ni = (e >> 2) & 3, r = e & 3;
    int qrow = q0 + wm + mi * 16 + quad * 4 + r;
    int ccol = c0 + wn + ni * 16 + l16;
    float a2 = 0.f;
    for (int k = 0; k < C; k++) {
      float d = F32[(size_t)qrow * C + k] - F32[(size_t)ccol * C + k];
      a2 = fmaf(d, d, a2);
    }
    if (a2 <= r2) memb |= 1ull << e;
  }
#pragma unroll
  for (int ni = 0; ni < 4; ni++) {
    int cl = wn + ni * 16 + l16;
    unsigned int w0b = 0, w1b = 0;
#pragma unroll
    for (int mi = 0; mi < 4; mi++)
#pragma unroll
      for (int r = 0; r < 4; r++)
        if (memb & (1ull << ((mi << 4) | (ni << 2) | r))) {
          unsigned int bitpos = ((mi & 1) << 4) | (quad << 2) | r;
          if (mi < 2) w0b |= 1u << bitpos;
          else w1b |= 1u << bitpos;
        }
    if (w0b) atomicOr(&tw[cl][(wm >> 5)], w0b);
    if (w1b) atomicOr(&tw[cl][(wm >> 5) + 1], w1b);
  }
  __syncthreads();
  {
    int row = tid >> 1, half = tid & 1;
    int wq = row >> 5, sb = row & 31;
    unsigned int lo = 0, hi = 0;
    for (int j = 0; j < 32; j++) {
      lo |= ((tw[half * 64 + j][wq] >> sb) & 1u) << j;
      hi |= ((tw[half * 64 + 32 + j][wq] >> sb) & 1u) << j;
    }
    mask[(size_t)(q0 + row) * 32 + (ct << 1) + half] =
        ((unsigned long long)hi << 32) | lo;
  }
  if (qt != ct) {
    int row = tid >> 1, word = tid & 1;
    unsigned long long v = (unsigned long long)tw[row][word * 2] |
                           ((unsigned long long)tw[row][word * 2 + 1] << 32);
    mask[(size_t)(c0 + row) * 32 + (qt << 1) + word] = v;
  }
}

// ---------------------------------------------------------------------------
// Ball-query pass 2 (XCD-swizzled; fp32 accumulate).
// ---------------------------------------------------------------------------
template <typename TIn>
__global__ void ball_gather_kernel(
    const unsigned long long* __restrict__ mask,
    const TIn* __restrict__ H, int CH,
    float* __restrict__ Yf, __hip_bfloat16* __restrict__ Yb,
    __hip_bfloat16* __restrict__ Ylo, float* __restrict__ nrm,
    int ldy, int S)
{
  int blk = blockIdx.x;
  int q = ((blk & 7) << 11) + (blk >> 3);
  int base = q & ~2047;
  int tid = threadIdx.x;
  __shared__ int idxl[64];
  __shared__ float wtab[64];
  __shared__ float npart[4];
  __shared__ int scount;
  if (tid < 32) {
    unsigned long long w = mask[(size_t)q * 32 + tid];
    int cnt = __popcll(w);
    int inc = cnt;
#pragma unroll
    for (int off = 1; off < 32; off <<= 1) {
      int o = __shfl_up(inc, off);
      if (tid >= off) inc += o;
    }
    if (tid == 31) scount = inc;
    int p = inc - cnt;
    while (w && p < 64) {
      int j = (tid << 6) + __builtin_ctzll(w);
      w &= w - 1;
      idxl[p++] = j;
    }
  }
  __syncthreads();
  int c = scount;
  if (tid < 64) {
    int p = tid;
    int cnt = (p < c && p < S) ? ((S - 1 - p) / c + 1) : 0;
    wtab[p] = (float)cnt / (float)S;
  }
  __syncthreads();
  float acc = 0.f;
  int lim = c < S ? c : S;
#pragma unroll 8
  for (int s = 0; s < lim; s++)
    acc += wtab[s] * (float)H[(size_t)(base + idxl[s]) * CH + tid];
  if (Yf) Yf[(size_t)q * ldy + tid] = acc;
  if (Yb) Yb[(size_t)q * ldy + tid] = (__hip_bfloat16)acc;
  if (Ylo) {
    __hip_bfloat16 hi = (__hip_bfloat16)acc;
    Ylo[(size_t)q * ldy + tid] = (__hip_bfloat16)(acc - (float)hi);
  }
  if (nrm) {
    float nv = acc * acc;
#pragma unroll
    for (int off = 32; off > 0; off >>= 1) nv += __shfl_down(nv, off);
    if ((tid & 63) == 0) npart[tid >> 6] = nv;
    __syncthreads();
    if (tid == 0) {
      float t = 0.f;
      for (int w = 0; w < (blockDim.x >> 6); w++) t += npart[w];
      nrm[q] = t;
    }
  }
}

// ---------------------------------------------------------------------------
extern "C" void kernel_launch(void* const* d_in, const int* in_sizes, int n_in,
                              void* d_out, int out_size, void* d_ws,
                              size_t ws_size, hipStream_t stream)
{
  const float* x      = (const float*)d_in[0];
  const float* sa1_w0 = (const float*)d_in[1];
  const float* sa1_b0 = (const float*)d_in[2];
  const float* sa1_w1 = (const float*)d_in[3];
  const float* sa1_b1 = (const float*)d_in[4];
  const float* sa2_w0 = (const float*)d_in[5];
  const float* sa2_b0 = (const float*)d_in[6];
  const float* sa2_w1 = (const float*)d_in[7];
  const float* sa2_b1 = (const float*)d_in[8];
  const float* sa3_w0 = (const float*)d_in[9];
  const float* sa3_b0 = (const float*)d_in[10];
  const float* sa3_w1 = (const float*)d_in[11];
  const float* sa3_b1 = (const float*)d_in[12];
  const float* fp1_w0 = (const float*)d_in[13];
  const float* fp1_b0 = (const float*)d_in[14];
  const float* fp1_w1 = (const float*)d_in[15];
  const float* fp1_b1 = (const float*)d_in[16];
  const float* fp2_w0 = (const float*)d_in[17];
  const float* fp2_b0 = (const float*)d_in[18];
  const float* fp2_w1 = (const float*)d_in[19];
  const float* fp2_b1 = (const float*)d_in[20];
  const float* fc1_w  = (const float*)d_in[21];
  const float* fc1_b  = (const float*)d_in[22];
  const float* fc2_w  = (const float*)d_in[23];
  const float* fc2_b  = (const float*)d_in[24];
  const float* out_w  = (const float*)d_in[25];
  const float* out_b  = (const float*)d_in[26];
  float* out = (float*)d_out;

  const size_t M = M_ROWS;
  float* ws = (float*)d_ws;
  float* G1  = ws + M * 256;   // [256,320)
  float* X1  = ws + M * 320;   // [320,384)
  float* X2  = ws + M * 384;   // [384,512)
  float* H2  = ws + M * 512;   // [512,640)
  __hip_bfloat16* H3b16 = (__hip_bfloat16*)(ws + M * 640);  // [640,768)
  unsigned long long* MASK = (unsigned long long*)(ws + M * 896);  // [896,960)
  __hip_bfloat16* X1b = (__hip_bfloat16*)(ws + M * 960);    // [960,992)
  __hip_bfloat16* X2b = (__hip_bfloat16*)(ws + M * 992);    // [992,1056)
  __hip_bfloat16* TB0 = (__hip_bfloat16*)(ws + M * 1056);   // [1056,1184)
  __hip_bfloat16* TB1 = (__hip_bfloat16*)(ws + M * 1184);   // [1184,1440)
  __hip_bfloat16* TB2 = (__hip_bfloat16*)(ws + M * 1440);   // [1440,1568)
  __hip_bfloat16* G   = (__hip_bfloat16*)(ws + M * 1568);   // [1568,2080)
  __hip_bfloat16* H3b = (__hip_bfloat16*)(ws + M * 2080);   // [2080,2208)
  __hip_bfloat16* WB  = (__hip_bfloat16*)(ws + M * 2208);   // weights
  __hip_bfloat16* X1lo = (__hip_bfloat16*)(ws + M * 2240);  // [2240,2272)
  __hip_bfloat16* X2lo = (__hip_bfloat16*)(ws + M * 2272);  // [2272,2336)
  float* nrmX1 = ws + M * 2336;                             // [2336,2337)
  float* nrmX2 = ws + M * 2337;                             // [2337,2338)
  if (ws_size < (size_t)M * 2340 * sizeof(float)) return;
  __hip_bfloat16* w_sa3_0 = WB;               // 256x128
  __hip_bfloat16* w_sa3_1 = w_sa3_0 + 32768;  // 256x256
  __hip_bfloat16* w_fp1_0 = w_sa3_1 + 65536;  // 512x128
  __hip_bfloat16* w_fp1_1 = w_fp1_0 + 65536;  // 512x512
  __hip_bfloat16* w_fp2_0 = w_fp1_1 + 262144; // 256x64
  __hip_bfloat16* w_fp2_1 = w_fp2_0 + 16384;  // 256x256
  __hip_bfloat16* w_fc1   = w_fp2_1 + 65536;  // 256x1024
  __hip_bfloat16* w_fc2   = w_fc1 + 262144;   // 128x256

  dim3 blk(256);
  TJobs jb;
  const float* srcs[8] = {sa3_w0, sa3_w1, fp1_w0, fp1_w1, fp2_w0, fp2_w1, fc1_w, fc2_w};
  __hip_bfloat16* dsts[8] = {w_sa3_0, w_sa3_1, w_fp1_0, w_fp1_1, w_fp2_0, w_fp2_1, w_fc1, w_fc2};
  int Ks[8] = {128, 256, 128, 512, 64, 256, 1024, 256};
  int Ns[8] = {256, 256, 512, 512, 256, 256, 256, 128};
  int off = 0;
  for (int i = 0; i < 8; i++) {
    jb.W[i] = srcs[i]; jb.Wt[i] = dsts[i];
    jb.K[i] = Ks[i]; jb.N[i] = Ns[i];
    jb.bx[i] = Ns[i] >> 5;
    jb.off[i] = off;
    off += (Ns[i] >> 5) * (Ks[i] >> 5);
  }
  // Prologue: weight transposes + SA1 fused in one dispatch.
  prologue_kernel<<<off + 256, blk, 0, stream>>>(jb, off, x, sa1_w0, sa1_b0,
                                                 sa1_w1, sa1_b1, G1);
  knn_mean4<<<4096, 256, 0, stream>>>(x, G1, X1, X1b, X1lo, nrmX1);
  // SA2 fused (bit-identical H2) + ball64 + gather2.
  sa2_fused<<<256, blk, 0, stream>>>(X1, sa2_w0, sa2_b0, sa2_w1, sa2_b1, H2);
  ball_mask_mfma<64><<<dim3(136, 8), blk, 0, stream>>>(X1, X1b, X1lo, nrmX1, MASK, 0.2f * 0.2f);
  ball_gather_kernel<float><<<16384, 128, 0, stream>>>(MASK, H2, 128, X2, X2b, X2lo, nrmX2, 128, 32);
  // ball128, then the fused layer-1 and layer-2 GEMM triples.
  ball_mask_mfma<128><<<dim3(136, 8), blk, 0, stream>>>(X2, X2b, X2lo, nrmX2, MASK, 0.4f * 0.4f);
  {
    GJobs g1;
    g1.A[0] = (const short*)X2b; g1.W[0] = (const short*)w_sa3_0; g1.bias[0] = sa3_b0;
    g1.Y[0] = TB0; g1.lda[0] = 128; g1.ldw[0] = 128; g1.ldy[0] = 256; g1.N[0] = 256; g1.K[0] = 128;
    g1.A[1] = (const short*)X2b; g1.W[1] = (const short*)w_fp1_0; g1.bias[1] = fp1_b0;
    g1.Y[1] = TB1; g1.lda[1] = 128; g1.ldw[1] = 128; g1.ldy[1] = 512; g1.N[1] = 512; g1.K[1] = 128;
    g1.A[2] = (const short*)X1b; g1.W[2] = (const short*)w_fp2_0; g1.bias[2] = fp2_b0;
    g1.Y[2] = TB2; g1.lda[2] = 64; g1.ldw[2] = 64; g1.ldy[2] = 256; g1.N[2] = 256; g1.K[2] = 64;
    int tot1 = 0;
    for (int i = 0; i < 3; i++) {
      g1.xt[i] = g1.N[i] >> 7;
      g1.off[i] = tot1;
      tot1 += g1.xt[i] * 128;
    }
    gemm_mfma_multi<<<tot1, blk, 0, stream>>>(g1);

    GJobs g2;
    g2.A[0] = (const short*)TB0; g2.W[0] = (const short*)w_sa3_1; g2.bias[0] = sa3_b1;
    g2.Y[0] = H3b16; g2.lda[0] = 256; g2.ldw[0] = 256; g2.ldy[0] = 256; g2.N[0] = 256; g2.K[0] = 256;
    g2.A[1] = (const short*)TB1; g2.W[1] = (const short*)w_fp1_1; g2.bias[1] = fp1_b1;
    g2.Y[1] = G + 256; g2.lda[1] = 512; g2.ldw[1] = 512; g2.ldy[1] = 1024; g2.N[1] = 512; g2.K[1] = 512;
    g2.A[2] = (const short*)TB2; g2.W[2] = (const short*)w_fp2_1; g2.bias[2] = fp2_b1;
    g2.Y[2] = G; g2.lda[2] = 256; g2.ldw[2] = 256; g2.ldy[2] = 1024; g2.N[2] = 256; g2.K[2] = 256;
    int tot2 = 0;
    for (int i = 0; i < 3; i++) {
      g2.xt[i] = g2.N[i] >> 7;
      g2.off[i] = tot2;
      tot2 += g2.xt[i] * 128;
    }
    gemm_mfma_multi<<<tot2, blk, 0, stream>>>(g2);
  }
  // gather3 fills G[768:1024] from sa3 output.
  ball_gather_kernel<__hip_bfloat16><<<16384, 256, 0, stream>>>(
      MASK, H3b16, 256, nullptr, G + 768, nullptr, nullptr, 1024, 64);
  // Head: fc1 (bf16), then fc2+out fused.
  gemm_mfma<true><<<dim3(2, 128), blk, 0, stream>>>(G, 1024, w_fc1, 1024, fc1_b, H3b, 256, 256, 1024);
  gemm_fc2_out<<<dim3(1, 128), blk, 0, stream>>>(H3b, w_fc2, fc2_b, out_w, out_b, out);
}

// Round 17
// 341.785 us; speedup vs baseline: 1.4385x; 1.0401x over previous
//
#include <hip/hip_runtime.h>
#include <hip/hip_bf16.h>
#include <cstdint>

#define M_ROWS 16384

typedef __attribute__((ext_vector_type(8))) short short8;
typedef __attribute__((ext_vector_type(4))) float f32x4;

__device__ __forceinline__ unsigned long long umin64(unsigned long long a,
                                                     unsigned long long b) {
  return a < b ? a : b;
}

// ---------------------------------------------------------------------------
// PROLOGUE: 8 weight transposes + SA1 fused MLP in one dispatch.
// ---------------------------------------------------------------------------
struct TJobs {
  const float* W[8];
  __hip_bfloat16* Wt[8];
  int K[8], N[8], bx[8], off[8];
};

__global__ __launch_bounds__(256) void prologue_kernel(
    TJobs jb, int toff,
    const float* __restrict__ x,
    const float* __restrict__ w0,
    const float* __restrict__ b0,
    const float* __restrict__ w1,
    const float* __restrict__ b1,
    float* __restrict__ G1)
{
  __shared__ float tile[32][33];
  __shared__ __align__(16) float Ts[64][68];
  __shared__ __align__(16) float Ws[64][68];
  __shared__ float xs[64][2];
  __shared__ float w0s[2][64];
  __shared__ float b0s[64];
  int bid = blockIdx.x;
  int tid = threadIdx.x;
  if (bid < toff) {
    int j = 0;
#pragma unroll
    for (int t = 1; t < 8; t++)
      if (bid >= jb.off[t]) j = t;
    int rel = bid - jb.off[j];
    int K = jb.K[j], N = jb.N[j];
    const float* W = jb.W[j];
    __hip_bfloat16* Wt = jb.Wt[j];
    int n0 = (rel % jb.bx[j]) << 5, k0 = (rel / jb.bx[j]) << 5;
    int c = tid & 31, i0 = tid >> 5;
#pragma unroll
    for (int p = 0; p < 4; p++) {
      int i = i0 + p * 8;
      tile[i][c] = W[(size_t)(k0 + i) * N + n0 + c];
    }
    __syncthreads();
#pragma unroll
    for (int p = 0; p < 4; p++) {
      int r = i0 + p * 8;
      Wt[(size_t)(n0 + r) * K + k0 + c] = (__hip_bfloat16)tile[c][r];
    }
    return;
  }
  int m0 = (bid - toff) << 6;
  if (tid < 128) {
    ((float*)xs)[tid] = x[(size_t)m0 * 2 + tid];
  } else if (tid < 192) {
    int n = tid - 128;
    w0s[0][n] = w0[n];
    b0s[n] = b0[n];
  } else {
    int n = tid - 192;
    w0s[1][n] = w0[64 + n];
  }
#pragma unroll
  for (int i = 0; i < 16; i++) {
    int idx = tid + (i << 8);
    int k = idx >> 6, n = idx & 63;
    Ws[k][n] = w1[(size_t)k * 64 + n];
  }
  __syncthreads();
#pragma unroll
  for (int i = 0; i < 16; i++) {
    int idx = tid + (i << 8);
    int m = idx >> 6, n = idx & 63;
    float acc = 0.f;
    acc += xs[m][0] * w0s[0][n];
    acc += xs[m][1] * w0s[1][n];
    Ts[n][m] = fmaxf(acc + b0s[n], 0.f);
  }
  __syncthreads();
  int tx = tid & 15, ty = tid >> 4;
  float acc[4][4] = {};
  for (int k = 0; k < 64; k++) {
    float4 a4 = *(const float4*)&Ts[k][ty << 2];
    float4 b4 = *(const float4*)&Ws[k][tx << 2];
    float av[4] = {a4.x, a4.y, a4.z, a4.w};
    float bv[4] = {b4.x, b4.y, b4.z, b4.w};
#pragma unroll
    for (int i = 0; i < 4; i++)
#pragma unroll
      for (int j = 0; j < 4; j++)
        acc[i][j] += av[i] * bv[j];
  }
  float4 bb = *(const float4*)&b1[tx << 2];
  float bv[4] = {bb.x, bb.y, bb.z, bb.w};
#pragma unroll
  for (int i = 0; i < 4; i++) {
    int m = m0 + (ty << 2) + i;
    float4 o;
    o.x = fmaxf(acc[i][0] + bv[0], 0.f);
    o.y = fmaxf(acc[i][1] + bv[1], 0.f);
    o.z = fmaxf(acc[i][2] + bv[2], 0.f);
    o.w = fmaxf(acc[i][3] + bv[3], 0.f);
    *(float4*)&G1[(size_t)m * 64 + (tx << 2)] = o;
  }
}

// ---------------------------------------------------------------------------
// SA2 fused (round-16 version, passing; H2 bit-identical).
// ---------------------------------------------------------------------------
__global__ __launch_bounds__(256) void sa2_fused(
    const float* __restrict__ X1,
    const float* __restrict__ w0,
    const float* __restrict__ b0,
    const float* __restrict__ w1,
    const float* __restrict__ b1,
    float* __restrict__ H2)
{
  __shared__ __align__(16) float Ts[128][68];
  __shared__ __align__(16) float Bs[16][132];
  __shared__ __align__(16) float Xs[16][68];
  int tid = threadIdx.x;
  int tx = tid & 15, ty = tid >> 4;
  int m0 = blockIdx.x << 6;
  float acc1[4][8] = {};
  for (int k0 = 0; k0 < 64; k0 += 16) {
#pragma unroll
    for (int i = 0; i < 4; i++) {
      int idx = tid + (i << 8);
      int m = idx >> 4, k = idx & 15;
      Xs[k][m] = X1[(size_t)(m0 + m) * 64 + k0 + k];
    }
#pragma unroll
    for (int i = 0; i < 8; i++) {
      int idx = tid + (i << 8);
      int n = idx & 127, k = idx >> 7;
      Bs[k][n] = w0[(size_t)(k0 + k) * 128 + n];
    }
    __syncthreads();
#pragma unroll
    for (int k = 0; k < 16; k++) {
      float av[4], bv[8];
#pragma unroll
      for (int i = 0; i < 4; i++) av[i] = Xs[k][ty * 4 + i];
#pragma unroll
      for (int j = 0; j < 8; j++) bv[j] = Bs[k][tx * 8 + j];
#pragma unroll
      for (int i = 0; i < 4; i++)
#pragma unroll
        for (int j = 0; j < 8; j++)
          acc1[i][j] += av[i] * bv[j];
    }
    __syncthreads();
  }
#pragma unroll
  for (int j = 0; j < 8; j++) {
    float bbv = b0[tx * 8 + j];
#pragma unroll
    for (int i = 0; i < 4; i++)
      Ts[tx * 8 + j][ty * 4 + i] = fmaxf(acc1[i][j] + bbv, 0.f);
  }
  __syncthreads();
  float acc2[4][8] = {};
  for (int k0 = 0; k0 < 128; k0 += 16) {
#pragma unroll
    for (int i = 0; i < 8; i++) {
      int idx = tid + (i << 8);
      int n = idx & 127, k = idx >> 7;
      Bs[k][n] = w1[(size_t)(k0 + k) * 128 + n];
    }
    __syncthreads();
#pragma unroll
    for (int k = 0; k < 16; k++) {
      float av[4], bv[8];
#pragma unroll
      for (int i = 0; i < 4; i++) av[i] = Ts[k0 + k][ty * 4 + i];
#pragma unroll
      for (int j = 0; j < 8; j++) bv[j] = Bs[k][tx * 8 + j];
#pragma unroll
      for (int i = 0; i < 4; i++)
#pragma unroll
        for (int j = 0; j < 8; j++)
          acc2[i][j] += av[i] * bv[j];
    }
    __syncthreads();
  }
#pragma unroll
  for (int i = 0; i < 4; i++) {
    int m = m0 + ty * 4 + i;
#pragma unroll
    for (int j = 0; j < 8; j++) {
      int n = tx * 8 + j;
      H2[(size_t)m * 128 + n] = fmaxf(acc2[i][j] + b1[n], 0.f);
    }
  }
}

// ---------------------------------------------------------------------------
// bf16 MFMA GEMM (single-job; used for fc1).
// ---------------------------------------------------------------------------
template <bool OUT_BF16>
__global__ __launch_bounds__(256) void gemm_mfma(
    const __hip_bfloat16* __restrict__ A, int lda,
    const __hip_bfloat16* __restrict__ Wt, int ldw,
    const float* __restrict__ bias,
    void* __restrict__ Y, int ldy, int N, int K)
{
  __shared__ __align__(16) short As[128][40];
  __shared__ __align__(16) short Bs[128][40];
  int tid = threadIdx.x;
  int wave = tid >> 6, lane = tid & 63;
  int quad = lane >> 4, l16 = lane & 15;
  int m0 = blockIdx.y << 7, n0 = blockIdx.x << 7;
  int wm = (wave >> 1) << 6, wn = (wave & 1) << 6;
  f32x4 acc[4][4] = {};
  const short* Ag = (const short*)A;
  const short* Bg = (const short*)Wt;
  int srow = tid >> 2, sq = tid & 3;
  for (int k0 = 0; k0 < K; k0 += 32) {
#pragma unroll
    for (int h = 0; h < 2; h++) {
      int r = srow + (h << 6);
      uint4 va = *(const uint4*)&Ag[(size_t)(m0 + r) * lda + k0 + sq * 8];
      *(uint4*)&As[r][sq * 8] = va;
      uint4 vb = *(const uint4*)&Bg[(size_t)(n0 + r) * ldw + k0 + sq * 8];
      *(uint4*)&Bs[r][sq * 8] = vb;
    }
    __syncthreads();
    short8 a[4], b[4];
#pragma unroll
    for (int mi = 0; mi < 4; mi++)
      a[mi] = *(const short8*)&As[wm + mi * 16 + l16][quad * 8];
#pragma unroll
    for (int ni = 0; ni < 4; ni++)
      b[ni] = *(const short8*)&Bs[wn + ni * 16 + l16][quad * 8];
#pragma unroll
    for (int mi = 0; mi < 4; mi++)
#pragma unroll
      for (int ni = 0; ni < 4; ni++)
        acc[mi][ni] = __builtin_amdgcn_mfma_f32_16x16x32_bf16(
            a[mi], b[ni], acc[mi][ni], 0, 0, 0);
    __syncthreads();
  }
  float bn[4];
#pragma unroll
  for (int ni = 0; ni < 4; ni++) bn[ni] = bias[n0 + wn + ni * 16 + l16];
#pragma unroll
  for (int mi = 0; mi < 4; mi++)
#pragma unroll
    for (int ni = 0; ni < 4; ni++) {
      int n = n0 + wn + ni * 16 + l16;
#pragma unroll
      for (int r = 0; r < 4; r++) {
        int m = m0 + wm + mi * 16 + quad * 4 + r;
        float v = fmaxf(acc[mi][ni][r] + bn[ni], 0.f);
        if (OUT_BF16)
          ((__hip_bfloat16*)Y)[(size_t)m * ldy + n] = (__hip_bfloat16)v;
        else
          ((float*)Y)[(size_t)m * ldy + n] = v;
      }
    }
}

// ---------------------------------------------------------------------------
// Multi-job bf16 MFMA GEMM.
// ---------------------------------------------------------------------------
struct GJobs {
  const short* A[3];
  const short* W[3];
  const float* bias[3];
  __hip_bfloat16* Y[3];
  int lda[3], ldw[3], ldy[3], N[3], K[3], xt[3], off[3];
};

__global__ __launch_bounds__(256) void gemm_mfma_multi(GJobs g)
{
  __shared__ __align__(16) short As[128][40];
  __shared__ __align__(16) short Bs[128][40];
  int bid = blockIdx.x;
  int j = 0;
#pragma unroll
  for (int t = 1; t < 3; t++)
    if (bid >= g.off[t]) j = t;
  int rel = bid - g.off[j];
  int xt = g.xt[j];
  int m0 = (rel / xt) << 7, n0 = (rel % xt) << 7;
  int lda = g.lda[j], ldw = g.ldw[j], ldy = g.ldy[j], K = g.K[j];
  const short* Ag = g.A[j];
  const short* Bg = g.W[j];
  const float* bias = g.bias[j];
  __hip_bfloat16* Y = g.Y[j];

  int tid = threadIdx.x;
  int wave = tid >> 6, lane = tid & 63;
  int quad = lane >> 4, l16 = lane & 15;
  int wm = (wave >> 1) << 6, wn = (wave & 1) << 6;
  f32x4 acc[4][4] = {};
  int srow = tid >> 2, sq = tid & 3;
  for (int k0 = 0; k0 < K; k0 += 32) {
#pragma unroll
    for (int h = 0; h < 2; h++) {
      int r = srow + (h << 6);
      uint4 va = *(const uint4*)&Ag[(size_t)(m0 + r) * lda + k0 + sq * 8];
      *(uint4*)&As[r][sq * 8] = va;
      uint4 vb = *(const uint4*)&Bg[(size_t)(n0 + r) * ldw + k0 + sq * 8];
      *(uint4*)&Bs[r][sq * 8] = vb;
    }
    __syncthreads();
    short8 a[4], b[4];
#pragma unroll
    for (int mi = 0; mi < 4; mi++)
      a[mi] = *(const short8*)&As[wm + mi * 16 + l16][quad * 8];
#pragma unroll
    for (int ni = 0; ni < 4; ni++)
      b[ni] = *(const short8*)&Bs[wn + ni * 16 + l16][quad * 8];
#pragma unroll
    for (int mi = 0; mi < 4; mi++)
#pragma unroll
      for (int ni = 0; ni < 4; ni++)
        acc[mi][ni] = __builtin_amdgcn_mfma_f32_16x16x32_bf16(
            a[mi], b[ni], acc[mi][ni], 0, 0, 0);
    __syncthreads();
  }
  float bn[4];
#pragma unroll
  for (int ni = 0; ni < 4; ni++) bn[ni] = bias[n0 + wn + ni * 16 + l16];
#pragma unroll
  for (int mi = 0; mi < 4; mi++)
#pragma unroll
    for (int ni = 0; ni < 4; ni++) {
      int n = n0 + wn + ni * 16 + l16;
#pragma unroll
      for (int r = 0; r < 4; r++) {
        int m = m0 + wm + mi * 16 + quad * 4 + r;
        float v = fmaxf(acc[mi][ni][r] + bn[ni], 0.f);
        Y[(size_t)m * ldy + n] = (__hip_bfloat16)v;
      }
    }
}

// ---------------------------------------------------------------------------
// fc2 + out head fused.
// ---------------------------------------------------------------------------
__global__ __launch_bounds__(256) void gemm_fc2_out(
    const __hip_bfloat16* __restrict__ A,
    const __hip_bfloat16* __restrict__ Wt,
    const float* __restrict__ bias,
    const float* __restrict__ wout,
    const float* __restrict__ bout,
    float* __restrict__ out)
{
  __shared__ __align__(16) short As[128][40];
  __shared__ __align__(16) short Bs[128][40];
  __shared__ float red[128][2];
  const int N = 128, K = 256, lda = 256, ldw = 256;
  int tid = threadIdx.x;
  int wave = tid >> 6, lane = tid & 63;
  int quad = lane >> 4, l16 = lane & 15;
  int m0 = blockIdx.y << 7;
  int wm = (wave >> 1) << 6, wn = (wave & 1) << 6;
  f32x4 acc[4][4] = {};
  const short* Ag = (const short*)A;
  const short* Bg = (const short*)Wt;
  int srow = tid >> 2, sq = tid & 3;
  for (int k0 = 0; k0 < K; k0 += 32) {
#pragma unroll
    for (int h = 0; h < 2; h++) {
      int r = srow + (h << 6);
      uint4 va = *(const uint4*)&Ag[(size_t)(m0 + r) * lda + k0 + sq * 8];
      *(uint4*)&As[r][sq * 8] = va;
      uint4 vb = *(const uint4*)&Bg[(size_t)(r % N) * ldw + k0 + sq * 8];
      *(uint4*)&Bs[r][sq * 8] = vb;
    }
    __syncthreads();
    short8 a[4], b[4];
#pragma unroll
    for (int mi = 0; mi < 4; mi++)
      a[mi] = *(const short8*)&As[wm + mi * 16 + l16][quad * 8];
#pragma unroll
    for (int ni = 0; ni < 4; ni++)
      b[ni] = *(const short8*)&Bs[wn + ni * 16 + l16][quad * 8];
#pragma unroll
    for (int mi = 0; mi < 4; mi++)
#pragma unroll
      for (int ni = 0; ni < 4; ni++)
        acc[mi][ni] = __builtin_amdgcn_mfma_f32_16x16x32_bf16(
            a[mi], b[ni], acc[mi][ni], 0, 0, 0);
    __syncthreads();
  }
  float bn[4], wo[4];
#pragma unroll
  for (int ni = 0; ni < 4; ni++) {
    int n = wn + ni * 16 + l16;
    bn[ni] = bias[n];
    wo[ni] = wout[n];
  }
  float sacc[4][4];
#pragma unroll
  for (int mi = 0; mi < 4; mi++)
#pragma unroll
    for (int r = 0; r < 4; r++) {
      float s = 0.f;
#pragma unroll
      for (int ni = 0; ni < 4; ni++)
        s += fmaxf(acc[mi][ni][r] + bn[ni], 0.f) * wo[ni];
      sacc[mi][r] = s;
    }
#pragma unroll
  for (int off = 1; off < 16; off <<= 1)
#pragma unroll
    for (int mi = 0; mi < 4; mi++)
#pragma unroll
      for (int r = 0; r < 4; r++)
        sacc[mi][r] += __shfl_xor(sacc[mi][r], off);
  int wp = wave & 1;
  if (l16 == 0) {
#pragma unroll
    for (int mi = 0; mi < 4; mi++)
#pragma unroll
      for (int r = 0; r < 4; r++)
        red[wm + mi * 16 + quad * 4 + r][wp] = sacc[mi][r];
  }
  __syncthreads();
  if (tid < 128) {
    float s = red[tid][0] + red[tid][1] + bout[0];
    out[(size_t)(m0 + tid)] = 1.f / (1.f + expf(-s));
  }
}

// ---------------------------------------------------------------------------
// SA1 KNN v9 (round-15/16 version, passing — bit-identical selection).
// ---------------------------------------------------------------------------
__global__ __launch_bounds__(256) void knn_mean4(
    const float* __restrict__ X,
    const float* __restrict__ G1,
    float* __restrict__ X1,
    __hip_bfloat16* __restrict__ X1b,
    __hip_bfloat16* __restrict__ X1lo,
    float* __restrict__ nrmX1)
{
  int blk = blockIdx.x;
  int qb = ((blk & 7) << 11) + ((blk >> 3) << 2);
  int base = qb & ~2047;
  int tid = threadIdx.x;
  int wave = tid >> 6, lane = tid & 63;
  __shared__ unsigned long long lmins[4][256];
  __shared__ unsigned long long qmins[4][64];
  __shared__ unsigned long long thr[4];
  __shared__ unsigned long long surv[4][256];
  __shared__ int scnt[4];
  __shared__ int selidx[4][32];
  if (tid < 4) scnt[tid] = 0;
  float xj[8], yj[8];
#pragma unroll
  for (int u = 0; u < 8; u++) {
    int j = (u << 8) + tid;
    float2 c = *(const float2*)&X[(size_t)(base + j) * 2];
    xj[u] = c.x;
    yj[u] = c.y;
  }
  unsigned long long key[4][8];
#pragma unroll
  for (int g = 0; g < 4; g++) {
    float qx = X[(size_t)(qb + g) * 2];
    float qy = X[(size_t)(qb + g) * 2 + 1];
    unsigned long long lm = ~0ull;
#pragma unroll
    for (int u = 0; u < 8; u++) {
      float dx = xj[u] - qx;
      float dy = yj[u] - qy;
      float d2 = dx * dx + dy * dy;
      key[g][u] = ((unsigned long long)__float_as_uint(d2) << 32) |
                  (unsigned)((u << 8) + tid);
      lm = umin64(lm, key[g][u]);
    }
    lmins[g][tid] = lm;
  }
  __syncthreads();
  {
    int g = wave;
    unsigned long long qm =
        umin64(umin64(lmins[g][lane], lmins[g][lane + 64]),
               umin64(lmins[g][lane + 128], lmins[g][lane + 192]));
    qmins[g][lane] = qm;
    int rank = 0;
    for (int i = 0; i < 64; i++) rank += (qmins[g][i] < qm);
    if (rank == 31) thr[g] = qm;
  }
  __syncthreads();
#pragma unroll
  for (int g = 0; g < 4; g++) {
    unsigned long long T = thr[g];
#pragma unroll
    for (int u = 0; u < 8; u++) {
      if (key[g][u] <= T) {
        int p = atomicAdd(&scnt[g], 1);
        if (p < 256) surv[g][p] = key[g][u];
      }
    }
  }
  __syncthreads();
  int ovf[4] = {scnt[0], scnt[1], scnt[2], scnt[3]};
  {
    int g = wave;
    int s = ovf[g];
    if (s <= 256) {
      for (int i = lane; i < s; i += 64) {
        unsigned long long c = surv[g][i];
        int r = 0;
        for (int j2 = 0; j2 < s; j2++) r += (surv[g][j2] < c);
        if (r < 32) selidx[g][r] = (int)(c & 0xffffffffULL);
      }
    }
  }
  if (ovf[0] > 256 || ovf[1] > 256 || ovf[2] > 256 || ovf[3] > 256) {
    unsigned long long* ob = &lmins[0][0];
    for (int g = 0; g < 4; g++) {
      if (ovf[g] <= 256) continue;
      __syncthreads();
      if (tid == 0) scnt[g] = 0;
      __syncthreads();
      unsigned long long T = thr[g];
#pragma unroll
      for (int u = 0; u < 8; u++) {
        if (key[g][u] <= T) {
          int p = atomicAdd(&scnt[g], 1);
          ob[p] = key[g][u];
        }
      }
      __syncthreads();
      int s2 = scnt[g];
      for (int i = tid; i < s2; i += 256) {
        unsigned long long c = ob[i];
        int r = 0;
        for (int j2 = 0; j2 < s2; j2++) r += (ob[j2] < c);
        if (r < 32) selidx[g][r] = (int)(c & 0xffffffffULL);
      }
    }
    __syncthreads();
  }
  {
    int g = wave;
    float acc = 0.f;
#pragma unroll 8
    for (int sI = 0; sI < 32; sI++)
      acc += G1[(size_t)(base + selidx[g][sI]) * 64 + lane];
    float v = acc * (1.0f / 32.0f);
    int q = qb + g;
    X1[(size_t)q * 64 + lane] = v;
    __hip_bfloat16 hi = (__hip_bfloat16)v;
    X1b[(size_t)q * 64 + lane] = hi;
    X1lo[(size_t)q * 64 + lane] = (__hip_bfloat16)(v - (float)hi);
    float nv = v * v;
#pragma unroll
    for (int off = 32; off > 0; off >>= 1) nv += __shfl_down(nv, off);
    if (lane == 0) nrmX1[q] = nv;
  }
}

// ---------------------------------------------------------------------------
// Ball-query pass 1 — split-bf16 MFMA gram + exact-decision guard band
// (round-12 version, passing; masks bit-identical).
// ---------------------------------------------------------------------------
template <int C>
__global__ __launch_bounds__(256) void ball_mask_mfma(
    const float* __restrict__ F32,
    const __hip_bfloat16* __restrict__ Fhi,
    const __hip_bfloat16* __restrict__ Flo,
    const float* __restrict__ nrm,
    unsigned long long* __restrict__ mask,
    float r2)
{
  __shared__ __align__(16) short Qh[128][40];
  __shared__ __align__(16) short Ql[128][40];
  __shared__ __align__(16) short Ch[128][40];
  __shared__ __align__(16) short Cl[128][40];
  __shared__ unsigned int tw[128][4];
  __shared__ float nqs[128], ncs[128];
  int tid = threadIdx.x;
  int p = blockIdx.x;
  int qt = 0;
  while (p >= 16 - qt) { p -= 16 - qt; qt++; }
  int ct = qt + p;
  int b0 = blockIdx.y << 11;
  int q0 = b0 + (qt << 7), c0 = b0 + (ct << 7);
  tw[tid >> 1][(tid & 1) * 2] = 0;
  tw[tid >> 1][(tid & 1) * 2 + 1] = 0;
  if (tid < 128) nqs[tid] = nrm[q0 + tid];
  else ncs[tid - 128] = nrm[c0 + tid - 128];

  int wave = tid >> 6, lane = tid & 63;
  int quad = lane >> 4, l16 = lane & 15;
  int wm = (wave >> 1) << 6, wn = (wave & 1) << 6;
  f32x4 acc[4][4] = {};
  const short* QH = (const short*)Fhi;
  const short* QL = (const short*)Flo;
  int srow = tid >> 2, sq = tid & 3;
  for (int k0 = 0; k0 < C; k0 += 32) {
#pragma unroll
    for (int h = 0; h < 2; h++) {
      int r = srow + (h << 6);
      *(uint4*)&Qh[r][sq * 8] = *(const uint4*)&QH[(size_t)(q0 + r) * C + k0 + sq * 8];
      *(uint4*)&Ql[r][sq * 8] = *(const uint4*)&QL[(size_t)(q0 + r) * C + k0 + sq * 8];
      *(uint4*)&Ch[r][sq * 8] = *(const uint4*)&QH[(size_t)(c0 + r) * C + k0 + sq * 8];
      *(uint4*)&Cl[r][sq * 8] = *(const uint4*)&QL[(size_t)(c0 + r) * C + k0 + sq * 8];
    }
    __syncthreads();
    short8 ah[4], al[4];
#pragma unroll
    for (int mi = 0; mi < 4; mi++) {
      ah[mi] = *(const short8*)&Qh[wm + mi * 16 + l16][quad * 8];
      al[mi] = *(const short8*)&Ql[wm + mi * 16 + l16][quad * 8];
    }
#pragma unroll
    for (int ni = 0; ni < 4; ni++) {
      short8 bh = *(const short8*)&Ch[wn + ni * 16 + l16][quad * 8];
      short8 bl = *(const short8*)&Cl[wn + ni * 16 + l16][quad * 8];
#pragma unroll
      for (int mi = 0; mi < 4; mi++) {
        acc[mi][ni] = __builtin_amdgcn_mfma_f32_16x16x32_bf16(ah[mi], bh, acc[mi][ni], 0, 0, 0);
        acc[mi][ni] = __builtin_amdgcn_mfma_f32_16x16x32_bf16(ah[mi], bl, acc[mi][ni], 0, 0, 0);
        acc[mi][ni] = __builtin_amdgcn_mfma_f32_16x16x32_bf16(al[mi], bh, acc[mi][ni], 0, 0, 0);
      }
    }
    __syncthreads();
  }
  unsigned long long memb = 0, fb = 0;
#pragma unroll
  for (int mi = 0; mi < 4; mi++)
#pragma unroll
    for (int ni = 0; ni < 4; ni++)
#pragma unroll
      for (int r = 0; r < 4; r++) {
        int e = (mi << 4) | (ni << 2) | r;
        float nqv = nqs[wm + mi * 16 + quad * 4 + r];
        float ncv = ncs[wn + ni * 16 + l16];
        float d2a = nqv + ncv - 2.f * acc[mi][ni][r];
        float eps = 4.0e-5f * (nqv + ncv) + 1.0e-6f;
        if (d2a < r2 - eps) memb |= 1ull << e;
        else if (d2a <= r2 + eps) fb |= 1ull << e;
      }
  while (fb) {
    int e = __builtin_ctzll(fb);
    fb &= fb - 1;
    int mi = e >> 4, ni = (e >> 2) & 3, r = e & 3;
    int qrow = q0 + wm + mi * 16 + quad * 4 + r;
    int ccol = c0 + wn + ni * 16 + l16;
    float a2 = 0.f;
    for (int k = 0; k < C; k++) {
      float d = F32[(size_t)qrow * C + k] - F32[(size_t)ccol * C + k];
      a2 = fmaf(d, d, a2);
    }
    if (a2 <= r2) memb |= 1ull << e;
  }
#pragma unroll
  for (int ni = 0; ni < 4; ni++) {
    int cl = wn + ni * 16 + l16;
    unsigned int w0b = 0, w1b = 0;
#pragma unroll
    for (int mi = 0; mi < 4; mi++)
#pragma unroll
      for (int r = 0; r < 4; r++)
        if (memb & (1ull << ((mi << 4) | (ni << 2) | r))) {
          unsigned int bitpos = ((mi & 1) << 4) | (quad << 2) | r;
          if (mi < 2) w0b |= 1u << bitpos;
          else w1b |= 1u << bitpos;
        }
    if (w0b) atomicOr(&tw[cl][(wm >> 5)], w0b);
    if (w1b) atomicOr(&tw[cl][(wm >> 5) + 1], w1b);
  }
  __syncthreads();
  {
    int row = tid >> 1, half = tid & 1;
    int wq = row >> 5, sb = row & 31;
    unsigned int lo = 0, hi = 0;
    for (int j = 0; j < 32; j++) {
      lo |= ((tw[half * 64 + j][wq] >> sb) & 1u) << j;
      hi |= ((tw[half * 64 + 32 + j][wq] >> sb) & 1u) << j;
    }
    mask[(size_t)(q0 + row) * 32 + (ct << 1) + half] =
        ((unsigned long long)hi << 32) | lo;
  }
  if (qt != ct) {
    int row = tid >> 1, word = tid & 1;
    unsigned long long v = (unsigned long long)tw[row][word * 2] |
                           ((unsigned long long)tw[row][word * 2 + 1] << 32);
    mask[(size_t)(c0 + row) * 32 + (qt << 1) + word] = v;
  }
}

// ---------------------------------------------------------------------------
// Ball-query gather v3 — 4 queries/block (one per wave), vectorized loads,
// ZERO __syncthreads (wave-internal LDS ordering). Per-channel accumulation
// chain ascending-s with the same fma contraction -> outputs bit-identical.
// fp32 variant: 2 ch/lane (float2). bf16 variant: 4 ch/lane (uint2).
// ---------------------------------------------------------------------------
__global__ __launch_bounds__(256) void ball_gather4_f32(
    const unsigned long long* __restrict__ mask,
    const float* __restrict__ H, int CH,
    float* __restrict__ Yf, __hip_bfloat16* __restrict__ Yb,
    __hip_bfloat16* __restrict__ Ylo, float* __restrict__ nrm,
    int ldy, int S)
{
  int blk = blockIdx.x;
  int tid = threadIdx.x;
  int wave = tid >> 6, lane = tid & 63;
  int q = ((blk & 7) << 11) + ((blk >> 3) << 2) + wave;
  int base = q & ~2047;
  __shared__ int idxl[4][64];
  __shared__ float wtab[4][64];
  __shared__ int scount[4];
  if (lane < 32) {
    unsigned long long w = mask[(size_t)q * 32 + lane];
    int cnt = __popcll(w);
    int inc = cnt;
#pragma unroll
    for (int off = 1; off < 32; off <<= 1) {
      int o = __shfl_up(inc, off);
      if (lane >= off) inc += o;
    }
    if (lane == 31) scount[wave] = inc;
    int p = inc - cnt;
    while (w && p < 64) {
      int j = (lane << 6) + __builtin_ctzll(w);
      w &= w - 1;
      idxl[wave][p++] = j;
    }
  }
  int c = scount[wave];  // same-wave write->read: in-order per wave
  {
    int p = lane;
    int cnt = (p < c && p < S) ? ((S - 1 - p) / c + 1) : 0;
    wtab[wave][p] = (float)cnt / (float)S;
  }
  float acc0 = 0.f, acc1 = 0.f;
  int lim = c < S ? c : S;
#pragma unroll 4
  for (int s = 0; s < lim; s++) {
    float wv = wtab[wave][s];
    float2 v = *(const float2*)&H[(size_t)(base + idxl[wave][s]) * CH + lane * 2];
    acc0 += wv * v.x;
    acc1 += wv * v.y;
  }
  int n0 = lane * 2;
  if (Yf) *(float2*)&Yf[(size_t)q * ldy + n0] = make_float2(acc0, acc1);
  if (Yb) {
    Yb[(size_t)q * ldy + n0] = (__hip_bfloat16)acc0;
    Yb[(size_t)q * ldy + n0 + 1] = (__hip_bfloat16)acc1;
  }
  if (Ylo) {
    __hip_bfloat16 h0 = (__hip_bfloat16)acc0, h1 = (__hip_bfloat16)acc1;
    Ylo[(size_t)q * ldy + n0] = (__hip_bfloat16)(acc0 - (float)h0);
    Ylo[(size_t)q * ldy + n0 + 1] = (__hip_bfloat16)(acc1 - (float)h1);
  }
  if (nrm) {
    float nv = acc0 * acc0 + acc1 * acc1;
#pragma unroll
    for (int off = 32; off > 0; off >>= 1) nv += __shfl_down(nv, off);
    if (lane == 0) nrm[q] = nv;
  }
}

__global__ __launch_bounds__(256) void ball_gather4_bf16(
    const unsigned long long* __restrict__ mask,
    const __hip_bfloat16* __restrict__ H, int CH,
    __hip_bfloat16* __restrict__ Yb, int ldy, int S)
{
  int blk = blockIdx.x;
  int tid = threadIdx.x;
  int wave = tid >> 6, lane = tid & 63;
  int q = ((blk & 7) << 11) + ((blk >> 3) << 2) + wave;
  int base = q & ~2047;
  __shared__ int idxl[4][64];
  __shared__ float wtab[4][64];
  __shared__ int scount[4];
  if (lane < 32) {
    unsigned long long w = mask[(size_t)q * 32 + lane];
    int cnt = __popcll(w);
    int inc = cnt;
#pragma unroll
    for (int off = 1; off < 32; off <<= 1) {
      int o = __shfl_up(inc, off);
      if (lane >= off) inc += o;
    }
    if (lane == 31) scount[wave] = inc;
    int p = inc - cnt;
    while (w && p < 64) {
      int j = (lane << 6) + __builtin_ctzll(w);
      w &= w - 1;
      idxl[wave][p++] = j;
    }
  }
  int c = scount[wave];
  {
    int p = lane;
    int cnt = (p < c && p < S) ? ((S - 1 - p) / c + 1) : 0;
    wtab[wave][p] = (float)cnt / (float)S;
  }
  const unsigned short* Hs = (const unsigned short*)H;
  float acc[4] = {0.f, 0.f, 0.f, 0.f};
  int lim = c < S ? c : S;
#pragma unroll 4
  for (int s = 0; s < lim; s++) {
    float wv = wtab[wave][s];
    uint2 v = *(const uint2*)&Hs[(size_t)(base + idxl[wave][s]) * CH + lane * 4];
    acc[0] += wv * __uint_as_float(v.x << 16);
    acc[1] += wv * __uint_as_float(v.x & 0xffff0000u);
    acc[2] += wv * __uint_as_float(v.y << 16);
    acc[3] += wv * __uint_as_float(v.y & 0xffff0000u);
  }
  int n0 = lane * 4;
#pragma unroll
  for (int j = 0; j < 4; j++)
    Yb[(size_t)q * ldy + n0 + j] = (__hip_bfloat16)acc[j];
}

// ---------------------------------------------------------------------------
extern "C" void kernel_launch(void* const* d_in, const int* in_sizes, int n_in,
                              void* d_out, int out_size, void* d_ws,
                              size_t ws_size, hipStream_t stream)
{
  const float* x      = (const float*)d_in[0];
  const float* sa1_w0 = (const float*)d_in[1];
  const float* sa1_b0 = (const float*)d_in[2];
  const float* sa1_w1 = (const float*)d_in[3];
  const float* sa1_b1 = (const float*)d_in[4];
  const float* sa2_w0 = (const float*)d_in[5];
  const float* sa2_b0 = (const float*)d_in[6];
  const float* sa2_w1 = (const float*)d_in[7];
  const float* sa2_b1 = (const float*)d_in[8];
  const float* sa3_w0 = (const float*)d_in[9];
  const float* sa3_b0 = (const float*)d_in[10];
  const float* sa3_w1 = (const float*)d_in[11];
  const float* sa3_b1 = (const float*)d_in[12];
  const float* fp1_w0 = (const float*)d_in[13];
  const float* fp1_b0 = (const float*)d_in[14];
  const float* fp1_w1 = (const float*)d_in[15];
  const float* fp1_b1 = (const float*)d_in[16];
  const float* fp2_w0 = (const float*)d_in[17];
  const float* fp2_b0 = (const float*)d_in[18];
  const float* fp2_w1 = (const float*)d_in[19];
  const float* fp2_b1 = (const float*)d_in[20];
  const float* fc1_w  = (const float*)d_in[21];
  const float* fc1_b  = (const float*)d_in[22];
  const float* fc2_w  = (const float*)d_in[23];
  const float* fc2_b  = (const float*)d_in[24];
  const float* out_w  = (const float*)d_in[25];
  const float* out_b  = (const float*)d_in[26];
  float* out = (float*)d_out;

  const size_t M = M_ROWS;
  float* ws = (float*)d_ws;
  float* G1  = ws + M * 256;   // [256,320)
  float* X1  = ws + M * 320;   // [320,384)
  float* X2  = ws + M * 384;   // [384,512)
  float* H2  = ws + M * 512;   // [512,640)
  __hip_bfloat16* H3b16 = (__hip_bfloat16*)(ws + M * 640);  // [640,768)
  unsigned long long* MASK = (unsigned long long*)(ws + M * 896);  // [896,960)
  __hip_bfloat16* X1b = (__hip_bfloat16*)(ws + M * 960);    // [960,992)
  __hip_bfloat16* X2b = (__hip_bfloat16*)(ws + M * 992);    // [992,1056)
  __hip_bfloat16* TB0 = (__hip_bfloat16*)(ws + M * 1056);   // [1056,1184)
  __hip_bfloat16* TB1 = (__hip_bfloat16*)(ws + M * 1184);   // [1184,1440)
  __hip_bfloat16* TB2 = (__hip_bfloat16*)(ws + M * 1440);   // [1440,1568)
  __hip_bfloat16* G   = (__hip_bfloat16*)(ws + M * 1568);   // [1568,2080)
  __hip_bfloat16* H3b = (__hip_bfloat16*)(ws + M * 2080);   // [2080,2208)
  __hip_bfloat16* WB  = (__hip_bfloat16*)(ws + M * 2208);   // weights
  __hip_bfloat16* X1lo = (__hip_bfloat16*)(ws + M * 2240);  // [2240,2272)
  __hip_bfloat16* X2lo = (__hip_bfloat16*)(ws + M * 2272);  // [2272,2336)
  float* nrmX1 = ws + M * 2336;                             // [2336,2337)
  float* nrmX2 = ws + M * 2337;                             // [2337,2338)
  if (ws_size < (size_t)M * 2340 * sizeof(float)) return;
  __hip_bfloat16* w_sa3_0 = WB;               // 256x128
  __hip_bfloat16* w_sa3_1 = w_sa3_0 + 32768;  // 256x256
  __hip_bfloat16* w_fp1_0 = w_sa3_1 + 65536;  // 512x128
  __hip_bfloat16* w_fp1_1 = w_fp1_0 + 65536;  // 512x512
  __hip_bfloat16* w_fp2_0 = w_fp1_1 + 262144; // 256x64
  __hip_bfloat16* w_fp2_1 = w_fp2_0 + 16384;  // 256x256
  __hip_bfloat16* w_fc1   = w_fp2_1 + 65536;  // 256x1024
  __hip_bfloat16* w_fc2   = w_fc1 + 262144;   // 128x256

  dim3 blk(256);
  TJobs jb;
  const float* srcs[8] = {sa3_w0, sa3_w1, fp1_w0, fp1_w1, fp2_w0, fp2_w1, fc1_w, fc2_w};
  __hip_bfloat16* dsts[8] = {w_sa3_0, w_sa3_1, w_fp1_0, w_fp1_1, w_fp2_0, w_fp2_1, w_fc1, w_fc2};
  int Ks[8] = {128, 256, 128, 512, 64, 256, 1024, 256};
  int Ns[8] = {256, 256, 512, 512, 256, 256, 256, 128};
  int off = 0;
  for (int i = 0; i < 8; i++) {
    jb.W[i] = srcs[i]; jb.Wt[i] = dsts[i];
    jb.K[i] = Ks[i]; jb.N[i] = Ns[i];
    jb.bx[i] = Ns[i] >> 5;
    jb.off[i] = off;
    off += (Ns[i] >> 5) * (Ks[i] >> 5);
  }
  // Prologue: weight transposes + SA1 fused in one dispatch.
  prologue_kernel<<<off + 256, blk, 0, stream>>>(jb, off, x, sa1_w0, sa1_b0,
                                                 sa1_w1, sa1_b1, G1);
  knn_mean4<<<4096, 256, 0, stream>>>(x, G1, X1, X1b, X1lo, nrmX1);
  // SA2 fused + ball64 + gather2 (4 queries/block, float2 loads).
  sa2_fused<<<256, blk, 0, stream>>>(X1, sa2_w0, sa2_b0, sa2_w1, sa2_b1, H2);
  ball_mask_mfma<64><<<dim3(136, 8), blk, 0, stream>>>(X1, X1b, X1lo, nrmX1, MASK, 0.2f * 0.2f);
  ball_gather4_f32<<<4096, blk, 0, stream>>>(MASK, H2, 128, X2, X2b, X2lo, nrmX2, 128, 32);
  // ball128, then the fused layer-1 and layer-2 GEMM triples.
  ball_mask_mfma<128><<<dim3(136, 8), blk, 0, stream>>>(X2, X2b, X2lo, nrmX2, MASK, 0.4f * 0.4f);
  {
    GJobs g1;
    g1.A[0] = (const short*)X2b; g1.W[0] = (const short*)w_sa3_0; g1.bias[0] = sa3_b0;
    g1.Y[0] = TB0; g1.lda[0] = 128; g1.ldw[0] = 128; g1.ldy[0] = 256; g1.N[0] = 256; g1.K[0] = 128;
    g1.A[1] = (const short*)X2b; g1.W[1] = (const short*)w_fp1_0; g1.bias[1] = fp1_b0;
    g1.Y[1] = TB1; g1.lda[1] = 128; g1.ldw[1] = 128; g1.ldy[1] = 512; g1.N[1] = 512; g1.K[1] = 128;
    g1.A[2] = (const short*)X1b; g1.W[2] = (const short*)w_fp2_0; g1.bias[2] = fp2_b0;
    g1.Y[2] = TB2; g1.lda[2] = 64; g1.ldw[2] = 64; g1.ldy[2] = 256; g1.N[2] = 256; g1.K[2] = 64;
    int tot1 = 0;
    for (int i = 0; i < 3; i++) {
      g1.xt[i] = g1.N[i] >> 7;
      g1.off[i] = tot1;
      tot1 += g1.xt[i] * 128;
    }
    gemm_mfma_multi<<<tot1, blk, 0, stream>>>(g1);

    GJobs g2;
    g2.A[0] = (const short*)TB0; g2.W[0] = (const short*)w_sa3_1; g2.bias[0] = sa3_b1;
    g2.Y[0] = H3b16; g2.lda[0] = 256; g2.ldw[0] = 256; g2.ldy[0] = 256; g2.N[0] = 256; g2.K[0] = 256;
    g2.A[1] = (const short*)TB1; g2.W[1] = (const short*)w_fp1_1; g2.bias[1] = fp1_b1;
    g2.Y[1] = G + 256; g2.lda[1] = 512; g2.ldw[1] = 512; g2.ldy[1] = 1024; g2.N[1] = 512; g2.K[1] = 512;
    g2.A[2] = (const short*)TB2; g2.W[2] = (const short*)w_fp2_1; g2.bias[2] = fp2_b1;
    g2.Y[2] = G; g2.lda[2] = 256; g2.ldw[2] = 256; g2.ldy[2] = 1024; g2.N[2] = 256; g2.K[2] = 256;
    int tot2 = 0;
    for (int i = 0; i < 3; i++) {
      g2.xt[i] = g2.N[i] >> 7;
      g2.off[i] = tot2;
      tot2 += g2.xt[i] * 128;
    }
    gemm_mfma_multi<<<tot2, blk, 0, stream>>>(g2);
  }
  // gather3 fills G[768:1024] (4 queries/block, uint2 bf16 loads).
  ball_gather4_bf16<<<4096, blk, 0, stream>>>(MASK, H3b16, 256, G + 768, 1024, 64);
  // Head: fc1 (bf16), then fc2+out fused.
  gemm_mfma<true><<<dim3(2, 128), blk, 0, stream>>>(G, 1024, w_fc1, 1024, fc1_b, H3b, 256, 256, 1024);
  gemm_fc2_out<<<dim3(1, 128), blk, 0, stream>>>(H3b, w_fc2, fc2_b, out_w, out_b, out);
}